// Round 4
// baseline (17002.249 us; speedup 1.0000x reference)
//
#include <hip/hip_runtime.h>
#include <hip/hip_bf16.h>

// Problem constants
#define BB_ 8
#define NVEC 4096
#define DIM 512
#define HEADS 8
#define DH 64
#define MM_ 256
#define ITERS 6
#define DEPTH 2
#define NCLASS 10
#define KER 33
#define INNER 512
#define LSEG 16  // NVEC / MM_

typedef long long ll;

// ---------------------------------------------------------------------------
// Tiled f32 GEMM: C[bz] = act(alpha * op(A[bz])@op(B[bz]) + bias) (+ C_in)
// 64x64 tile, BK=16, 256 threads, 16 outputs/thread. M,N from grid (mult of 64).
// ---------------------------------------------------------------------------
template<bool TB, bool GELU_ACT, bool RESID>
__global__ void __launch_bounds__(256)
gemm_k(const float* __restrict__ A, const float* __restrict__ B,
       const float* __restrict__ bias, float* __restrict__ C,
       int K, int lda, int ldb, int ldc,
       ll sA, ll sB, ll sC, float alpha)
{
    const int bz = blockIdx.z;
    const float* Ab = A + (ll)bz * sA;
    const float* Bb = B + (ll)bz * sB;
    float* Cb = C + (ll)bz * sC;
    const int m0 = blockIdx.y * 64;
    const int n0 = blockIdx.x * 64;
    const int tid = threadIdx.x;

    __shared__ __align__(16) float As[16][64];
    __shared__ __align__(16) float Bs[16][64];

    const int rt = tid / 16;   // 0..15 row group
    const int ct = tid % 16;   // 0..15 col group
    float acc[4][4] = {};

    const int la_r = tid >> 2;           // 0..63
    const int la_k = (tid & 3) * 4;      // 0,4,8,12
    const int lb_k = tid >> 4;           // 0..15
    const int lb_n = (tid & 15) * 4;     // 0..60

    for (int k0 = 0; k0 < K; k0 += 16) {
        {
            const float* p = Ab + (ll)(m0 + la_r) * lda + k0 + la_k;
            float4 v = *(const float4*)p;
            As[la_k + 0][la_r] = v.x; As[la_k + 1][la_r] = v.y;
            As[la_k + 2][la_r] = v.z; As[la_k + 3][la_r] = v.w;
        }
        if (TB) {
            const float* p = Bb + (ll)(n0 + la_r) * ldb + k0 + la_k;
            float4 v = *(const float4*)p;
            Bs[la_k + 0][la_r] = v.x; Bs[la_k + 1][la_r] = v.y;
            Bs[la_k + 2][la_r] = v.z; Bs[la_k + 3][la_r] = v.w;
        } else {
            const float* p = Bb + (ll)(k0 + lb_k) * ldb + n0 + lb_n;
            float4 v = *(const float4*)p;
            Bs[lb_k][lb_n + 0] = v.x; Bs[lb_k][lb_n + 1] = v.y;
            Bs[lb_k][lb_n + 2] = v.z; Bs[lb_k][lb_n + 3] = v.w;
        }
        __syncthreads();
#pragma unroll
        for (int kk = 0; kk < 16; ++kk) {
            float4 a4 = *(const float4*)&As[kk][rt * 4];
            float4 b4 = *(const float4*)&Bs[kk][ct * 4];
            float a[4] = {a4.x, a4.y, a4.z, a4.w};
            float b[4] = {b4.x, b4.y, b4.z, b4.w};
#pragma unroll
            for (int i = 0; i < 4; ++i)
#pragma unroll
                for (int j = 0; j < 4; ++j)
                    acc[i][j] = fmaf(a[i], b[j], acc[i][j]);
        }
        __syncthreads();
    }

#pragma unroll
    for (int i = 0; i < 4; ++i) {
        const int m = m0 + rt * 4 + i;
#pragma unroll
        for (int j = 0; j < 4; ++j) {
            const int n = n0 + ct * 4 + j;
            float v = alpha * acc[i][j];
            if (bias) v += bias[n];
            if (GELU_ACT) {
                float xx = v;
                float t = tanhf(0.7978845608f * (xx + 0.044715f * xx * xx * xx));
                v = 0.5f * xx * (1.0f + t);
            }
            float* cp = Cb + (ll)m * ldc + n;
            if (RESID) v += *cp;
            *cp = v;
        }
    }
}

// ---------------------------------------------------------------------------
__global__ void embed_k(const float* __restrict__ x, const float* __restrict__ w,
                        const float* __restrict__ b, float* __restrict__ h)
{
    ll idx = (ll)blockIdx.x * 256 + threadIdx.x;   // B*NVEC*DIM
    int d = (int)(idx & 511);
    ll bn = idx >> 9;
    h[idx] = x[bn * 2] * w[d] + x[bn * 2 + 1] * w[512 + d] + b[d];
}

// one block (256 thr) per row of 512
__global__ void __launch_bounds__(256)
ln_k(const float* __restrict__ X, const float* __restrict__ g,
     const float* __restrict__ bta, float* __restrict__ Y)
{
    const ll row = blockIdx.x;
    const float* x = X + row * 512;
    float* y = Y + row * 512;
    const int tid = threadIdx.x;
    float v0 = x[tid], v1 = x[tid + 256];
    float s = v0 + v1;
    float q = v0 * v0 + v1 * v1;
    __shared__ float sred[8];
    for (int o = 32; o; o >>= 1) { s += __shfl_down(s, o); q += __shfl_down(q, o); }
    const int lane = tid & 63, w = tid >> 6;
    if (lane == 0) { sred[w] = s; sred[4 + w] = q; }
    __syncthreads();
    float ssum = sred[0] + sred[1] + sred[2] + sred[3];
    float qsum = sred[4] + sred[5] + sred[6] + sred[7];
    float mu = ssum * (1.0f / 512.0f);
    float var = qsum * (1.0f / 512.0f) - mu * mu;
    float r = rsqrtf(var + 1e-5f);
    y[tid] = (v0 - mu) * r * g[tid] + bta[tid];
    y[tid + 256] = (v1 - mu) * r * g[tid + 256] + bta[tid + 256];
}

// scatter scaled q from qkv_b [4096,1536] into Qb [h][n][64]
__global__ void qstore_k(const float* __restrict__ qkvb, float* __restrict__ Qb)
{
    int idx = blockIdx.x * 256 + threadIdx.x;   // 4096*512
    int c = idx & 511;
    int n = idx >> 9;
    int h = c >> 6, d = c & 63;
    Qb[((ll)(h * NVEC + n)) * 64 + d] = qkvb[(ll)n * 1536 + c] * 0.125f;
}

// landmark means for one batch sample: ql (scaled) / kl, layout [h][m][64]
__global__ void landmarksb_k(const float* __restrict__ qkvb,
                             float* __restrict__ qlb, float* __restrict__ klb)
{
    int idx = blockIdx.x * 256 + threadIdx.x;   // 8*256*64 = 131072
    int d = idx & 63;
    int m = (idx >> 6) & 255;
    int h = idx >> 14;
    const float* base = qkvb + (ll)(m * LSEG) * 1536 + h * 64 + d;
    float sq = 0.f, sk = 0.f;
#pragma unroll
    for (int l = 0; l < LSEG; ++l) {
        sq += base[(ll)l * 1536];
        sk += base[(ll)l * 1536 + 512];
    }
    int o = h * 16384 + m * 64 + d;
    qlb[o] = sq * (0.0625f * 0.125f);  // mean * DH^-0.5
    klb[o] = sk * 0.0625f;
}

// in-place row softmax, one block per row
__global__ void __launch_bounds__(256)
softmax_k(float* __restrict__ X, int L)
{
    const ll row = blockIdx.x;
    float* x = X + row * (ll)L;
    const int tid = threadIdx.x;
    __shared__ float red[8];
    float m = -1e30f;
    for (int i = tid; i < L; i += 256) m = fmaxf(m, x[i]);
    for (int o = 32; o; o >>= 1) m = fmaxf(m, __shfl_down(m, o));
    const int lane = tid & 63, w = tid >> 6;
    if (lane == 0) red[w] = m;
    __syncthreads();
    m = fmaxf(fmaxf(red[0], red[1]), fmaxf(red[2], red[3]));
    __syncthreads();
    float s = 0.f;
    for (int i = tid; i < L; i += 256) {
        float e = __expf(x[i] - m);
        x[i] = e;
        s += e;
    }
    for (int o = 32; o; o >>= 1) s += __shfl_down(s, o);
    if (lane == 0) red[w] = s;
    __syncthreads();
    s = red[0] + red[1] + red[2] + red[3];
    float inv = 1.0f / s;
    for (int i = tid; i < L; i += 256) x[i] *= inv;
}

// z0 = x^T / (max_rowsum * max_colsum), one block per (b,h)
__global__ void __launch_bounds__(256)
pinv_init_k(const float* __restrict__ X, float* __restrict__ Z)
{
    const ll bh = blockIdx.x;
    const float* x = X + bh * 65536;
    float* z = Z + bh * 65536;
    const int tid = threadIdx.x;
    float rs = 0.f, cs = 0.f;
    for (int j = 0; j < 256; ++j) {
        rs += fabsf(x[tid * 256 + j]);
        cs += fabsf(x[j * 256 + tid]);
    }
    __shared__ float rbuf[256], cbuf[256];
    rbuf[tid] = rs; cbuf[tid] = cs;
    __syncthreads();
    for (int o = 128; o; o >>= 1) {
        if (tid < o) {
            rbuf[tid] = fmaxf(rbuf[tid], rbuf[tid + o]);
            cbuf[tid] = fmaxf(cbuf[tid], cbuf[tid + o]);
        }
        __syncthreads();
    }
    float inv = 1.0f / (rbuf[0] * cbuf[0]);
    for (int e = tid; e < 65536; e += 256) {
        int i = e >> 8, j = e & 255;
        z[e] = x[j * 256 + i] * inv;
    }
}

// Y = alpha*I - X   (batched 256x256); safe in-place (elementwise same index)
__global__ void isub_k(const float* __restrict__ X, float* __restrict__ Y, float alpha)
{
    ll idx = (ll)blockIdx.x * 256 + threadIdx.x;
    int loc = (int)(idx & 65535);
    float v = -X[idx];
    if ((loc >> 8) == (loc & 255)) v += alpha;
    Y[idx] = v;
}

// depthwise conv for one batch sample: convb[n, h*64+d] = sum_j v[n+j-16, h*64+d]*w[h,j]
__global__ void convb_k(const float* __restrict__ qkvb, const float* __restrict__ cw,
                        float* __restrict__ convb)
{
    int idx = blockIdx.x * 256 + threadIdx.x;  // 4096*512
    int c = idx & 511;
    int n = idx >> 9;
    int h = c >> 6;
    const float* v = qkvb + 1024 + c;
    float acc = 0.f;
#pragma unroll
    for (int j = 0; j < KER; ++j) {
        int nn = n + j - (KER / 2);
        if (nn >= 0 && nn < NVEC) acc += v[(ll)nn * 1536] * cw[h * KER + j];
    }
    convb[(ll)n * 512 + c] = acc;
}

__global__ void final_init_k(const float* __restrict__ fb, float* __restrict__ out)
{
    int i = threadIdx.x;
    if (i < BB_ * NCLASS) out[i] = fb[i % NCLASS];
}

// grid (256 chunks, B); each block: partial dot over 8192 elems for 10 classes
__global__ void __launch_bounds__(256)
final_gemv_k(const float* __restrict__ hbuf, const float* __restrict__ w,
             float* __restrict__ out)
{
    const int b = blockIdx.y;
    const int chunk = blockIdx.x;
    const int tid = threadIdx.x;
    const float* hrow = hbuf + (ll)b * (NVEC * DIM);
    float pc[NCLASS] = {};
    const int k0 = chunk * 8192;
    for (int e = 0; e < 32; ++e) {
        int k = k0 + e * 256 + tid;
        float hv = hrow[k];
        const float* wr = w + (ll)k * NCLASS;
#pragma unroll
        for (int c = 0; c < NCLASS; ++c) pc[c] += hv * wr[c];
    }
    __shared__ float red[256];
    for (int c = 0; c < NCLASS; ++c) {
        red[tid] = pc[c];
        __syncthreads();
        for (int o = 128; o; o >>= 1) {
            if (tid < o) red[tid] += red[tid + o];
            __syncthreads();
        }
        if (tid == 0) atomicAdd(out + b * NCLASS + c, red[0]);
        __syncthreads();
    }
}

// ---------------------------------------------------------------------------
static inline void gemm(hipStream_t s, int M, int N, int K,
                        const float* A, int lda, ll sA,
                        const float* B, int ldb, ll sB,
                        float* C, int ldc, ll sC,
                        int batch, float alpha, const float* bias,
                        bool tb, bool gelu, bool resid)
{
    dim3 grid(N / 64, M / 64, batch);
    dim3 blk(256);
    if (tb)
        hipLaunchKernelGGL((gemm_k<true, false, false>), grid, blk, 0, s,
                           A, B, bias, C, K, lda, ldb, ldc, sA, sB, sC, alpha);
    else if (gelu)
        hipLaunchKernelGGL((gemm_k<false, true, false>), grid, blk, 0, s,
                           A, B, bias, C, K, lda, ldb, ldc, sA, sB, sC, alpha);
    else if (resid)
        hipLaunchKernelGGL((gemm_k<false, false, true>), grid, blk, 0, s,
                           A, B, bias, C, K, lda, ldb, ldc, sA, sB, sC, alpha);
    else
        hipLaunchKernelGGL((gemm_k<false, false, false>), grid, blk, 0, s,
                           A, B, bias, C, K, lda, ldb, ldc, sA, sB, sC, alpha);
}

extern "C" void kernel_launch(void* const* d_in, const int* in_sizes, int n_in,
                              void* d_out, int out_size, void* d_ws, size_t ws_size,
                              hipStream_t stream)
{
    const float* x      = (const float*)d_in[0];
    const float* lin_w  = (const float*)d_in[1];
    const float* lin_b  = (const float*)d_in[2];
    const float* ln1_g  = (const float*)d_in[3];
    const float* ln1_b  = (const float*)d_in[4];
    const float* qkv_w  = (const float*)d_in[5];
    const float* out_w  = (const float*)d_in[6];
    const float* out_b  = (const float*)d_in[7];
    const float* conv_w = (const float*)d_in[8];
    const float* ln2_g  = (const float*)d_in[9];
    const float* ln2_b  = (const float*)d_in[10];
    const float* ff1_w  = (const float*)d_in[11];
    const float* ff1_b  = (const float*)d_in[12];
    const float* ff2_w  = (const float*)d_in[13];
    const float* ff2_b  = (const float*)d_in[14];
    const float* final_w = (const float*)d_in[15];
    const float* final_b = (const float*)d_in[16];
    float* out = (float*)d_out;
    float* ws  = (float*)d_ws;

    // Compact workspace layout (floats). Total = 60,817,408 fl = 232 MB.
    const ll F_H   = 0;                       // [B][4096][512]       16,777,216
    const ll F_Q   = 16777216;                // [b][h][4096][64]     16,777,216 (pre-scaled)
    const ll F_S   = 33554432;                // shared scratch       18,874,368
    const ll F_AT2 = F_S + 18874368;          // [bh][256][256]        4,194,304
    const ll F_QL  = F_AT2 + 4194304;         // [bh][256][64]         1,048,576
    const ll F_KL  = F_QL + 1048576;
    const ll F_A3V = F_KL + 1048576;
    const ll F_WB  = F_A3V + 1048576;
    const ll F_END = F_WB + 1048576;          // 60,817,408

    if (ws_size < (size_t)F_END * 4) return;  // too small: leave out zeroed (diagnostic)

    float* H   = ws + F_H;
    float* Q   = ws + F_Q;
    float* S   = ws + F_S;
    float* AT2 = ws + F_AT2;
    float* QL  = ws + F_QL;
    float* KL  = ws + F_KL;
    float* A3V = ws + F_A3V;
    float* WB  = ws + F_WB;

    // scratch sub-buffers (time-sliced)
    float* XLNb  = S;                 // 2,097,152   phase1 / FFN ln chunk
    float* QKVb  = S + 2097152;       // 6,291,456   phase1 / FFN hidden
    float* ATT3b = S + 8388608;       // 8,388,608   phase1
    float* CONVb = S + 16777216;      // 2,097,152   phase1
    float* Z0    = S;                 // 4,194,304   phase2
    float* Z1    = S + 4194304;
    float* T1    = S + 8388608;
    float* T2    = S + 12582912;
    float* ATT1b = S;                 // 8,388,608   phase3
    float* AOUTb = S + 8388608;       // 2,097,152   phase3
    float* HIDc  = S + 2097152;       // 8,388,608   FFN

    // embed
    hipLaunchKernelGGL(embed_k, dim3(65536), dim3(256), 0, stream, x, lin_w, lin_b, H);

    for (int i = 0; i < DEPTH; ++i) {
        const float* wq  = qkv_w + (ll)i * 512 * 1536;
        const float* wo  = out_w + (ll)i * 512 * 512;
        const float* bo  = out_b + (ll)i * 512;
        const float* cw  = conv_w + (ll)i * HEADS * KER;
        const float* g1  = ln1_g + (ll)i * 512;
        const float* b1  = ln1_b + (ll)i * 512;
        const float* g2  = ln2_g + (ll)i * 512;
        const float* b2  = ln2_b + (ll)i * 512;
        const float* f1w = ff1_w + (ll)i * 512 * 2048;
        const float* f1b = ff1_b + (ll)i * 2048;
        const float* f2w = ff2_w + (ll)i * 2048 * 512;
        const float* f2b = ff2_b + (ll)i * 512;

        // ---- Phase 1: per batch sample ----
        for (int b = 0; b < BB_; ++b) {
            float* Hb = H + (ll)b * 2097152;
            // LN1 for this sample
            hipLaunchKernelGGL(ln_k, dim3(4096), dim3(256), 0, stream, Hb, g1, b1, XLNb);
            // qkv_b = xln_b @ wq   [4096,512]@[512,1536]
            gemm(stream, 4096, 1536, 512, XLNb, 512, 0, wq, 1536, 0,
                 QKVb, 1536, 0, 1, 1.0f, nullptr, false, false, false);
            // store scaled q
            hipLaunchKernelGGL(qstore_k, dim3(8192), dim3(256), 0, stream,
                               QKVb, Q + (ll)b * 2097152);
            // landmarks
            hipLaunchKernelGGL(landmarksb_k, dim3(512), dim3(256), 0, stream,
                               QKVb, QL + (ll)b * 131072, KL + (ll)b * 131072);
            // attn3 = ql_b @ k_b^T  -> [h][256][4096], batch over 8 heads
            gemm(stream, 256, 4096, 64,
                 QL + (ll)b * 131072, 64, 16384,
                 QKVb + 512, 1536, 64,
                 ATT3b, 4096, 1048576, 8, 1.0f, nullptr, true, false, false);
            hipLaunchKernelGGL(softmax_k, dim3(2048), dim3(256), 0, stream, ATT3b, 4096);
            // a3v = attn3 @ v_b  [256,4096]@[4096,64] per head
            gemm(stream, 256, 64, 4096,
                 ATT3b, 4096, 1048576,
                 QKVb + 1024, 1536, 64,
                 A3V + (ll)b * 131072, 64, 16384, 8, 1.0f, nullptr, false, false, false);
            // depthwise conv of v_b
            hipLaunchKernelGGL(convb_k, dim3(8192), dim3(256), 0, stream, QKVb, cw, CONVb);
            // H_b += conv_b @ wo   (bias added later in phase 3 projection)
            gemm(stream, 4096, 512, 512, CONVb, 512, 0, wo, 512, 0,
                 Hb, 512, 0, 1, 1.0f, nullptr, false, false, true);
        }

        // ---- Phase 2: batched over all 64 (b,h) ----
        // attn2 = softmax(ql @ kl^T)
        gemm(stream, 256, 256, 64, QL, 64, 16384, KL, 64, 16384,
             AT2, 256, 65536, 64, 1.0f, nullptr, true, false, false);
        hipLaunchKernelGGL(softmax_k, dim3(16384), dim3(256), 0, stream, AT2, 256);
        // pinv (Newton-Schulz)
        hipLaunchKernelGGL(pinv_init_k, dim3(64), dim3(256), 0, stream, AT2, Z0);
        float* zc = Z0; float* zn = Z1;
        for (int it = 0; it < ITERS; ++it) {
            // T1 = x @ z
            gemm(stream, 256, 256, 256, AT2, 256, 65536, zc, 256, 65536,
                 T1, 256, 65536, 64, 1.0f, nullptr, false, false, false);
            // T2 = 7I - T1
            hipLaunchKernelGGL(isub_k, dim3(16384), dim3(256), 0, stream, T1, T2, 7.0f);
            // zn = T1 @ T2
            gemm(stream, 256, 256, 256, T1, 256, 65536, T2, 256, 65536,
                 zn, 256, 65536, 64, 1.0f, nullptr, false, false, false);
            // zn = 15I - zn (in place)
            hipLaunchKernelGGL(isub_k, dim3(16384), dim3(256), 0, stream, zn, zn, 15.0f);
            // T2 = T1 @ zn
            gemm(stream, 256, 256, 256, T1, 256, 65536, zn, 256, 65536,
                 T2, 256, 65536, 64, 1.0f, nullptr, false, false, false);
            // T2 = 13I - T2 (in place)
            hipLaunchKernelGGL(isub_k, dim3(16384), dim3(256), 0, stream, T2, T2, 13.0f);
            // zn = 0.25 * zc @ T2
            gemm(stream, 256, 256, 256, zc, 256, 65536, T2, 256, 65536,
                 zn, 256, 65536, 64, 0.25f, nullptr, false, false, false);
            float* t = zc; zc = zn; zn = t;
        }
        // wb = z @ a3v  [256,256]@[256,64]
        gemm(stream, 256, 64, 256, zc, 256, 65536, A3V, 64, 16384,
             WB, 64, 16384, 64, 1.0f, nullptr, false, false, false);

        // ---- Phase 3: per batch sample ----
        for (int b = 0; b < BB_; ++b) {
            float* Hb = H + (ll)b * 2097152;
            // attn1 = softmax(q_b @ kl_b^T)   [4096,64]@[64,256] per head
            gemm(stream, 4096, 256, 64,
                 Q + (ll)b * 2097152, 64, 262144,
                 KL + (ll)b * 131072, 64, 16384,
                 ATT1b, 256, 1048576, 8, 1.0f, nullptr, true, false, false);
            hipLaunchKernelGGL(softmax_k, dim3(32768), dim3(256), 0, stream, ATT1b, 256);
            // aout_b = attn1 @ wb  -> [4096,512] (heads interleaved via ldc)
            gemm(stream, 4096, 64, 256,
                 ATT1b, 256, 1048576,
                 WB + (ll)b * 131072, 64, 16384,
                 AOUTb, 512, 64, 8, 1.0f, nullptr, false, false, false);
            // H_b += aout_b @ wo + bo
            gemm(stream, 4096, 512, 512, AOUTb, 512, 0, wo, 512, 0,
                 Hb, 512, 0, 1, 1.0f, bo, false, false, true);
        }

        // ---- FFN (row chunks of 4096) ----
        for (int c = 0; c < BB_; ++c) {
            float* Hc = H + (ll)c * 2097152;
            hipLaunchKernelGGL(ln_k, dim3(4096), dim3(256), 0, stream, Hc, g2, b2, XLNb);
            gemm(stream, 4096, 2048, 512, XLNb, 512, 0, f1w, 2048, 0,
                 HIDc, 2048, 0, 1, 1.0f, f1b, false, true, false);
            gemm(stream, 4096, 512, 2048, HIDc, 2048, 0, f2w, 512, 0,
                 Hc, 512, 0, 1, 1.0f, f2b, false, false, true);
        }
    }

    // final: out = h.reshape(B,-1) @ final_w + final_b
    hipLaunchKernelGGL(final_init_k, dim3(1), dim3(128), 0, stream, final_b, out);
    hipLaunchKernelGGL(final_gemv_k, dim3(256, BB_), dim3(256), 0, stream, H, final_w, out);
}

// Round 6
// 7184.545 us; speedup vs baseline: 2.3665x; 2.3665x over previous
//
#include <hip/hip_runtime.h>
#include <hip/hip_bf16.h>

// Problem constants
#define BB_ 8
#define NVEC 4096
#define DIM 512
#define HEADS 8
#define DH 64
#define MM_ 256
#define ITERS 6
#define DEPTH 2
#define NCLASS 10
#define KER 33
#define INNER 512
#define LSEG 16  // NVEC / MM_

typedef long long ll;
typedef __bf16 bh16;
typedef __attribute__((ext_vector_type(8))) __bf16 bf16x8;
typedef __attribute__((ext_vector_type(4))) float f32x4;

// ===========================================================================
// MFMA bf16 GEMM (TN): C = op(A[M,K] @ B_t[N,K]^T) ; A,B bf16 row-major.
// Tile BM=WR*64 x BN=WC*64, BK=32, 256 threads = 4 waves, wave does 64x64.
// LDS slot-swizzle: 16B slot index ^= (row>>1)&3  (2-way banks instead of 8).
// Two-level batch: z -> bo=z/BI (stride sXo), bi=z%BI (stride sXi).
// ===========================================================================
template<int WR, int WC, bool GELU_ACT, bool RESID, bool BF16OUT>
__global__ void __launch_bounds__(256)
mgemm_k(const bh16* __restrict__ A, const bh16* __restrict__ B,
        const float* __restrict__ bias, void* __restrict__ Cv,
        int K, int lda, int ldb, int ldc,
        int BI, ll sAo, ll sAi, ll sBo, ll sBi, ll sCo, ll sCi)
{
    constexpr int BM = WR * 64, BN = WC * 64;
    const int bz = blockIdx.z;
    const int bo = bz / BI, bi = bz % BI;
    const bh16* Ab = A + bo * sAo + (ll)bi * sAi;
    const bh16* Bb = B + bo * sBo + (ll)bi * sBi;
    const ll coff = bo * sCo + (ll)bi * sCi;
    const int m0 = blockIdx.y * BM;
    const int n0 = blockIdx.x * BN;
    const int tid = threadIdx.x;
    const int lane = tid & 63;
    const int wave = tid >> 6;
    const int wr = wave / WC, wc = wave % WC;

    __shared__ bh16 Al[BM * 32];
    __shared__ bh16 Bl[BN * 32];

    f32x4 acc[4][4];
#pragma unroll
    for (int i = 0; i < 4; ++i)
#pragma unroll
        for (int j = 0; j < 4; ++j) acc[i][j] = (f32x4){0.f, 0.f, 0.f, 0.f};

    const int srow = tid >> 2;   // 0..63
    const int ssl  = tid & 3;    // global 16B slot

    const int rsel  = ((lane & 15) >> 1) & 3;
    const int kslot = lane >> 4;

    for (int k0 = 0; k0 < K; k0 += 32) {
        __syncthreads();
#pragma unroll
        for (int i = 0; i < BM / 64; ++i) {
            int row = i * 64 + srow;
            int sl = ssl ^ ((row >> 1) & 3);
            bf16x8 v = *(const bf16x8*)(Ab + (ll)(m0 + row) * lda + k0 + ssl * 8);
            *(bf16x8*)(Al + row * 32 + sl * 8) = v;
        }
#pragma unroll
        for (int i = 0; i < BN / 64; ++i) {
            int row = i * 64 + srow;
            int sl = ssl ^ ((row >> 1) & 3);
            bf16x8 v = *(const bf16x8*)(Bb + (ll)(n0 + row) * ldb + k0 + ssl * 8);
            *(bf16x8*)(Bl + row * 32 + sl * 8) = v;
        }
        __syncthreads();

        bf16x8 af[4], bfr[4];
#pragma unroll
        for (int mi = 0; mi < 4; ++mi) {
            int row = wr * 64 + mi * 16 + (lane & 15);
            af[mi] = *(const bf16x8*)(Al + row * 32 + (kslot ^ rsel) * 8);
        }
#pragma unroll
        for (int ni = 0; ni < 4; ++ni) {
            int row = wc * 64 + ni * 16 + (lane & 15);
            bfr[ni] = *(const bf16x8*)(Bl + row * 32 + (kslot ^ rsel) * 8);
        }
#pragma unroll
        for (int mi = 0; mi < 4; ++mi)
#pragma unroll
            for (int ni = 0; ni < 4; ++ni)
                acc[mi][ni] = __builtin_amdgcn_mfma_f32_16x16x32_bf16(
                    af[mi], bfr[ni], acc[mi][ni], 0, 0, 0);
    }

#pragma unroll
    for (int mi = 0; mi < 4; ++mi) {
#pragma unroll
        for (int ni = 0; ni < 4; ++ni) {
            const int colg = n0 + wc * 64 + ni * 16 + (lane & 15);
            const float bia = bias ? bias[colg] : 0.f;
#pragma unroll
            for (int r = 0; r < 4; ++r) {
                const int rowg = m0 + wr * 64 + mi * 16 + (lane >> 4) * 4 + r;
                float v = acc[mi][ni][r] + bia;
                if (GELU_ACT) {
                    float t = tanhf(0.7978845608f * (v + 0.044715f * v * v * v));
                    v = 0.5f * v * (1.0f + t);
                }
                if (BF16OUT) {
                    ((bh16*)Cv)[coff + (ll)rowg * ldc + colg] = (bh16)v;
                } else {
                    float* p = (float*)Cv + coff + (ll)rowg * ldc + colg;
                    float o = v;
                    if (RESID) o += *p;
                    *p = o;
                }
            }
        }
    }
}

template<int WR, int WC, bool G, bool R, bool BO>
static inline void mgemm(hipStream_t s, int M, int N, int K,
                         const bh16* A, int lda, const bh16* B, int ldb,
                         void* C, int ldc, const float* bias, int batch, int BI,
                         ll sAo, ll sAi, ll sBo, ll sBi, ll sCo, ll sCi)
{
    dim3 grid(N / (WC * 64), M / (WR * 64), batch);
    hipLaunchKernelGGL((mgemm_k<WR, WC, G, R, BO>), grid, dim3(256), 0, s,
                       A, B, bias, C, K, lda, ldb, ldc, BI, sAo, sAi, sBo, sBi, sCo, sCi);
}

// ===========================================================================
// f32 tiled GEMM (kept for pinv chain / attn2 / wb - precision sensitive)
// ===========================================================================
template<bool TB>
__global__ void __launch_bounds__(256)
gemm_k(const float* __restrict__ A, const float* __restrict__ B,
       float* __restrict__ C, int K, int lda, int ldb, int ldc,
       ll sA, ll sB, ll sC, float alpha)
{
    const int bz = blockIdx.z;
    const float* Ab = A + (ll)bz * sA;
    const float* Bb = B + (ll)bz * sB;
    float* Cb = C + (ll)bz * sC;
    const int m0 = blockIdx.y * 64;
    const int n0 = blockIdx.x * 64;
    const int tid = threadIdx.x;

    __shared__ __align__(16) float As[16][64];
    __shared__ __align__(16) float Bs[16][64];

    const int rt = tid / 16;
    const int ct = tid % 16;
    float acc[4][4] = {};

    const int la_r = tid >> 2;
    const int la_k = (tid & 3) * 4;
    const int lb_k = tid >> 4;
    const int lb_n = (tid & 15) * 4;

    for (int k0 = 0; k0 < K; k0 += 16) {
        {
            const float* p = Ab + (ll)(m0 + la_r) * lda + k0 + la_k;
            float4 v = *(const float4*)p;
            As[la_k + 0][la_r] = v.x; As[la_k + 1][la_r] = v.y;
            As[la_k + 2][la_r] = v.z; As[la_k + 3][la_r] = v.w;
        }
        if (TB) {
            const float* p = Bb + (ll)(n0 + la_r) * ldb + k0 + la_k;
            float4 v = *(const float4*)p;
            Bs[la_k + 0][la_r] = v.x; Bs[la_k + 1][la_r] = v.y;
            Bs[la_k + 2][la_r] = v.z; Bs[la_k + 3][la_r] = v.w;
        } else {
            const float* p = Bb + (ll)(k0 + lb_k) * ldb + n0 + lb_n;
            float4 v = *(const float4*)p;
            Bs[lb_k][lb_n + 0] = v.x; Bs[lb_k][lb_n + 1] = v.y;
            Bs[lb_k][lb_n + 2] = v.z; Bs[lb_k][lb_n + 3] = v.w;
        }
        __syncthreads();
#pragma unroll
        for (int kk = 0; kk < 16; ++kk) {
            float4 a4 = *(const float4*)&As[kk][rt * 4];
            float4 b4 = *(const float4*)&Bs[kk][ct * 4];
            float a[4] = {a4.x, a4.y, a4.z, a4.w};
            float b[4] = {b4.x, b4.y, b4.z, b4.w};
#pragma unroll
            for (int i = 0; i < 4; ++i)
#pragma unroll
                for (int j = 0; j < 4; ++j)
                    acc[i][j] = fmaf(a[i], b[j], acc[i][j]);
        }
        __syncthreads();
    }
#pragma unroll
    for (int i = 0; i < 4; ++i)
#pragma unroll
        for (int j = 0; j < 4; ++j)
            Cb[(ll)(m0 + rt * 4 + i) * ldc + n0 + ct * 4 + j] = alpha * acc[i][j];
}

static inline void gemm(hipStream_t s, int M, int N, int K,
                        const float* A, int lda, ll sA,
                        const float* B, int ldb, ll sB,
                        float* C, int ldc, ll sC,
                        int batch, float alpha, bool tb)
{
    dim3 grid(N / 64, M / 64, batch);
    if (tb)
        hipLaunchKernelGGL((gemm_k<true>), grid, dim3(256), 0, s, A, B, C, K, lda, ldb, ldc, sA, sB, sC, alpha);
    else
        hipLaunchKernelGGL((gemm_k<false>), grid, dim3(256), 0, s, A, B, C, K, lda, ldb, ldc, sA, sB, sC, alpha);
}

// ===========================================================================
// Small kernels
// ===========================================================================
__global__ void embed_k(const float* __restrict__ x, const float* __restrict__ w,
                        const float* __restrict__ b, float* __restrict__ h)
{
    ll idx = (ll)blockIdx.x * 256 + threadIdx.x;
    int d = (int)(idx & 511);
    ll bn = idx >> 9;
    h[idx] = x[bn * 2] * w[d] + x[bn * 2 + 1] * w[512 + d] + b[d];
}

// LayerNorm, bf16 output; one block per row of 512
__global__ void __launch_bounds__(256)
ln_k(const float* __restrict__ X, const float* __restrict__ g,
     const float* __restrict__ bta, bh16* __restrict__ Y)
{
    const ll row = blockIdx.x;
    const float* x = X + row * 512;
    bh16* y = Y + row * 512;
    const int tid = threadIdx.x;
    float v0 = x[tid], v1 = x[tid + 256];
    float s = v0 + v1;
    float q = v0 * v0 + v1 * v1;
    __shared__ float sred[8];
    for (int o = 32; o; o >>= 1) { s += __shfl_down(s, o); q += __shfl_down(q, o); }
    const int lane = tid & 63, w = tid >> 6;
    if (lane == 0) { sred[w] = s; sred[4 + w] = q; }
    __syncthreads();
    float ssum = sred[0] + sred[1] + sred[2] + sred[3];
    float qsum = sred[4] + sred[5] + sred[6] + sred[7];
    float mu = ssum * (1.0f / 512.0f);
    float var = qsum * (1.0f / 512.0f) - mu * mu;
    float r = rsqrtf(var + 1e-5f);
    y[tid] = (bh16)((v0 - mu) * r * g[tid] + bta[tid]);
    y[tid + 256] = (bh16)((v1 - mu) * r * g[tid + 256] + bta[tid + 256]);
}

// weight f32 [R][C] -> bf16 [C][R]
__global__ void cvtT_k(const float* __restrict__ in, bh16* __restrict__ outp, int C, int R)
{
    int idx = blockIdx.x * 256 + threadIdx.x;   // C*R/8 threads
    int c = idx % C, rg = idx / C;
    bf16x8 o;
#pragma unroll
    for (int j = 0; j < 8; ++j) o[j] = (bh16)in[(ll)(rg * 8 + j) * C + c];
    *(bf16x8*)(outp + (ll)c * R + rg * 8) = o;
}

// scaled q scatter: qkv_b bf16 [4096,1536] -> Qb bf16 [h][4096][64]
__global__ void qstore_k(const bh16* __restrict__ qkvb, bh16* __restrict__ Qb)
{
    int idx = blockIdx.x * 256 + threadIdx.x;   // 262144
    int c8 = (idx & 63) * 8;
    int n = idx >> 6;
    bf16x8 v = *(const bf16x8*)(qkvb + (ll)n * 1536 + c8);
    bf16x8 o;
#pragma unroll
    for (int j = 0; j < 8; ++j) o[j] = (bh16)((float)v[j] * 0.125f);
    int h = c8 >> 6, d = c8 & 63;
    *(bf16x8*)(Qb + (ll)h * 262144 + n * 64 + d) = o;
}

// landmark means (f32 + bf16 outputs), per sample
__global__ void landmarksb_k(const bh16* __restrict__ qkvb,
                             float* __restrict__ QLb, float* __restrict__ KLb,
                             bh16* __restrict__ qlb, bh16* __restrict__ klb)
{
    int idx = blockIdx.x * 256 + threadIdx.x;   // 131072
    int d = idx & 63;
    int m = (idx >> 6) & 255;
    int h = idx >> 14;
    const bh16* base = qkvb + (ll)(m * LSEG) * 1536 + h * 64 + d;
    float sq = 0.f, sk = 0.f;
#pragma unroll
    for (int l = 0; l < LSEG; ++l) {
        sq += (float)base[(ll)l * 1536];
        sk += (float)base[(ll)l * 1536 + 512];
    }
    int o = h * 16384 + m * 64 + d;
    float qlv = sq * (0.0625f * 0.125f);
    float klv = sk * 0.0625f;
    QLb[o] = qlv; KLb[o] = klv;
    qlb[o] = (bh16)qlv; klb[o] = (bh16)klv;
}

// vT: qkv_b v-slice -> vt [h][64][4096] bf16 (coalesced reads, 16B scattered writes)
__global__ void vt_k(const bh16* __restrict__ qkvb, bh16* __restrict__ vt)
{
    int idx = blockIdx.x * 256 + threadIdx.x;   // 262144
    int d = idx & 63, ng = (idx >> 6) & 511, h = idx >> 15;
    const bh16* src = qkvb + 1024 + h * 64 + d;
    bf16x8 o;
#pragma unroll
    for (int j = 0; j < 8; ++j) o[j] = src[(ll)(ng * 8 + j) * 1536];
    *(bf16x8*)(vt + (ll)h * 262144 + (ll)d * 4096 + ng * 8) = o;
}

// wb f32 [bh][256][64] -> wbT bf16 [bh][64][256]
__global__ void wbt_k(const float* __restrict__ wb, bh16* __restrict__ wbt)
{
    int idx = blockIdx.x * 256 + threadIdx.x;   // 131072
    int d = idx & 63, kg = (idx >> 6) & 31, bhh = idx >> 11;
    const float* p = wb + (ll)bhh * 16384 + kg * 8 * 64 + d;
    bf16x8 o;
#pragma unroll
    for (int j = 0; j < 8; ++j) o[j] = (bh16)p[j * 64];
    *(bf16x8*)(wbt + (ll)bhh * 16384 + d * 256 + kg * 8) = o;
}

// reduce split-K partials: [8h][8s][16384] -> out[131072]
__global__ void a3vred_k(const float* __restrict__ part, float* __restrict__ outp)
{
    int idx = blockIdx.x * 256 + threadIdx.x;   // 131072
    int h = idx >> 14, o = idx & 16383;
    const float* p = part + (ll)h * 131072 + o;
    float s = 0.f;
#pragma unroll
    for (int j = 0; j < 8; ++j) s += p[j * 16384];
    outp[idx] = s;
}

// depthwise conv (bf16 in/out, f32 math)
__global__ void convb_k(const bh16* __restrict__ qkvb, const float* __restrict__ cw,
                        bh16* __restrict__ convb)
{
    int idx = blockIdx.x * 256 + threadIdx.x;   // 4096*512
    int c = idx & 511, n = idx >> 9, h = c >> 6;
    const bh16* v = qkvb + 1024 + c;
    float acc = 0.f;
#pragma unroll
    for (int j = 0; j < KER; ++j) {
        int nn = n + j - (KER / 2);
        if (nn >= 0 && nn < NVEC) acc += (float)v[(ll)nn * 1536] * cw[h * KER + j];
    }
    convb[(ll)n * 512 + c] = (bh16)acc;
}

// -------- softmax --------
__device__ __forceinline__ float blkmax(float m, float* red, int tid)
{
#pragma unroll
    for (int o = 32; o; o >>= 1) m = fmaxf(m, __shfl_down(m, o));
    if ((tid & 63) == 0) red[tid >> 6] = m;
    __syncthreads();
    m = fmaxf(fmaxf(red[0], red[1]), fmaxf(red[2], red[3]));
    __syncthreads();
    return m;
}
__device__ __forceinline__ float blksum(float s, float* red, int tid)
{
#pragma unroll
    for (int o = 32; o; o >>= 1) s += __shfl_down(s, o);
    if ((tid & 63) == 0) red[tid >> 6] = s;
    __syncthreads();
    s = red[0] + red[1] + red[2] + red[3];
    __syncthreads();
    return s;
}

// in-place bf16 row softmax (L == 4096 or 256)
__global__ void __launch_bounds__(256)
softmax_bf_k(bh16* __restrict__ X, int L)
{
    const ll row = blockIdx.x;
    bh16* x = X + row * (ll)L;
    const int tid = threadIdx.x;
    __shared__ float red[4];
    if (L == 4096) {
        float v[16];
        bf16x8 a = *(const bf16x8*)(x + tid * 8);
        bf16x8 b = *(const bf16x8*)(x + 2048 + tid * 8);
#pragma unroll
        for (int j = 0; j < 8; ++j) { v[j] = (float)a[j]; v[8 + j] = (float)b[j]; }
        float m = -1e30f;
#pragma unroll
        for (int j = 0; j < 16; ++j) m = fmaxf(m, v[j]);
        m = blkmax(m, red, tid);
        float s = 0.f;
#pragma unroll
        for (int j = 0; j < 16; ++j) { v[j] = __expf(v[j] - m); s += v[j]; }
        s = blksum(s, red, tid);
        float inv = 1.0f / s;
        bf16x8 oa, ob;
#pragma unroll
        for (int j = 0; j < 8; ++j) { oa[j] = (bh16)(v[j] * inv); ob[j] = (bh16)(v[8 + j] * inv); }
        *(bf16x8*)(x + tid * 8) = oa;
        *(bf16x8*)(x + 2048 + tid * 8) = ob;
    } else {
        float v = (float)x[tid];
        float m = blkmax(v, red, tid);
        float e = __expf(v - m);
        float s = blksum(e, red, tid);
        x[tid] = (bh16)(e / s);
    }
}

// f32 in-place row softmax (for AT2)
__global__ void __launch_bounds__(256)
softmax_k(float* __restrict__ X, int L)
{
    const ll row = blockIdx.x;
    float* x = X + row * (ll)L;
    const int tid = threadIdx.x;
    __shared__ float red[4];
    float v = x[tid];
    float m = blkmax(v, red, tid);
    float e = __expf(v - m);
    float s = blksum(e, red, tid);
    x[tid] = e / s;
}

// z0 = x^T / (max_rowsum * max_colsum)
__global__ void __launch_bounds__(256)
pinv_init_k(const float* __restrict__ X, float* __restrict__ Z)
{
    const ll bh = blockIdx.x;
    const float* x = X + bh * 65536;
    float* z = Z + bh * 65536;
    const int tid = threadIdx.x;
    float rs = 0.f, cs = 0.f;
    for (int j = 0; j < 256; ++j) {
        rs += fabsf(x[tid * 256 + j]);
        cs += fabsf(x[j * 256 + tid]);
    }
    __shared__ float rbuf[256], cbuf[256];
    rbuf[tid] = rs; cbuf[tid] = cs;
    __syncthreads();
    for (int o = 128; o; o >>= 1) {
        if (tid < o) {
            rbuf[tid] = fmaxf(rbuf[tid], rbuf[tid + o]);
            cbuf[tid] = fmaxf(cbuf[tid], cbuf[tid + o]);
        }
        __syncthreads();
    }
    float inv = 1.0f / (rbuf[0] * cbuf[0]);
    for (int e = tid; e < 65536; e += 256) {
        int i = e >> 8, j = e & 255;
        z[e] = x[j * 256 + i] * inv;
    }
}

// Y = alpha*I - X
__global__ void isub_k(const float* __restrict__ X, float* __restrict__ Y, float alpha)
{
    ll idx = (ll)blockIdx.x * 256 + threadIdx.x;
    int loc = (int)(idx & 65535);
    float v = -X[idx];
    if ((loc >> 8) == (loc & 255)) v += alpha;
    Y[idx] = v;
}

__global__ void final_init_k(const float* __restrict__ fb, float* __restrict__ out)
{
    int i = threadIdx.x;
    if (i < BB_ * NCLASS) out[i] = fb[i % NCLASS];
}

__global__ void __launch_bounds__(256)
final_gemv_k(const float* __restrict__ hbuf, const float* __restrict__ w,
             float* __restrict__ out)
{
    const int b = blockIdx.y;
    const int chunk = blockIdx.x;
    const int tid = threadIdx.x;
    const float* hrow = hbuf + (ll)b * (NVEC * DIM);
    float pc[NCLASS] = {};
    const int k0 = chunk * 8192;
    for (int e = 0; e < 32; ++e) {
        int k = k0 + e * 256 + tid;
        float hv = hrow[k];
        const float* wr = w + (ll)k * NCLASS;
#pragma unroll
        for (int c = 0; c < NCLASS; ++c) pc[c] += hv * wr[c];
    }
    __shared__ float red[256];
    for (int c = 0; c < NCLASS; ++c) {
        red[tid] = pc[c];
        __syncthreads();
        for (int o = 128; o; o >>= 1) {
            if (tid < o) red[tid] += red[tid + o];
            __syncthreads();
        }
        if (tid == 0) atomicAdd(out + b * NCLASS + c, red[0]);
        __syncthreads();
    }
}

// ===========================================================================
extern "C" void kernel_launch(void* const* d_in, const int* in_sizes, int n_in,
                              void* d_out, int out_size, void* d_ws, size_t ws_size,
                              hipStream_t stream)
{
    const float* x      = (const float*)d_in[0];
    const float* lin_w  = (const float*)d_in[1];
    const float* lin_b  = (const float*)d_in[2];
    const float* ln1_g  = (const float*)d_in[3];
    const float* ln1_b  = (const float*)d_in[4];
    const float* qkv_w  = (const float*)d_in[5];
    const float* out_w  = (const float*)d_in[6];
    const float* out_b  = (const float*)d_in[7];
    const float* conv_w = (const float*)d_in[8];
    const float* ln2_g  = (const float*)d_in[9];
    const float* ln2_b  = (const float*)d_in[10];
    const float* ff1_w  = (const float*)d_in[11];
    const float* ff1_b  = (const float*)d_in[12];
    const float* ff2_w  = (const float*)d_in[13];
    const float* ff2_b  = (const float*)d_in[14];
    const float* final_w = (const float*)d_in[15];
    const float* final_b = (const float*)d_in[16];
    float* out = (float*)d_out;
    float* ws  = (float*)d_ws;

    // ---- workspace layout (f32 units), total 53,477,376 f32 = 214 MB ----
    float* H    = ws;                                  // [8][4096][512] f32
    bh16*  Qbf  = (bh16*)(ws + 16777216);              // [8][8h][4096][64] bf16
    float* S    = ws + 25165824;                       // 20,971,520 f32 scratch
    float* QL   = ws + 46137344;                       // [64bh][256][64] f32
    float* KL   = ws + 47185920;
    bh16*  qlbf = (bh16*)(ws + 48234496);              // [64bh][256][64] bf16
    bh16*  klbf = (bh16*)(ws + 48758784);
    float* A3V  = ws + 49283072;                       // [64bh][256][64] f32
    float* WB   = ws + 50331648;                       // [64bh][256][64] f32
    bh16*  WBT  = (bh16*)(ws + 51380224);              // [64bh][64][256] bf16
    bh16*  WQT  = (bh16*)(ws + 51904512);              // [1536][512] bf16
    bh16*  WOT  = (bh16*)(ws + 52297728);              // [512][512] bf16
    bh16*  F1WT = (bh16*)(ws + 52428800);              // [2048][512] bf16
    bh16*  F2WT = (bh16*)(ws + 52953088);              // [512][2048] bf16
    if (ws_size < 53477376ULL * 4) return;

    // S aliases (time-sliced)
    bh16*  XLNbf  = (bh16*)(S);                        // [4096][512] bf16
    bh16*  QKVbf  = (bh16*)(S + 1048576);              // [4096][1536] bf16
    bh16*  VTb    = (bh16*)(S + 4194304);              // [8h][64][4096] bf16
    bh16*  ATT3bf = (bh16*)(S + 5242880);              // [8h][256][4096] bf16
    float* A3Vp   = S + 9437184;                       // [8h][8s][256][64] f32
    bh16*  CONVbf = (bh16*)(S + 10485760);             // [4096][512] bf16
    float* Z0 = S;
    float* Z1 = S + 4194304;
    float* T1 = S + 8388608;
    float* T2 = S + 12582912;
    float* AT2 = S + 16777216;                         // [64bh][256][256] f32
    bh16*  ATT1bf = (bh16*)S;                          // [8h][4096][256] bf16
    bh16*  AOUTbf = (bh16*)(S + 4194304);              // [4096][512] bf16
    bh16*  HIDbf  = (bh16*)(S + 1048576);              // [4096][2048] bf16

    // embed
    hipLaunchKernelGGL(embed_k, dim3(65536), dim3(256), 0, stream, x, lin_w, lin_b, H);

    for (int i = 0; i < DEPTH; ++i) {
        const float* wq  = qkv_w + (ll)i * 512 * 1536;
        const float* wo  = out_w + (ll)i * 512 * 512;
        const float* bo  = out_b + (ll)i * 512;
        const float* cw  = conv_w + (ll)i * HEADS * KER;
        const float* g1  = ln1_g + (ll)i * 512;
        const float* b1  = ln1_b + (ll)i * 512;
        const float* g2  = ln2_g + (ll)i * 512;
        const float* b2  = ln2_b + (ll)i * 512;
        const float* f1w = ff1_w + (ll)i * 512 * 2048;
        const float* f1b = ff1_b + (ll)i * 2048;
        const float* f2w = ff2_w + (ll)i * 2048 * 512;
        const float* f2b = ff2_b + (ll)i * 512;

        // weight convert+transpose (bf16 [N][K])
        hipLaunchKernelGGL(cvtT_k, dim3(384), dim3(256), 0, stream, wq, WQT, 1536, 512);
        hipLaunchKernelGGL(cvtT_k, dim3(128), dim3(256), 0, stream, wo, WOT, 512, 512);
        hipLaunchKernelGGL(cvtT_k, dim3(512), dim3(256), 0, stream, f1w, F1WT, 2048, 512);
        hipLaunchKernelGGL(cvtT_k, dim3(512), dim3(256), 0, stream, f2w, F2WT, 512, 2048);

        // ---- Phase 1: per sample ----
        for (int b = 0; b < BB_; ++b) {
            float* Hb = H + (ll)b * 2097152;
            hipLaunchKernelGGL(ln_k, dim3(4096), dim3(256), 0, stream, Hb, g1, b1, XLNbf);
            // qkv [4096,512]@[512,1536] -> bf16
            mgemm<2,2,false,false,true>(stream, 4096, 1536, 512, XLNbf, 512, WQT, 512,
                QKVbf, 1536, nullptr, 1, 1, 0,0, 0,0, 0,0);
            hipLaunchKernelGGL(qstore_k, dim3(1024), dim3(256), 0, stream,
                               QKVbf, Qbf + (ll)b * 2097152);
            hipLaunchKernelGGL(landmarksb_k, dim3(512), dim3(256), 0, stream, QKVbf,
                               QL + (ll)b * 131072, KL + (ll)b * 131072,
                               qlbf + (ll)b * 131072, klbf + (ll)b * 131072);
            hipLaunchKernelGGL(vt_k, dim3(1024), dim3(256), 0, stream, QKVbf, VTb);
            // attn3 scores: per head, [256,64]@[64 x 4096 rows of k]
            mgemm<2,2,false,false,true>(stream, 256, 4096, 64,
                qlbf + (ll)b * 131072, 64, QKVbf + 512, 1536,
                ATT3bf, 4096, nullptr, 8, 8, 0, 16384, 0, 64, 0, 1048576);
            hipLaunchKernelGGL(softmax_bf_k, dim3(2048), dim3(256), 0, stream, ATT3bf, 4096);
            // a3v split-K (z = h*8 + s): [256,4096]@vT[64,4096]^T, K chunk 512
            mgemm<4,1,false,false,false>(stream, 256, 64, 512,
                ATT3bf, 4096, VTb, 4096,
                A3Vp, 64, nullptr, 64, 8, 1048576, 512, 262144, 512, 131072, 16384);
            hipLaunchKernelGGL(a3vred_k, dim3(512), dim3(256), 0, stream,
                               A3Vp, A3V + (ll)b * 131072);
            // depthwise conv of v, then H += conv @ Wo (no bias here)
            hipLaunchKernelGGL(convb_k, dim3(8192), dim3(256), 0, stream, QKVbf, cw, CONVbf);
            mgemm<2,2,false,true,false>(stream, 4096, 512, 512, CONVbf, 512, WOT, 512,
                Hb, 512, nullptr, 1, 1, 0,0, 0,0, 0,0);
        }

        // ---- Phase 2: pinv (f32, batched 64) ----
        gemm(stream, 256, 256, 64, QL, 64, 16384, KL, 64, 16384,
             AT2, 256, 65536, 64, 1.0f, true);
        hipLaunchKernelGGL(softmax_k, dim3(16384), dim3(256), 0, stream, AT2, 256);
        hipLaunchKernelGGL(pinv_init_k, dim3(64), dim3(256), 0, stream, AT2, Z0);
        float* zc = Z0; float* zn = Z1;
        for (int it = 0; it < ITERS; ++it) {
            gemm(stream, 256, 256, 256, AT2, 256, 65536, zc, 256, 65536,
                 T1, 256, 65536, 64, 1.0f, false);
            hipLaunchKernelGGL(isub_k, dim3(16384), dim3(256), 0, stream, T1, T2, 7.0f);
            gemm(stream, 256, 256, 256, T1, 256, 65536, T2, 256, 65536,
                 zn, 256, 65536, 64, 1.0f, false);
            hipLaunchKernelGGL(isub_k, dim3(16384), dim3(256), 0, stream, zn, zn, 15.0f);
            gemm(stream, 256, 256, 256, T1, 256, 65536, zn, 256, 65536,
                 T2, 256, 65536, 64, 1.0f, false);
            hipLaunchKernelGGL(isub_k, dim3(16384), dim3(256), 0, stream, T2, T2, 13.0f);
            gemm(stream, 256, 256, 256, zc, 256, 65536, T2, 256, 65536,
                 zn, 256, 65536, 64, 0.25f, false);
            float* t = zc; zc = zn; zn = t;
        }
        gemm(stream, 256, 64, 256, zc, 256, 65536, A3V, 64, 16384,
             WB, 64, 16384, 64, 1.0f, false);
        hipLaunchKernelGGL(wbt_k, dim3(512), dim3(256), 0, stream, WB, WBT);

        // ---- Phase 3: per sample ----
        for (int b = 0; b < BB_; ++b) {
            float* Hb = H + (ll)b * 2097152;
            // attn1 = q @ kl^T  [4096,64]@[256,64]^T per head
            mgemm<2,2,false,false,true>(stream, 4096, 256, 64,
                Qbf + (ll)b * 2097152, 64, klbf + (ll)b * 131072, 64,
                ATT1bf, 256, nullptr, 8, 8, 0, 262144, 0, 16384, 0, 1048576);
            hipLaunchKernelGGL(softmax_bf_k, dim3(32768), dim3(256), 0, stream, ATT1bf, 256);
            // aout = attn1 @ wb   [4096,256]@wbT[64,256]^T per head, heads into cols
            mgemm<4,1,false,false,true>(stream, 4096, 64, 256,
                ATT1bf, 256, WBT + (ll)b * 131072, 256,
                AOUTbf, 512, nullptr, 8, 8, 0, 1048576, 0, 16384, 0, 64);
            // H += aout @ Wo + bo
            mgemm<2,2,false,true,false>(stream, 4096, 512, 512, AOUTbf, 512, WOT, 512,
                Hb, 512, bo, 1, 1, 0,0, 0,0, 0,0);
        }

        // ---- FFN: per sample ----
        for (int b = 0; b < BB_; ++b) {
            float* Hb = H + (ll)b * 2097152;
            hipLaunchKernelGGL(ln_k, dim3(4096), dim3(256), 0, stream, Hb, g2, b2, XLNbf);
            mgemm<2,2,true,false,true>(stream, 4096, 2048, 512, XLNbf, 512, F1WT, 512,
                HIDbf, 2048, f1b, 1, 1, 0,0, 0,0, 0,0);
            mgemm<2,2,false,true,false>(stream, 4096, 512, 2048, HIDbf, 2048, F2WT, 2048,
                Hb, 512, f2b, 1, 1, 0,0, 0,0, 0,0);
        }
    }

    hipLaunchKernelGGL(final_init_k, dim3(1), dim3(128), 0, stream, final_b, out);
    hipLaunchKernelGGL(final_gemv_k, dim3(256, BB_), dim3(256), 0, stream, H, final_w, out);
}

// Round 7
// 5788.614 us; speedup vs baseline: 2.9372x; 1.2412x over previous
//
#include <hip/hip_runtime.h>
#include <hip/hip_bf16.h>

// Problem constants
#define BB_ 8
#define NVEC 4096
#define DIM 512
#define HEADS 8
#define DH 64
#define MM_ 256
#define ITERS 6
#define DEPTH 2
#define NCLASS 10
#define KER 33
#define INNER 512
#define LSEG 16  // NVEC / MM_

typedef long long ll;
typedef __bf16 bh16;
typedef __attribute__((ext_vector_type(8))) __bf16 bf16x8;
typedef __attribute__((ext_vector_type(4))) float f32x4;

// ===========================================================================
// MFMA bf16 GEMM. TRB=0 (TN): C = A[M,K] @ B_t[N,K]^T. TRB=1 (NN):
// C = A[M,K] @ B[K,N] (B transposed into LDS during staging).
// Tile BM=WR*64 x BN=WC*64, BK=32, 256 threads = 4 waves (WR*WC==4).
// Epilogue: v = alpha*acc (+bias[col]) (+diagv if row==col) (+GELU).
// DUAL: C gets raw acc, C2 gets diagv*I - acc (both bf16).
// Two-level batch: z -> bo=z/BI (stride sXo), bi=z%BI (stride sXi).
// ===========================================================================
template<int WR, int WC, bool TRB, bool GELU_ACT, bool RESID, bool BF16OUT, bool DUAL>
__global__ void __launch_bounds__(256)
mgemm_k(const bh16* __restrict__ A, const bh16* __restrict__ B,
        const float* __restrict__ bias, void* __restrict__ Cv, void* __restrict__ C2v,
        int K, int lda, int ldb, int ldc,
        int BI, ll sAo, ll sAi, ll sBo, ll sBi, ll sCo, ll sCi,
        float alpha, float diagv)
{
    constexpr int BM = WR * 64, BN = WC * 64;
    const int bz = blockIdx.z;
    const int bo = bz / BI, bi = bz % BI;
    const bh16* Ab = A + bo * sAo + (ll)bi * sAi;
    const bh16* Bb = B + bo * sBo + (ll)bi * sBi;
    const ll coff = bo * sCo + (ll)bi * sCi;
    const int m0 = blockIdx.y * BM;
    const int n0 = blockIdx.x * BN;
    const int tid = threadIdx.x;
    const int lane = tid & 63;
    const int wave = tid >> 6;
    const int wr = wave / WC, wc = wave % WC;

    __shared__ bh16 Al[BM * 32];
    __shared__ bh16 Bl[BN * 32];

    f32x4 acc[4][4];
#pragma unroll
    for (int i = 0; i < 4; ++i)
#pragma unroll
        for (int j = 0; j < 4; ++j) acc[i][j] = (f32x4){0.f, 0.f, 0.f, 0.f};

    const int srow = tid >> 2;   // 0..63
    const int ssl  = tid & 3;    // 16B slot

    const int rsel  = ((lane & 15) >> 1) & 3;
    const int kslot = lane >> 4;

    for (int k0 = 0; k0 < K; k0 += 32) {
        __syncthreads();
#pragma unroll
        for (int i = 0; i < BM / 64; ++i) {
            int row = i * 64 + srow;
            int sl = ssl ^ ((row >> 1) & 3);
            bf16x8 v = *(const bf16x8*)(Ab + (ll)(m0 + row) * lda + k0 + ssl * 8);
            *(bf16x8*)(Al + row * 32 + sl * 8) = v;
        }
        if (!TRB) {
#pragma unroll
            for (int i = 0; i < BN / 64; ++i) {
                int row = i * 64 + srow;
                int sl = ssl ^ ((row >> 1) & 3);
                bf16x8 v = *(const bf16x8*)(Bb + (ll)(n0 + row) * ldb + k0 + ssl * 8);
                *(bf16x8*)(Bl + row * 32 + sl * 8) = v;
            }
        } else {
            // B stored [K][N]; transpose into LDS [n][k] with matching swizzle
            const int bk = tid >> 3;                 // 0..31
            const int nb0 = (tid & 7) * (BN / 8);
#pragma unroll
            for (int v8 = 0; v8 < BN / 64; ++v8) {
                int nb = nb0 + v8 * 8;
                bf16x8 v = *(const bf16x8*)(Bb + (ll)(k0 + bk) * ldb + n0 + nb);
#pragma unroll
                for (int j = 0; j < 8; ++j) {
                    int n = nb + j;
                    int sl = (bk >> 3) ^ ((n >> 1) & 3);
                    Bl[n * 32 + sl * 8 + (bk & 7)] = v[j];
                }
            }
        }
        __syncthreads();

        bf16x8 af[4], bfr[4];
#pragma unroll
        for (int mi = 0; mi < 4; ++mi) {
            int row = wr * 64 + mi * 16 + (lane & 15);
            af[mi] = *(const bf16x8*)(Al + row * 32 + (kslot ^ rsel) * 8);
        }
#pragma unroll
        for (int ni = 0; ni < 4; ++ni) {
            int row = wc * 64 + ni * 16 + (lane & 15);
            bfr[ni] = *(const bf16x8*)(Bl + row * 32 + (kslot ^ rsel) * 8);
        }
#pragma unroll
        for (int mi = 0; mi < 4; ++mi)
#pragma unroll
            for (int ni = 0; ni < 4; ++ni)
                acc[mi][ni] = __builtin_amdgcn_mfma_f32_16x16x32_bf16(
                    af[mi], bfr[ni], acc[mi][ni], 0, 0, 0);
    }

#pragma unroll
    for (int mi = 0; mi < 4; ++mi) {
#pragma unroll
        for (int ni = 0; ni < 4; ++ni) {
            const int colg = n0 + wc * 64 + ni * 16 + (lane & 15);
            const float bia = (!DUAL && bias) ? bias[colg] : 0.f;
#pragma unroll
            for (int r = 0; r < 4; ++r) {
                const int rowg = m0 + wr * 64 + mi * 16 + (lane >> 4) * 4 + r;
                const float a = acc[mi][ni][r];
                const ll off = coff + (ll)rowg * ldc + colg;
                if (DUAL) {
                    ((bh16*)Cv)[off] = (bh16)a;
                    float w = ((rowg == colg) ? diagv : 0.f) - a;
                    ((bh16*)C2v)[off] = (bh16)w;
                } else {
                    float v = alpha * a + bia;
                    if (diagv != 0.f && rowg == colg) v += diagv;
                    if (GELU_ACT) {
                        float t = tanhf(0.7978845608f * (v + 0.044715f * v * v * v));
                        v = 0.5f * v * (1.0f + t);
                    }
                    if (BF16OUT) {
                        ((bh16*)Cv)[off] = (bh16)v;
                    } else {
                        float* p = (float*)Cv + off;
                        float o = v;
                        if (RESID) o += *p;
                        *p = o;
                    }
                }
            }
        }
    }
}

template<int WR, int WC, bool TRB, bool G, bool R, bool BO, bool D>
static inline void mg(hipStream_t s, int M, int N, int K,
                      const bh16* A, int lda, const bh16* B, int ldb,
                      void* C, int ldc, void* C2, const float* bias,
                      int batch, int BI,
                      ll sAo, ll sAi, ll sBo, ll sBi, ll sCo, ll sCi,
                      float alpha, float diagv)
{
    dim3 grid(N / (WC * 64), M / (WR * 64), batch);
    hipLaunchKernelGGL((mgemm_k<WR, WC, TRB, G, R, BO, D>), grid, dim3(256), 0, s,
                       A, B, bias, C, C2, K, lda, ldb, ldc, BI,
                       sAo, sAi, sBo, sBi, sCo, sCi, alpha, diagv);
}

// ===========================================================================
// Small kernels
// ===========================================================================
__global__ void embed_k(const float* __restrict__ x, const float* __restrict__ w,
                        const float* __restrict__ b, float* __restrict__ h)
{
    ll idx = (ll)blockIdx.x * 256 + threadIdx.x;
    int d = (int)(idx & 511);
    ll bn = idx >> 9;
    h[idx] = x[bn * 2] * w[d] + x[bn * 2 + 1] * w[512 + d] + b[d];
}

// LayerNorm, bf16 output; one block per row of 512
__global__ void __launch_bounds__(256)
ln_k(const float* __restrict__ X, const float* __restrict__ g,
     const float* __restrict__ bta, bh16* __restrict__ Y)
{
    const ll row = blockIdx.x;
    const float* x = X + row * 512;
    bh16* y = Y + row * 512;
    const int tid = threadIdx.x;
    float v0 = x[tid], v1 = x[tid + 256];
    float s = v0 + v1;
    float q = v0 * v0 + v1 * v1;
    __shared__ float sred[8];
    for (int o = 32; o; o >>= 1) { s += __shfl_down(s, o); q += __shfl_down(q, o); }
    const int lane = tid & 63, w = tid >> 6;
    if (lane == 0) { sred[w] = s; sred[4 + w] = q; }
    __syncthreads();
    float ssum = sred[0] + sred[1] + sred[2] + sred[3];
    float qsum = sred[4] + sred[5] + sred[6] + sred[7];
    float mu = ssum * (1.0f / 512.0f);
    float var = qsum * (1.0f / 512.0f) - mu * mu;
    float r = rsqrtf(var + 1e-5f);
    y[tid] = (bh16)((v0 - mu) * r * g[tid] + bta[tid]);
    y[tid + 256] = (bh16)((v1 - mu) * r * g[tid + 256] + bta[tid + 256]);
}

// weight f32 [R][C] -> bf16 [C][R]
__global__ void cvtT_k(const float* __restrict__ in, bh16* __restrict__ outp, int C, int R)
{
    int idx = blockIdx.x * 256 + threadIdx.x;   // C*R/8 threads
    int c = idx % C, rg = idx / C;
    bf16x8 o;
#pragma unroll
    for (int j = 0; j < 8; ++j) o[j] = (bh16)in[(ll)(rg * 8 + j) * C + c];
    *(bf16x8*)(outp + (ll)c * R + rg * 8) = o;
}

// scaled q scatter: qkv_b bf16 [4096,1536] -> Qb bf16 [h][4096][64]
__global__ void qstore_k(const bh16* __restrict__ qkvb, bh16* __restrict__ Qb)
{
    int idx = blockIdx.x * 256 + threadIdx.x;   // 262144
    int c8 = (idx & 63) * 8;
    int n = idx >> 6;
    bf16x8 v = *(const bf16x8*)(qkvb + (ll)n * 1536 + c8);
    bf16x8 o;
#pragma unroll
    for (int j = 0; j < 8; ++j) o[j] = (bh16)((float)v[j] * 0.125f);
    int h = c8 >> 6, d = c8 & 63;
    *(bf16x8*)(Qb + (ll)h * 262144 + n * 64 + d) = o;
}

// landmark means (bf16 outputs), per sample; ql pre-scaled by DH^-0.5
__global__ void landmarksb_k(const bh16* __restrict__ qkvb,
                             bh16* __restrict__ qlb, bh16* __restrict__ klb)
{
    int idx = blockIdx.x * 256 + threadIdx.x;   // 131072
    int d = idx & 63;
    int m = (idx >> 6) & 255;
    int h = idx >> 14;
    const bh16* base = qkvb + (ll)(m * LSEG) * 1536 + h * 64 + d;
    float sq = 0.f, sk = 0.f;
#pragma unroll
    for (int l = 0; l < LSEG; ++l) {
        sq += (float)base[(ll)l * 1536];
        sk += (float)base[(ll)l * 1536 + 512];
    }
    int o = h * 16384 + m * 64 + d;
    qlb[o] = (bh16)(sq * (0.0625f * 0.125f));
    klb[o] = (bh16)(sk * 0.0625f);
}

// vT: qkv_b v-slice -> vt [h][64][4096] bf16
__global__ void vt_k(const bh16* __restrict__ qkvb, bh16* __restrict__ vt)
{
    int idx = blockIdx.x * 256 + threadIdx.x;   // 262144
    int d = idx & 63, ng = (idx >> 6) & 511, h = idx >> 15;
    const bh16* src = qkvb + 1024 + h * 64 + d;
    bf16x8 o;
#pragma unroll
    for (int j = 0; j < 8; ++j) o[j] = src[(ll)(ng * 8 + j) * 1536];
    *(bf16x8*)(vt + (ll)h * 262144 + (ll)d * 4096 + ng * 8) = o;
}

// wb bf16 [bh][256][64] -> wbT bf16 [bh][64][256]
__global__ void wbt_k(const bh16* __restrict__ wb, bh16* __restrict__ wbt)
{
    int idx = blockIdx.x * 256 + threadIdx.x;   // 131072
    int d = idx & 63, kg = (idx >> 6) & 31, bhh = idx >> 11;
    const bh16* p = wb + (ll)bhh * 16384 + kg * 8 * 64 + d;
    bf16x8 o;
#pragma unroll
    for (int j = 0; j < 8; ++j) o[j] = p[j * 64];
    *(bf16x8*)(wbt + (ll)bhh * 16384 + d * 256 + kg * 8) = o;
}

// reduce split-K partials: [8h][8s][16384] f32 -> bf16 out[131072]
__global__ void a3vred_k(const float* __restrict__ part, bh16* __restrict__ outp)
{
    int idx = blockIdx.x * 256 + threadIdx.x;   // 131072
    int h = idx >> 14, o = idx & 16383;
    const float* p = part + (ll)h * 131072 + o;
    float s = 0.f;
#pragma unroll
    for (int j = 0; j < 8; ++j) s += p[j * 16384];
    outp[idx] = (bh16)s;
}

// depthwise conv (bf16 in/out, f32 math)
__global__ void convb_k(const bh16* __restrict__ qkvb, const float* __restrict__ cw,
                        bh16* __restrict__ convb)
{
    int idx = blockIdx.x * 256 + threadIdx.x;   // 4096*512
    int c = idx & 511, n = idx >> 9, h = c >> 6;
    const bh16* v = qkvb + 1024 + c;
    float acc = 0.f;
#pragma unroll
    for (int j = 0; j < KER; ++j) {
        int nn = n + j - (KER / 2);
        if (nn >= 0 && nn < NVEC) acc += (float)v[(ll)nn * 1536] * cw[h * KER + j];
    }
    convb[(ll)n * 512 + c] = (bh16)acc;
}

// -------- softmax helpers --------
__device__ __forceinline__ float blkmax(float m, float* red, int tid)
{
#pragma unroll
    for (int o = 32; o; o >>= 1) m = fmaxf(m, __shfl_down(m, o));
    if ((tid & 63) == 0) red[tid >> 6] = m;
    __syncthreads();
    m = fmaxf(fmaxf(red[0], red[1]), fmaxf(red[2], red[3]));
    __syncthreads();
    return m;
}
__device__ __forceinline__ float blksum(float s, float* red, int tid)
{
#pragma unroll
    for (int o = 32; o; o >>= 1) s += __shfl_down(s, o);
    if ((tid & 63) == 0) red[tid >> 6] = s;
    __syncthreads();
    s = red[0] + red[1] + red[2] + red[3];
    __syncthreads();
    return s;
}

// in-place bf16 row softmax (L == 4096 or 256)
__global__ void __launch_bounds__(256)
softmax_bf_k(bh16* __restrict__ X, int L)
{
    const ll row = blockIdx.x;
    bh16* x = X + row * (ll)L;
    const int tid = threadIdx.x;
    __shared__ float red[4];
    if (L == 4096) {
        float v[16];
        bf16x8 a = *(const bf16x8*)(x + tid * 8);
        bf16x8 b = *(const bf16x8*)(x + 2048 + tid * 8);
#pragma unroll
        for (int j = 0; j < 8; ++j) { v[j] = (float)a[j]; v[8 + j] = (float)b[j]; }
        float m = -1e30f;
#pragma unroll
        for (int j = 0; j < 16; ++j) m = fmaxf(m, v[j]);
        m = blkmax(m, red, tid);
        float s = 0.f;
#pragma unroll
        for (int j = 0; j < 16; ++j) { v[j] = __expf(v[j] - m); s += v[j]; }
        s = blksum(s, red, tid);
        float inv = 1.0f / s;
        bf16x8 oa, ob;
#pragma unroll
        for (int j = 0; j < 8; ++j) { oa[j] = (bh16)(v[j] * inv); ob[j] = (bh16)(v[8 + j] * inv); }
        *(bf16x8*)(x + tid * 8) = oa;
        *(bf16x8*)(x + 2048 + tid * 8) = ob;
    } else {
        float v = (float)x[tid];
        float m = blkmax(v, red, tid);
        float e = __expf(v - m);
        float s = blksum(e, red, tid);
        x[tid] = (bh16)(e / s);
    }
}

// z0 = x^T / (max_rowsum * max_colsum), bf16 in/out, f32 math
__global__ void __launch_bounds__(256)
pinv_init_k(const bh16* __restrict__ X, bh16* __restrict__ Z)
{
    const ll bh = blockIdx.x;
    const bh16* x = X + bh * 65536;
    bh16* z = Z + bh * 65536;
    const int tid = threadIdx.x;
    float rs = 0.f, cs = 0.f;
    for (int j = 0; j < 256; ++j) {
        rs += fabsf((float)x[tid * 256 + j]);
        cs += fabsf((float)x[j * 256 + tid]);
    }
    __shared__ float rbuf[256], cbuf[256];
    rbuf[tid] = rs; cbuf[tid] = cs;
    __syncthreads();
    for (int o = 128; o; o >>= 1) {
        if (tid < o) {
            rbuf[tid] = fmaxf(rbuf[tid], rbuf[tid + o]);
            cbuf[tid] = fmaxf(cbuf[tid], cbuf[tid + o]);
        }
        __syncthreads();
    }
    float inv = 1.0f / (rbuf[0] * cbuf[0]);
    for (int e = tid; e < 65536; e += 256) {
        int i = e >> 8, j = e & 255;
        z[e] = (bh16)((float)x[j * 256 + i] * inv);
    }
}

__global__ void final_init_k(const float* __restrict__ fb, float* __restrict__ out)
{
    int i = threadIdx.x;
    if (i < BB_ * NCLASS) out[i] = fb[i % NCLASS];
}

__global__ void __launch_bounds__(256)
final_gemv_k(const float* __restrict__ hbuf, const float* __restrict__ w,
             float* __restrict__ out)
{
    const int b = blockIdx.y;
    const int chunk = blockIdx.x;
    const int tid = threadIdx.x;
    const float* hrow = hbuf + (ll)b * (NVEC * DIM);
    float pc[NCLASS] = {};
    const int k0 = chunk * 8192;
    for (int e = 0; e < 32; ++e) {
        int k = k0 + e * 256 + tid;
        float hv = hrow[k];
        const float* wr = w + (ll)k * NCLASS;
#pragma unroll
        for (int c = 0; c < NCLASS; ++c) pc[c] += hv * wr[c];
    }
    __shared__ float red[256];
    for (int c = 0; c < NCLASS; ++c) {
        red[tid] = pc[c];
        __syncthreads();
        for (int o = 128; o; o >>= 1) {
            if (tid < o) red[tid] += red[tid + o];
            __syncthreads();
        }
        if (tid == 0) atomicAdd(out + b * NCLASS + c, red[0]);
        __syncthreads();
    }
}

// ===========================================================================
extern "C" void kernel_launch(void* const* d_in, const int* in_sizes, int n_in,
                              void* d_out, int out_size, void* d_ws, size_t ws_size,
                              hipStream_t stream)
{
    const float* x      = (const float*)d_in[0];
    const float* lin_w  = (const float*)d_in[1];
    const float* lin_b  = (const float*)d_in[2];
    const float* ln1_g  = (const float*)d_in[3];
    const float* ln1_b  = (const float*)d_in[4];
    const float* qkv_w  = (const float*)d_in[5];
    const float* out_w  = (const float*)d_in[6];
    const float* out_b  = (const float*)d_in[7];
    const float* conv_w = (const float*)d_in[8];
    const float* ln2_g  = (const float*)d_in[9];
    const float* ln2_b  = (const float*)d_in[10];
    const float* ff1_w  = (const float*)d_in[11];
    const float* ff1_b  = (const float*)d_in[12];
    const float* ff2_w  = (const float*)d_in[13];
    const float* ff2_b  = (const float*)d_in[14];
    const float* final_w = (const float*)d_in[15];
    const float* final_b = (const float*)d_in[16];
    float* out = (float*)d_out;
    float* ws  = (float*)d_ws;

    // ---- workspace layout (f32 units), total 50,331,648 f32 = 201 MB ----
    float* H    = ws;                                  // [8][4096][512] f32
    bh16*  Qbf  = (bh16*)(ws + 16777216);              // [8][8h][4096][64] bf16
    float* S    = ws + 25165824;                       // 20,971,520 f32 scratch
    bh16*  qlbf = (bh16*)(ws + 46137344);              // [64bh][256][64] bf16
    bh16*  klbf = (bh16*)(ws + 46661632);
    bh16*  A3Vb = (bh16*)(ws + 47185920);              // [64bh][256][64] bf16
    bh16*  WBb  = (bh16*)(ws + 47710208);              // [64bh][256][64] bf16
    bh16*  WBT  = (bh16*)(ws + 48234496);              // [64bh][64][256] bf16
    bh16*  WQT  = (bh16*)(ws + 48758784);              // [1536][512] bf16
    bh16*  WOT  = (bh16*)(ws + 49152000);              // [512][512] bf16
    bh16*  F1WT = (bh16*)(ws + 49283072);              // [2048][512] bf16
    bh16*  F2WT = (bh16*)(ws + 49807360);              // [512][2048] bf16
    if (ws_size < 50331648ULL * 4) return;

    // S aliases — phase 1 (per sample)
    bh16*  XLNbf  = (bh16*)(S);                        // [4096][512] bf16
    bh16*  QKVbf  = (bh16*)(S + 1048576);              // [4096][1536] bf16
    bh16*  VTb    = (bh16*)(S + 4194304);              // [8h][64][4096] bf16
    bh16*  ATT3bf = (bh16*)(S + 5242880);              // [8h][256][4096] bf16
    float* A3Vp   = S + 9437184;                       // [8h][8s][256][64] f32
    bh16*  CONVbf = (bh16*)(S + 10485760);             // [4096][512] bf16
    // S aliases — phase 2 (pinv, bf16 buffers [64bh][256][256])
    bh16*  Xbf = (bh16*)(S);
    bh16*  Z0  = (bh16*)(S + 2097152);
    bh16*  Z1  = (bh16*)(S + 4194304);
    bh16*  T1  = (bh16*)(S + 6291456);
    bh16*  T2  = (bh16*)(S + 8388608);
    // S aliases — phase 3
    bh16*  ATT1bf = (bh16*)S;                          // [8h][4096][256] bf16
    bh16*  AOUTbf = (bh16*)(S + 4194304);              // [4096][512] bf16
    // S aliases — FFN
    bh16*  HIDbf  = (bh16*)(S + 1048576);              // [4096][2048] bf16

    // embed
    hipLaunchKernelGGL(embed_k, dim3(65536), dim3(256), 0, stream, x, lin_w, lin_b, H);

    for (int i = 0; i < DEPTH; ++i) {
        const float* wq  = qkv_w + (ll)i * 512 * 1536;
        const float* wo  = out_w + (ll)i * 512 * 512;
        const float* bo  = out_b + (ll)i * 512;
        const float* cw  = conv_w + (ll)i * HEADS * KER;
        const float* g1  = ln1_g + (ll)i * 512;
        const float* b1  = ln1_b + (ll)i * 512;
        const float* g2  = ln2_g + (ll)i * 512;
        const float* b2  = ln2_b + (ll)i * 512;
        const float* f1w = ff1_w + (ll)i * 512 * 2048;
        const float* f1b = ff1_b + (ll)i * 2048;
        const float* f2w = ff2_w + (ll)i * 2048 * 512;
        const float* f2b = ff2_b + (ll)i * 512;

        // weight convert+transpose (bf16 [N][K])
        hipLaunchKernelGGL(cvtT_k, dim3(384), dim3(256), 0, stream, wq, WQT, 1536, 512);
        hipLaunchKernelGGL(cvtT_k, dim3(128), dim3(256), 0, stream, wo, WOT, 512, 512);
        hipLaunchKernelGGL(cvtT_k, dim3(512), dim3(256), 0, stream, f1w, F1WT, 2048, 512);
        hipLaunchKernelGGL(cvtT_k, dim3(512), dim3(256), 0, stream, f2w, F2WT, 512, 2048);

        // ---- Phase 1: per sample ----
        for (int b = 0; b < BB_; ++b) {
            float* Hb = H + (ll)b * 2097152;
            hipLaunchKernelGGL(ln_k, dim3(4096), dim3(256), 0, stream, Hb, g1, b1, XLNbf);
            // qkv [4096,512]@[512,1536] -> bf16
            mg<2,2,0,0,0,1,0>(stream, 4096, 1536, 512, XLNbf, 512, WQT, 512,
                QKVbf, 1536, nullptr, nullptr, 1, 1, 0,0, 0,0, 0,0, 1.f, 0.f);
            hipLaunchKernelGGL(qstore_k, dim3(1024), dim3(256), 0, stream,
                               QKVbf, Qbf + (ll)b * 2097152);
            hipLaunchKernelGGL(landmarksb_k, dim3(512), dim3(256), 0, stream, QKVbf,
                               qlbf + (ll)b * 131072, klbf + (ll)b * 131072);
            hipLaunchKernelGGL(vt_k, dim3(1024), dim3(256), 0, stream, QKVbf, VTb);
            // attn3 scores: per head [256,64]@k^T
            mg<2,2,0,0,0,1,0>(stream, 256, 4096, 64,
                qlbf + (ll)b * 131072, 64, QKVbf + 512, 1536,
                ATT3bf, 4096, nullptr, nullptr, 8, 8, 0, 16384, 0, 64, 0, 1048576, 1.f, 0.f);
            hipLaunchKernelGGL(softmax_bf_k, dim3(2048), dim3(256), 0, stream, ATT3bf, 4096);
            // a3v split-K: [256,4096]@vT[64,4096]^T, K chunk 512, f32 partials
            mg<4,1,0,0,0,0,0>(stream, 256, 64, 512,
                ATT3bf, 4096, VTb, 4096,
                A3Vp, 64, nullptr, nullptr, 64, 8, 1048576, 512, 262144, 512, 131072, 16384, 1.f, 0.f);
            hipLaunchKernelGGL(a3vred_k, dim3(512), dim3(256), 0, stream,
                               A3Vp, A3Vb + (ll)b * 131072);
            // depthwise conv of v, then H += conv @ Wo
            hipLaunchKernelGGL(convb_k, dim3(8192), dim3(256), 0, stream, QKVbf, cw, CONVbf);
            mg<2,2,0,0,1,0,0>(stream, 4096, 512, 512, CONVbf, 512, WOT, 512,
                Hb, 512, nullptr, nullptr, 1, 1, 0,0, 0,0, 0,0, 1.f, 0.f);
        }

        // ---- Phase 2: pinv, all bf16 MFMA, batched 64 ----
        // X = softmax(ql @ kl^T)
        mg<2,2,0,0,0,1,0>(stream, 256, 256, 64, qlbf, 64, klbf, 64,
            Xbf, 256, nullptr, nullptr, 64, 64, 0, 16384, 0, 16384, 0, 65536, 1.f, 0.f);
        hipLaunchKernelGGL(softmax_bf_k, dim3(16384), dim3(256), 0, stream, Xbf, 256);
        hipLaunchKernelGGL(pinv_init_k, dim3(64), dim3(256), 0, stream, Xbf, Z0);
        bh16* zc = Z0; bh16* zn = Z1;
        for (int it = 0; it < ITERS; ++it) {
            // T1 = X@zc ; T2 = 7I - T1   (NN dual)
            mg<2,2,1,0,0,1,1>(stream, 256, 256, 256, Xbf, 256, zc, 256,
                T1, 256, T2, nullptr, 64, 64, 0, 65536, 0, 65536, 0, 65536, 1.f, 7.f);
            // zn = 15I - T1@T2
            mg<2,2,1,0,0,1,0>(stream, 256, 256, 256, T1, 256, T2, 256,
                zn, 256, nullptr, nullptr, 64, 64, 0, 65536, 0, 65536, 0, 65536, -1.f, 15.f);
            // T2 = 13I - T1@zn
            mg<2,2,1,0,0,1,0>(stream, 256, 256, 256, T1, 256, zn, 256,
                T2, 256, nullptr, nullptr, 64, 64, 0, 65536, 0, 65536, 0, 65536, -1.f, 13.f);
            // zn = 0.25 * zc@T2
            mg<2,2,1,0,0,1,0>(stream, 256, 256, 256, zc, 256, T2, 256,
                zn, 256, nullptr, nullptr, 64, 64, 0, 65536, 0, 65536, 0, 65536, 0.25f, 0.f);
            bh16* t = zc; zc = zn; zn = t;
        }
        // WB = zc @ A3V  (NN, [256,256]@[256,64])
        mg<4,1,1,0,0,1,0>(stream, 256, 64, 256, zc, 256, A3Vb, 64,
            WBb, 64, nullptr, nullptr, 64, 64, 0, 65536, 0, 16384, 0, 16384, 1.f, 0.f);
        hipLaunchKernelGGL(wbt_k, dim3(512), dim3(256), 0, stream, WBb, WBT);

        // ---- Phase 3: per sample ----
        for (int b = 0; b < BB_; ++b) {
            float* Hb = H + (ll)b * 2097152;
            // attn1 = q @ kl^T  [4096,64]@[256,64]^T per head
            mg<2,2,0,0,0,1,0>(stream, 4096, 256, 64,
                Qbf + (ll)b * 2097152, 64, klbf + (ll)b * 131072, 64,
                ATT1bf, 256, nullptr, nullptr, 8, 8, 0, 262144, 0, 16384, 0, 1048576, 1.f, 0.f);
            hipLaunchKernelGGL(softmax_bf_k, dim3(32768), dim3(256), 0, stream, ATT1bf, 256);
            // aout = attn1 @ wb  (heads into cols via ldc)
            mg<4,1,0,0,0,1,0>(stream, 4096, 64, 256,
                ATT1bf, 256, WBT + (ll)b * 131072, 256,
                AOUTbf, 512, nullptr, nullptr, 8, 8, 0, 1048576, 0, 16384, 0, 64, 1.f, 0.f);
            // H += aout @ Wo + bo
            mg<2,2,0,0,1,0,0>(stream, 4096, 512, 512, AOUTbf, 512, WOT, 512,
                Hb, 512, nullptr, bo, 1, 1, 0,0, 0,0, 0,0, 1.f, 0.f);
        }

        // ---- FFN: per sample ----
        for (int b = 0; b < BB_; ++b) {
            float* Hb = H + (ll)b * 2097152;
            hipLaunchKernelGGL(ln_k, dim3(4096), dim3(256), 0, stream, Hb, g2, b2, XLNbf);
            mg<2,2,0,1,0,1,0>(stream, 4096, 2048, 512, XLNbf, 512, F1WT, 512,
                HIDbf, 2048, nullptr, f1b, 1, 1, 0,0, 0,0, 0,0, 1.f, 0.f);
            mg<2,2,0,0,1,0,0>(stream, 4096, 512, 2048, HIDbf, 2048, F2WT, 2048,
                Hb, 512, nullptr, f2b, 1, 1, 0,0, 0,0, 0,0, 1.f, 0.f);
        }
    }

    hipLaunchKernelGGL(final_init_k, dim3(1), dim3(128), 0, stream, final_b, out);
    hipLaunchKernelGGL(final_gemv_k, dim3(256, BB_), dim3(256), 0, stream, H, final_w, out);
}

// Round 8
// 4344.505 us; speedup vs baseline: 3.9135x; 1.3324x over previous
//
#include <hip/hip_runtime.h>
#include <hip/hip_bf16.h>

// Problem constants
#define BB_ 8
#define NVEC 4096
#define DIM 512
#define HEADS 8
#define DH 64
#define MM_ 256
#define ITERS 6
#define DEPTH 2
#define NCLASS 10
#define KER 33
#define INNER 512
#define LSEG 16  // NVEC / MM_

typedef long long ll;
typedef __bf16 bh16;
typedef __attribute__((ext_vector_type(8))) __bf16 bf16x8;
typedef __attribute__((ext_vector_type(4))) float f32x4;

// ===========================================================================
// MFMA bf16 GEMM. TRB=0 (TN): C = A[M,K] @ B_t[N,K]^T. TRB=1 (NN):
// C = A[M,K] @ B[K,N] (B transposed into LDS during staging).
// Tile BM=WR*64 x BN=WC*64, BK=32, 256 threads = 4 waves (WR*WC==4).
// Epilogue: v = alpha*acc (+bias[col]) (+diagv if row==col) (+GELU).
// DUAL: C gets raw acc, C2 gets diagv*I - acc (both bf16).
// Two-level batch: z -> bo=z/BI (stride sXo), bi=z%BI (stride sXi).
// ===========================================================================
template<int WR, int WC, bool TRB, bool GELU_ACT, bool RESID, bool BF16OUT, bool DUAL>
__global__ void __launch_bounds__(256)
mgemm_k(const bh16* __restrict__ A, const bh16* __restrict__ B,
        const float* __restrict__ bias, void* __restrict__ Cv, void* __restrict__ C2v,
        int K, int lda, int ldb, int ldc,
        int BI, ll sAo, ll sAi, ll sBo, ll sBi, ll sCo, ll sCi,
        float alpha, float diagv)
{
    constexpr int BM = WR * 64, BN = WC * 64;
    const int bz = blockIdx.z;
    const int bo = bz / BI, bi = bz % BI;
    const bh16* Ab = A + bo * sAo + (ll)bi * sAi;
    const bh16* Bb = B + bo * sBo + (ll)bi * sBi;
    const ll coff = bo * sCo + (ll)bi * sCi;
    const int m0 = blockIdx.y * BM;
    const int n0 = blockIdx.x * BN;
    const int tid = threadIdx.x;
    const int lane = tid & 63;
    const int wave = tid >> 6;
    const int wr = wave / WC, wc = wave % WC;

    __shared__ bh16 Al[BM * 32];
    __shared__ bh16 Bl[BN * 32];

    f32x4 acc[4][4];
#pragma unroll
    for (int i = 0; i < 4; ++i)
#pragma unroll
        for (int j = 0; j < 4; ++j) acc[i][j] = (f32x4){0.f, 0.f, 0.f, 0.f};

    const int srow = tid >> 2;   // 0..63
    const int ssl  = tid & 3;    // 16B slot

    const int rsel  = ((lane & 15) >> 1) & 3;
    const int kslot = lane >> 4;

    for (int k0 = 0; k0 < K; k0 += 32) {
        __syncthreads();
#pragma unroll
        for (int i = 0; i < BM / 64; ++i) {
            int row = i * 64 + srow;
            int sl = ssl ^ ((row >> 1) & 3);
            bf16x8 v = *(const bf16x8*)(Ab + (ll)(m0 + row) * lda + k0 + ssl * 8);
            *(bf16x8*)(Al + row * 32 + sl * 8) = v;
        }
        if (!TRB) {
#pragma unroll
            for (int i = 0; i < BN / 64; ++i) {
                int row = i * 64 + srow;
                int sl = ssl ^ ((row >> 1) & 3);
                bf16x8 v = *(const bf16x8*)(Bb + (ll)(n0 + row) * ldb + k0 + ssl * 8);
                *(bf16x8*)(Bl + row * 32 + sl * 8) = v;
            }
        } else {
            // B stored [K][N]; transpose into LDS [n][k] with matching swizzle
            const int bk = tid >> 3;                 // 0..31
            const int nb0 = (tid & 7) * (BN / 8);
#pragma unroll
            for (int v8 = 0; v8 < BN / 64; ++v8) {
                int nb = nb0 + v8 * 8;
                bf16x8 v = *(const bf16x8*)(Bb + (ll)(k0 + bk) * ldb + n0 + nb);
#pragma unroll
                for (int j = 0; j < 8; ++j) {
                    int n = nb + j;
                    int sl = (bk >> 3) ^ ((n >> 1) & 3);
                    Bl[n * 32 + sl * 8 + (bk & 7)] = v[j];
                }
            }
        }
        __syncthreads();

        bf16x8 af[4], bfr[4];
#pragma unroll
        for (int mi = 0; mi < 4; ++mi) {
            int row = wr * 64 + mi * 16 + (lane & 15);
            af[mi] = *(const bf16x8*)(Al + row * 32 + (kslot ^ rsel) * 8);
        }
#pragma unroll
        for (int ni = 0; ni < 4; ++ni) {
            int row = wc * 64 + ni * 16 + (lane & 15);
            bfr[ni] = *(const bf16x8*)(Bl + row * 32 + (kslot ^ rsel) * 8);
        }
#pragma unroll
        for (int mi = 0; mi < 4; ++mi)
#pragma unroll
            for (int ni = 0; ni < 4; ++ni)
                acc[mi][ni] = __builtin_amdgcn_mfma_f32_16x16x32_bf16(
                    af[mi], bfr[ni], acc[mi][ni], 0, 0, 0);
    }

#pragma unroll
    for (int mi = 0; mi < 4; ++mi) {
#pragma unroll
        for (int ni = 0; ni < 4; ++ni) {
            const int colg = n0 + wc * 64 + ni * 16 + (lane & 15);
            const float bia = (!DUAL && bias) ? bias[colg] : 0.f;
#pragma unroll
            for (int r = 0; r < 4; ++r) {
                const int rowg = m0 + wr * 64 + mi * 16 + (lane >> 4) * 4 + r;
                const float a = acc[mi][ni][r];
                const ll off = coff + (ll)rowg * ldc + colg;
                if (DUAL) {
                    ((bh16*)Cv)[off] = (bh16)a;
                    float w = ((rowg == colg) ? diagv : 0.f) - a;
                    ((bh16*)C2v)[off] = (bh16)w;
                } else {
                    float v = alpha * a + bia;
                    if (diagv != 0.f && rowg == colg) v += diagv;
                    if (GELU_ACT) {
                        float t = tanhf(0.7978845608f * (v + 0.044715f * v * v * v));
                        v = 0.5f * v * (1.0f + t);
                    }
                    if (BF16OUT) {
                        ((bh16*)Cv)[off] = (bh16)v;
                    } else {
                        float* p = (float*)Cv + off;
                        float o = v;
                        if (RESID) o += *p;
                        *p = o;
                    }
                }
            }
        }
    }
}

template<int WR, int WC, bool TRB, bool G, bool R, bool BO, bool D>
static inline void mg(hipStream_t s, int M, int N, int K,
                      const bh16* A, int lda, const bh16* B, int ldb,
                      void* C, int ldc, void* C2, const float* bias,
                      int batch, int BI,
                      ll sAo, ll sAi, ll sBo, ll sBi, ll sCo, ll sCi,
                      float alpha, float diagv)
{
    dim3 grid(N / (WC * 64), M / (WR * 64), batch);
    hipLaunchKernelGGL((mgemm_k<WR, WC, TRB, G, R, BO, D>), grid, dim3(256), 0, s,
                       A, B, bias, C, C2, K, lda, ldb, ldc, BI,
                       sAo, sAi, sBo, sBi, sCo, sCi, alpha, diagv);
}

// ===========================================================================
// Small kernels
// ===========================================================================
__global__ void embed_k(const float* __restrict__ x, const float* __restrict__ w,
                        const float* __restrict__ b, float* __restrict__ h)
{
    ll idx = (ll)blockIdx.x * 256 + threadIdx.x;
    int d = (int)(idx & 511);
    ll bn = idx >> 9;
    h[idx] = x[bn * 2] * w[d] + x[bn * 2 + 1] * w[512 + d] + b[d];
}

// LayerNorm, bf16 output; one block per row of 512
__global__ void __launch_bounds__(256)
ln_k(const float* __restrict__ X, const float* __restrict__ g,
     const float* __restrict__ bta, bh16* __restrict__ Y)
{
    const ll row = blockIdx.x;
    const float* x = X + row * 512;
    bh16* y = Y + row * 512;
    const int tid = threadIdx.x;
    float v0 = x[tid], v1 = x[tid + 256];
    float s = v0 + v1;
    float q = v0 * v0 + v1 * v1;
    __shared__ float sred[8];
    for (int o = 32; o; o >>= 1) { s += __shfl_down(s, o); q += __shfl_down(q, o); }
    const int lane = tid & 63, w = tid >> 6;
    if (lane == 0) { sred[w] = s; sred[4 + w] = q; }
    __syncthreads();
    float ssum = sred[0] + sred[1] + sred[2] + sred[3];
    float qsum = sred[4] + sred[5] + sred[6] + sred[7];
    float mu = ssum * (1.0f / 512.0f);
    float var = qsum * (1.0f / 512.0f) - mu * mu;
    float r = rsqrtf(var + 1e-5f);
    y[tid] = (bh16)((v0 - mu) * r * g[tid] + bta[tid]);
    y[tid + 256] = (bh16)((v1 - mu) * r * g[tid + 256] + bta[tid + 256]);
}

// weight f32 [R][C] -> bf16 [C][R]
__global__ void cvtT_k(const float* __restrict__ in, bh16* __restrict__ outp, int C, int R)
{
    int idx = blockIdx.x * 256 + threadIdx.x;   // C*R/8 threads
    int c = idx % C, rg = idx / C;
    bf16x8 o;
#pragma unroll
    for (int j = 0; j < 8; ++j) o[j] = (bh16)in[(ll)(rg * 8 + j) * C + c];
    *(bf16x8*)(outp + (ll)c * R + rg * 8) = o;
}

// landmark means for ALL samples; ql pre-scaled by DH^-0.5
__global__ void landmarks_k(const bh16* __restrict__ qkv,
                            bh16* __restrict__ qlb, bh16* __restrict__ klb)
{
    int idx = blockIdx.x * 256 + threadIdx.x;   // 8*8*256*64 = 1,048,576
    int d = idx & 63;
    int m = (idx >> 6) & 255;
    int h = (idx >> 14) & 7;
    int b = idx >> 17;
    const bh16* base = qkv + (ll)b * (NVEC * 1536) + (ll)(m * LSEG) * 1536 + h * 64 + d;
    float sq = 0.f, sk = 0.f;
#pragma unroll
    for (int l = 0; l < LSEG; ++l) {
        sq += (float)base[(ll)l * 1536];
        sk += (float)base[(ll)l * 1536 + 512];
    }
    ll o = (ll)(b * 8 + h) * 16384 + m * 64 + d;
    qlb[o] = (bh16)(sq * (0.0625f * 0.125f));
    klb[o] = (bh16)(sk * 0.0625f);
}

// wb bf16 [bh][256][64] -> wbT bf16 [bh][64][256]
__global__ void wbt_k(const bh16* __restrict__ wb, bh16* __restrict__ wbt)
{
    int idx = blockIdx.x * 256 + threadIdx.x;   // 131072
    int d = idx & 63, kg = (idx >> 6) & 31, bhh = idx >> 11;
    const bh16* p = wb + (ll)bhh * 16384 + kg * 8 * 64 + d;
    bf16x8 o;
#pragma unroll
    for (int j = 0; j < 8; ++j) o[j] = p[j * 64];
    *(bf16x8*)(wbt + (ll)bhh * 16384 + d * 256 + kg * 8) = o;
}

// reduce split-K partials for a 2-sample chunk:
// part [2][8h][8s][256][64] f32 -> A3Vb bf16 at [bh0+smp*8+h][256][64]
__global__ void a3vred_k(const float* __restrict__ part, bh16* __restrict__ outp)
{
    int idx = blockIdx.x * 256 + threadIdx.x;   // 262144
    int smp = idx >> 17;
    int rest = idx & 131071;
    int h = rest >> 14, o = rest & 16383;
    const float* p = part + (ll)smp * 1048576 + (ll)h * 131072 + o;
    float s = 0.f;
#pragma unroll
    for (int j = 0; j < 8; ++j) s += p[j * 16384];
    outp[(ll)(smp * 8 + h) * 16384 + o] = (bh16)s;
}

// depthwise conv for ALL samples (bf16 in/out, f32 math)
__global__ void conv_k(const bh16* __restrict__ qkv, const float* __restrict__ cw,
                       bh16* __restrict__ convo)
{
    ll idx = (ll)blockIdx.x * 256 + threadIdx.x;  // 8*4096*512
    int c = (int)(idx & 511);
    int n = (int)((idx >> 9) & 4095);
    int b = (int)(idx >> 21);
    int h = c >> 6;
    const bh16* v = qkv + (ll)b * (NVEC * 1536) + 1024 + c;
    float acc = 0.f;
#pragma unroll
    for (int j = 0; j < KER; ++j) {
        int nn = n + j - (KER / 2);
        if (nn >= 0 && nn < NVEC) acc += (float)v[(ll)nn * 1536] * cw[h * KER + j];
    }
    convo[idx] = (bh16)acc;
}

// -------- softmax helpers --------
__device__ __forceinline__ float blkmax(float m, float* red, int tid)
{
#pragma unroll
    for (int o = 32; o; o >>= 1) m = fmaxf(m, __shfl_down(m, o));
    if ((tid & 63) == 0) red[tid >> 6] = m;
    __syncthreads();
    m = fmaxf(fmaxf(red[0], red[1]), fmaxf(red[2], red[3]));
    __syncthreads();
    return m;
}
__device__ __forceinline__ float blksum(float s, float* red, int tid)
{
#pragma unroll
    for (int o = 32; o; o >>= 1) s += __shfl_down(s, o);
    if ((tid & 63) == 0) red[tid >> 6] = s;
    __syncthreads();
    s = red[0] + red[1] + red[2] + red[3];
    __syncthreads();
    return s;
}

// in-place bf16 row softmax (L == 4096 or 256)
__global__ void __launch_bounds__(256)
softmax_bf_k(bh16* __restrict__ X, int L)
{
    const ll row = blockIdx.x;
    bh16* x = X + row * (ll)L;
    const int tid = threadIdx.x;
    __shared__ float red[4];
    if (L == 4096) {
        float v[16];
        bf16x8 a = *(const bf16x8*)(x + tid * 8);
        bf16x8 b = *(const bf16x8*)(x + 2048 + tid * 8);
#pragma unroll
        for (int j = 0; j < 8; ++j) { v[j] = (float)a[j]; v[8 + j] = (float)b[j]; }
        float m = -1e30f;
#pragma unroll
        for (int j = 0; j < 16; ++j) m = fmaxf(m, v[j]);
        m = blkmax(m, red, tid);
        float s = 0.f;
#pragma unroll
        for (int j = 0; j < 16; ++j) { v[j] = __expf(v[j] - m); s += v[j]; }
        s = blksum(s, red, tid);
        float inv = 1.0f / s;
        bf16x8 oa, ob;
#pragma unroll
        for (int j = 0; j < 8; ++j) { oa[j] = (bh16)(v[j] * inv); ob[j] = (bh16)(v[8 + j] * inv); }
        *(bf16x8*)(x + tid * 8) = oa;
        *(bf16x8*)(x + 2048 + tid * 8) = ob;
    } else {
        float v = (float)x[tid];
        float m = blkmax(v, red, tid);
        float e = __expf(v - m);
        float s = blksum(e, red, tid);
        x[tid] = (bh16)(e / s);
    }
}

// z0 = x^T / (max_rowsum * max_colsum), bf16 in/out, f32 math
__global__ void __launch_bounds__(256)
pinv_init_k(const bh16* __restrict__ X, bh16* __restrict__ Z)
{
    const ll bh = blockIdx.x;
    const bh16* x = X + bh * 65536;
    bh16* z = Z + bh * 65536;
    const int tid = threadIdx.x;
    float rs = 0.f, cs = 0.f;
    for (int j = 0; j < 256; ++j) {
        rs += fabsf((float)x[tid * 256 + j]);
        cs += fabsf((float)x[j * 256 + tid]);
    }
    __shared__ float rbuf[256], cbuf[256];
    rbuf[tid] = rs; cbuf[tid] = cs;
    __syncthreads();
    for (int o = 128; o; o >>= 1) {
        if (tid < o) {
            rbuf[tid] = fmaxf(rbuf[tid], rbuf[tid + o]);
            cbuf[tid] = fmaxf(cbuf[tid], cbuf[tid + o]);
        }
        __syncthreads();
    }
    float inv = 1.0f / (rbuf[0] * cbuf[0]);
    for (int e = tid; e < 65536; e += 256) {
        int i = e >> 8, j = e & 255;
        z[e] = (bh16)((float)x[j * 256 + i] * inv);
    }
}

__global__ void final_init_k(const float* __restrict__ fb, float* __restrict__ out)
{
    int i = threadIdx.x;
    if (i < BB_ * NCLASS) out[i] = fb[i % NCLASS];
}

__global__ void __launch_bounds__(256)
final_gemv_k(const float* __restrict__ hbuf, const float* __restrict__ w,
             float* __restrict__ out)
{
    const int b = blockIdx.y;
    const int chunk = blockIdx.x;
    const int tid = threadIdx.x;
    const float* hrow = hbuf + (ll)b * (NVEC * DIM);
    float pc[NCLASS] = {};
    const int k0 = chunk * 8192;
    for (int e = 0; e < 32; ++e) {
        int k = k0 + e * 256 + tid;
        float hv = hrow[k];
        const float* wr = w + (ll)k * NCLASS;
#pragma unroll
        for (int c = 0; c < NCLASS; ++c) pc[c] += hv * wr[c];
    }
    __shared__ float red[256];
    for (int c = 0; c < NCLASS; ++c) {
        red[tid] = pc[c];
        __syncthreads();
        for (int o = 128; o; o >>= 1) {
            if (tid < o) red[tid] += red[tid + o];
            __syncthreads();
        }
        if (tid == 0) atomicAdd(out + b * NCLASS + c, red[0]);
        __syncthreads();
    }
}

// ===========================================================================
extern "C" void kernel_launch(void* const* d_in, const int* in_sizes, int n_in,
                              void* d_out, int out_size, void* d_ws, size_t ws_size,
                              hipStream_t stream)
{
    const float* x      = (const float*)d_in[0];
    const float* lin_w  = (const float*)d_in[1];
    const float* lin_b  = (const float*)d_in[2];
    const float* ln1_g  = (const float*)d_in[3];
    const float* ln1_b  = (const float*)d_in[4];
    const float* qkv_w  = (const float*)d_in[5];
    const float* out_w  = (const float*)d_in[6];
    const float* out_b  = (const float*)d_in[7];
    const float* conv_w = (const float*)d_in[8];
    const float* ln2_g  = (const float*)d_in[9];
    const float* ln2_b  = (const float*)d_in[10];
    const float* ff1_w  = (const float*)d_in[11];
    const float* ff1_b  = (const float*)d_in[12];
    const float* ff2_w  = (const float*)d_in[13];
    const float* ff2_b  = (const float*)d_in[14];
    const float* final_w = (const float*)d_in[15];
    const float* final_b = (const float*)d_in[16];
    float* out = (float*)d_out;
    float* ws  = (float*)d_ws;

    // ---- workspace layout (f32 units), total 56,623,104 f32 = 226.5 MB ----
    // (proven available: Round 4 ran with a 60.8M-f32 layout)
    float* H    = ws;                                  // [8][4096][512] f32, 16,777,216
    bh16*  QKV  = (bh16*)(ws + 16777216);              // [8][4096][1536] bf16, 25,165,824 f32
    float* P    = ws + 41943040;                       // pool, 10,485,760 f32
    bh16*  qlbf = (bh16*)(ws + 52428800);              // [64bh][256][64] bf16
    bh16*  klbf = (bh16*)(ws + 52953088);
    bh16*  A3Vb = (bh16*)(ws + 53477376);              // [64bh][256][64] bf16
    bh16*  WBb  = (bh16*)(ws + 54001664);
    bh16*  WBT  = (bh16*)(ws + 54525952);              // [64bh][64][256] bf16
    bh16*  WQT  = (bh16*)(ws + 55050240);              // [1536][512] bf16
    bh16*  WOT  = (bh16*)(ws + 55443456);              // [512][512] bf16
    bh16*  F1WT = (bh16*)(ws + 55574528);              // [2048][512] bf16
    bh16*  F2WT = (bh16*)(ws + 56098816);              // [512][2048] bf16
    if (ws_size < 56623104ULL * 4) return;

    // pool aliases (time-sliced)
    bh16*  XLNall = (bh16*)P;                          // [32768][512] bf16 (8,388,608 f32)
    bh16*  ATT3c  = (bh16*)P;                          // [16bh][256][4096] bf16 (8,388,608 f32)
    float* A3Vp   = P + 8388608;                       // [2][8h][8s][256][64] f32 (2,097,152)
    bh16*  CONVa  = (bh16*)P;                          // [8][4096][512] bf16 (8,388,608 f32)
    bh16*  Xbf = (bh16*)P;                             // pinv: 5 x [64][256][256] bf16
    bh16*  Z0  = (bh16*)(P + 2097152);
    bh16*  Z1  = (bh16*)(P + 4194304);
    bh16*  T1  = (bh16*)(P + 6291456);
    bh16*  T2  = (bh16*)(P + 8388608);
    bh16*  ATT1c  = (bh16*)P;                          // [16bh][4096][256] bf16 (8,388,608 f32)
    bh16*  AOUTc  = (bh16*)(P + 8388608);              // [2][4096][512] bf16 (2,097,152 f32)
    bh16*  XLNc   = (bh16*)P;                          // FFN: [8192][512] bf16 (2,097,152 f32)
    bh16*  HIDc   = (bh16*)(P + 2097152);              // [2][4096][2048] bf16 (8,388,608 f32)

    const ll SMP = (ll)NVEC * 1536;                    // qkv stride per sample (bf16)

    // embed
    hipLaunchKernelGGL(embed_k, dim3(65536), dim3(256), 0, stream, x, lin_w, lin_b, H);

    for (int i = 0; i < DEPTH; ++i) {
        const float* wq  = qkv_w + (ll)i * 512 * 1536;
        const float* wo  = out_w + (ll)i * 512 * 512;
        const float* bo  = out_b + (ll)i * 512;
        const float* cw  = conv_w + (ll)i * HEADS * KER;
        const float* g1  = ln1_g + (ll)i * 512;
        const float* b1  = ln1_b + (ll)i * 512;
        const float* g2  = ln2_g + (ll)i * 512;
        const float* b2  = ln2_b + (ll)i * 512;
        const float* f1w = ff1_w + (ll)i * 512 * 2048;
        const float* f1b = ff1_b + (ll)i * 2048;
        const float* f2w = ff2_w + (ll)i * 2048 * 512;
        const float* f2b = ff2_b + (ll)i * 512;

        // weight convert+transpose (bf16 [N][K])
        hipLaunchKernelGGL(cvtT_k, dim3(384), dim3(256), 0, stream, wq, WQT, 1536, 512);
        hipLaunchKernelGGL(cvtT_k, dim3(128), dim3(256), 0, stream, wo, WOT, 512, 512);
        hipLaunchKernelGGL(cvtT_k, dim3(512), dim3(256), 0, stream, f1w, F1WT, 2048, 512);
        hipLaunchKernelGGL(cvtT_k, dim3(512), dim3(256), 0, stream, f2w, F2WT, 512, 2048);

        // LN1 (all samples) + qkv (M=32768, one launch)
        hipLaunchKernelGGL(ln_k, dim3(32768), dim3(256), 0, stream, H, g1, b1, XLNall);
        mg<2,2,0,0,0,1,0>(stream, 32768, 1536, 512, XLNall, 512, WQT, 512,
            QKV, 1536, nullptr, nullptr, 1, 1, 0,0, 0,0, 0,0, 1.f, 0.f);

        // landmarks (all samples)
        hipLaunchKernelGGL(landmarks_k, dim3(4096), dim3(256), 0, stream, QKV, qlbf, klbf);

        // ---- attn3 / softmax / a3v in 2-sample chunks ----
        for (int c = 0; c < 4; ++c) {
            const bh16* qkvc = QKV + (ll)c * 2 * SMP;
            // attn3: z = smp*8+h (BI=8)
            mg<2,2,0,0,0,1,0>(stream, 256, 4096, 64,
                qlbf + (ll)c * 262144, 64, qkvc + 512, 1536,
                ATT3c, 4096, nullptr, nullptr, 16, 8,
                131072, 16384, SMP, 64, 8388608LL, 1048576, 1.f, 0.f);
            hipLaunchKernelGGL(softmax_bf_k, dim3(4096), dim3(256), 0, stream, ATT3c, 4096);
            // a3v (NN via TRB), split-K 8, per sample: z = h*8+s
            for (int s = 0; s < 2; ++s) {
                mg<4,1,1,0,0,0,0>(stream, 256, 64, 512,
                    ATT3c + (ll)s * 8 * 1048576, 4096, qkvc + (ll)s * SMP + 1024, 1536,
                    A3Vp + (ll)s * 1048576, 64, nullptr, nullptr, 64, 8,
                    1048576, 512, 64, 512LL * 1536, 131072, 16384, 1.f, 0.f);
            }
            hipLaunchKernelGGL(a3vred_k, dim3(1024), dim3(256), 0, stream,
                               A3Vp, A3Vb + (ll)c * 2 * 131072);
        }

        // ---- depthwise conv (all samples) + H += conv @ Wo ----
        hipLaunchKernelGGL(conv_k, dim3(65536), dim3(256), 0, stream, QKV, cw, CONVa);
        mg<2,2,0,0,1,0,0>(stream, 32768, 512, 512, CONVa, 512, WOT, 512,
            H, 512, nullptr, nullptr, 1, 1, 0,0, 0,0, 0,0, 1.f, 0.f);

        // ---- pinv (bf16 MFMA, batched 64) ----
        mg<2,2,0,0,0,1,0>(stream, 256, 256, 64, qlbf, 64, klbf, 64,
            Xbf, 256, nullptr, nullptr, 64, 64, 0, 16384, 0, 16384, 0, 65536, 1.f, 0.f);
        hipLaunchKernelGGL(softmax_bf_k, dim3(16384), dim3(256), 0, stream, Xbf, 256);
        hipLaunchKernelGGL(pinv_init_k, dim3(64), dim3(256), 0, stream, Xbf, Z0);
        bh16* zc = Z0; bh16* zn = Z1;
        for (int it = 0; it < ITERS; ++it) {
            mg<2,2,1,0,0,1,1>(stream, 256, 256, 256, Xbf, 256, zc, 256,
                T1, 256, T2, nullptr, 64, 64, 0, 65536, 0, 65536, 0, 65536, 1.f, 7.f);
            mg<2,2,1,0,0,1,0>(stream, 256, 256, 256, T1, 256, T2, 256,
                zn, 256, nullptr, nullptr, 64, 64, 0, 65536, 0, 65536, 0, 65536, -1.f, 15.f);
            mg<2,2,1,0,0,1,0>(stream, 256, 256, 256, T1, 256, zn, 256,
                T2, 256, nullptr, nullptr, 64, 64, 0, 65536, 0, 65536, 0, 65536, -1.f, 13.f);
            mg<2,2,1,0,0,1,0>(stream, 256, 256, 256, zc, 256, T2, 256,
                zn, 256, nullptr, nullptr, 64, 64, 0, 65536, 0, 65536, 0, 65536, 0.25f, 0.f);
            bh16* t = zc; zc = zn; zn = t;
        }
        // WB = zc @ A3V  (NN)
        mg<4,1,1,0,0,1,0>(stream, 256, 64, 256, zc, 256, A3Vb, 64,
            WBb, 64, nullptr, nullptr, 64, 64, 0, 65536, 0, 16384, 0, 16384, 1.f, 0.f);
        hipLaunchKernelGGL(wbt_k, dim3(512), dim3(256), 0, stream, WBb, WBT);

        // ---- attn1 / softmax / a1@wb / out-proj in 2-sample chunks ----
        for (int c = 0; c < 4; ++c) {
            const bh16* qkvc = QKV + (ll)c * 2 * SMP;
            // attn1 = 0.125 * q @ kl^T; q read in place (lda=1536); z = smp*8+h
            mg<2,2,0,0,0,1,0>(stream, 4096, 256, 64,
                qkvc, 1536, klbf + (ll)c * 262144, 64,
                ATT1c, 256, nullptr, nullptr, 16, 8,
                SMP, 64, 131072, 16384, 8388608LL, 1048576, 0.125f, 0.f);
            hipLaunchKernelGGL(softmax_bf_k, dim3(65536), dim3(256), 0, stream, ATT1c, 256);
            // aout = attn1 @ wb (heads into cols via ldc=512)
            mg<4,1,0,0,0,1,0>(stream, 4096, 64, 256,
                ATT1c, 256, WBT + (ll)c * 262144, 256,
                AOUTc, 512, nullptr, nullptr, 16, 8,
                8388608LL, 1048576, 131072, 16384, 2097152LL, 64, 1.f, 0.f);
            // H += aout @ Wo + bo   (M=8192)
            mg<2,2,0,0,1,0,0>(stream, 8192, 512, 512, AOUTc, 512, WOT, 512,
                H + (ll)c * 2 * 2097152, 512, nullptr, bo, 1, 1, 0,0, 0,0, 0,0, 1.f, 0.f);
        }

        // ---- FFN in 2-sample chunks ----
        for (int c = 0; c < 4; ++c) {
            float* Hc = H + (ll)c * 2 * 2097152;
            hipLaunchKernelGGL(ln_k, dim3(8192), dim3(256), 0, stream, Hc, g2, b2, XLNc);
            mg<2,2,0,1,0,1,0>(stream, 8192, 2048, 512, XLNc, 512, F1WT, 512,
                HIDc, 2048, nullptr, f1b, 1, 1, 0,0, 0,0, 0,0, 1.f, 0.f);
            mg<2,2,0,0,1,0,0>(stream, 8192, 512, 2048, HIDc, 2048, F2WT, 2048,
                Hc, 512, nullptr, f2b, 1, 1, 0,0, 0,0, 0,0, 1.f, 0.f);
        }
    }

    hipLaunchKernelGGL(final_init_k, dim3(1), dim3(128), 0, stream, final_b, out);
    hipLaunchKernelGGL(final_gemv_k, dim3(256, BB_), dim3(256), 0, stream, H, final_w, out);
}

// Round 9
// 3669.997 us; speedup vs baseline: 4.6328x; 1.1838x over previous
//
#include <hip/hip_runtime.h>
#include <hip/hip_bf16.h>

// Problem constants
#define BB_ 8
#define NVEC 4096
#define DIM 512
#define HEADS 8
#define DH 64
#define MM_ 256
#define ITERS 6
#define DEPTH 2
#define NCLASS 10
#define KER 33
#define INNER 512
#define LSEG 16  // NVEC / MM_

typedef long long ll;
typedef __bf16 bh16;
typedef __attribute__((ext_vector_type(8))) __bf16 bf16x8;
typedef __attribute__((ext_vector_type(4))) float f32x4;

// ===========================================================================
// MFMA bf16 GEMM. TRB=0 (TN): C = A[M,K] @ B_t[N,K]^T. TRB=1 (NN):
// C = A[M,K] @ B[K,N] (B transposed into LDS during staging).
// Tile BM=WR*64 x BN=WC*64, BK=32, 256 threads = 4 waves (WR*WC==4).
// Epilogue: v = alpha*acc (+bias[col]) (+diagv if row==col) (+GELU).
// DUAL: C gets raw acc, C2 gets diagv*I - acc (both bf16).
// Two-level batch: z -> bo=z/BI (stride sXo), bi=z%BI (stride sXi).
// ===========================================================================
template<int WR, int WC, bool TRB, bool GELU_ACT, bool RESID, bool BF16OUT, bool DUAL>
__global__ void __launch_bounds__(256)
mgemm_k(const bh16* __restrict__ A, const bh16* __restrict__ B,
        const float* __restrict__ bias, void* __restrict__ Cv, void* __restrict__ C2v,
        int K, int lda, int ldb, int ldc,
        int BI, ll sAo, ll sAi, ll sBo, ll sBi, ll sCo, ll sCi,
        float alpha, float diagv)
{
    constexpr int BM = WR * 64, BN = WC * 64;
    const int bz = blockIdx.z;
    const int bo = bz / BI, bi = bz % BI;
    const bh16* Ab = A + bo * sAo + (ll)bi * sAi;
    const bh16* Bb = B + bo * sBo + (ll)bi * sBi;
    const ll coff = bo * sCo + (ll)bi * sCi;
    const int m0 = blockIdx.y * BM;
    const int n0 = blockIdx.x * BN;
    const int tid = threadIdx.x;
    const int lane = tid & 63;
    const int wave = tid >> 6;
    const int wr = wave / WC, wc = wave % WC;

    __shared__ bh16 Al[BM * 32];
    __shared__ bh16 Bl[BN * 32];

    f32x4 acc[4][4];
#pragma unroll
    for (int i = 0; i < 4; ++i)
#pragma unroll
        for (int j = 0; j < 4; ++j) acc[i][j] = (f32x4){0.f, 0.f, 0.f, 0.f};

    const int srow = tid >> 2;   // 0..63
    const int ssl  = tid & 3;    // 16B slot

    const int rsel  = ((lane & 15) >> 1) & 3;
    const int kslot = lane >> 4;

    for (int k0 = 0; k0 < K; k0 += 32) {
        __syncthreads();
#pragma unroll
        for (int i = 0; i < BM / 64; ++i) {
            int row = i * 64 + srow;
            int sl = ssl ^ ((row >> 1) & 3);
            bf16x8 v = *(const bf16x8*)(Ab + (ll)(m0 + row) * lda + k0 + ssl * 8);
            *(bf16x8*)(Al + row * 32 + sl * 8) = v;
        }
        if (!TRB) {
#pragma unroll
            for (int i = 0; i < BN / 64; ++i) {
                int row = i * 64 + srow;
                int sl = ssl ^ ((row >> 1) & 3);
                bf16x8 v = *(const bf16x8*)(Bb + (ll)(n0 + row) * ldb + k0 + ssl * 8);
                *(bf16x8*)(Bl + row * 32 + sl * 8) = v;
            }
        } else {
            // B stored [K][N]; transpose into LDS [n][k] with matching swizzle
            const int bk = tid >> 3;                 // 0..31
            const int nb0 = (tid & 7) * (BN / 8);
#pragma unroll
            for (int v8 = 0; v8 < BN / 64; ++v8) {
                int nb = nb0 + v8 * 8;
                bf16x8 v = *(const bf16x8*)(Bb + (ll)(k0 + bk) * ldb + n0 + nb);
#pragma unroll
                for (int j = 0; j < 8; ++j) {
                    int n = nb + j;
                    int sl = (bk >> 3) ^ ((n >> 1) & 3);
                    Bl[n * 32 + sl * 8 + (bk & 7)] = v[j];
                }
            }
        }
        __syncthreads();

        bf16x8 af[4], bfr[4];
#pragma unroll
        for (int mi = 0; mi < 4; ++mi) {
            int row = wr * 64 + mi * 16 + (lane & 15);
            af[mi] = *(const bf16x8*)(Al + row * 32 + (kslot ^ rsel) * 8);
        }
#pragma unroll
        for (int ni = 0; ni < 4; ++ni) {
            int row = wc * 64 + ni * 16 + (lane & 15);
            bfr[ni] = *(const bf16x8*)(Bl + row * 32 + (kslot ^ rsel) * 8);
        }
#pragma unroll
        for (int mi = 0; mi < 4; ++mi)
#pragma unroll
            for (int ni = 0; ni < 4; ++ni)
                acc[mi][ni] = __builtin_amdgcn_mfma_f32_16x16x32_bf16(
                    af[mi], bfr[ni], acc[mi][ni], 0, 0, 0);
    }

#pragma unroll
    for (int mi = 0; mi < 4; ++mi) {
#pragma unroll
        for (int ni = 0; ni < 4; ++ni) {
            const int colg = n0 + wc * 64 + ni * 16 + (lane & 15);
            const float bia = (!DUAL && bias) ? bias[colg] : 0.f;
#pragma unroll
            for (int r = 0; r < 4; ++r) {
                const int rowg = m0 + wr * 64 + mi * 16 + (lane >> 4) * 4 + r;
                const float a = acc[mi][ni][r];
                const ll off = coff + (ll)rowg * ldc + colg;
                if (DUAL) {
                    ((bh16*)Cv)[off] = (bh16)a;
                    float w = ((rowg == colg) ? diagv : 0.f) - a;
                    ((bh16*)C2v)[off] = (bh16)w;
                } else {
                    float v = alpha * a + bia;
                    if (diagv != 0.f && rowg == colg) v += diagv;
                    if (GELU_ACT) {
                        float t = tanhf(0.7978845608f * (v + 0.044715f * v * v * v));
                        v = 0.5f * v * (1.0f + t);
                    }
                    if (BF16OUT) {
                        ((bh16*)Cv)[off] = (bh16)v;
                    } else {
                        float* p = (float*)Cv + off;
                        float o = v;
                        if (RESID) o += *p;
                        *p = o;
                    }
                }
            }
        }
    }
}

template<int WR, int WC, bool TRB, bool G, bool R, bool BO, bool D>
static inline void mg(hipStream_t s, int M, int N, int K,
                      const bh16* A, int lda, const bh16* B, int ldb,
                      void* C, int ldc, void* C2, const float* bias,
                      int batch, int BI,
                      ll sAo, ll sAi, ll sBo, ll sBi, ll sCo, ll sCi,
                      float alpha, float diagv)
{
    dim3 grid(N / (WC * 64), M / (WR * 64), batch);
    hipLaunchKernelGGL((mgemm_k<WR, WC, TRB, G, R, BO, D>), grid, dim3(256), 0, s,
                       A, B, bias, C, C2, K, lda, ldb, ldc, BI,
                       sAo, sAi, sBo, sBi, sCo, sCi, alpha, diagv);
}

// ===========================================================================
// Small kernels
// ===========================================================================
__global__ void embed_k(const float* __restrict__ x, const float* __restrict__ w,
                        const float* __restrict__ b, float* __restrict__ h)
{
    ll idx = (ll)blockIdx.x * 256 + threadIdx.x;
    int d = (int)(idx & 511);
    ll bn = idx >> 9;
    h[idx] = x[bn * 2] * w[d] + x[bn * 2 + 1] * w[512 + d] + b[d];
}

// LayerNorm, bf16 output; one block per row of 512
__global__ void __launch_bounds__(256)
ln_k(const float* __restrict__ X, const float* __restrict__ g,
     const float* __restrict__ bta, bh16* __restrict__ Y)
{
    const ll row = blockIdx.x;
    const float* x = X + row * 512;
    bh16* y = Y + row * 512;
    const int tid = threadIdx.x;
    float v0 = x[tid], v1 = x[tid + 256];
    float s = v0 + v1;
    float q = v0 * v0 + v1 * v1;
    __shared__ float sred[8];
    for (int o = 32; o; o >>= 1) { s += __shfl_down(s, o); q += __shfl_down(q, o); }
    const int lane = tid & 63, w = tid >> 6;
    if (lane == 0) { sred[w] = s; sred[4 + w] = q; }
    __syncthreads();
    float ssum = sred[0] + sred[1] + sred[2] + sred[3];
    float qsum = sred[4] + sred[5] + sred[6] + sred[7];
    float mu = ssum * (1.0f / 512.0f);
    float var = qsum * (1.0f / 512.0f) - mu * mu;
    float r = rsqrtf(var + 1e-5f);
    y[tid] = (bh16)((v0 - mu) * r * g[tid] + bta[tid]);
    y[tid + 256] = (bh16)((v1 - mu) * r * g[tid + 256] + bta[tid + 256]);
}

// weight f32 [R][C] -> bf16 [C][R]
__global__ void cvtT_k(const float* __restrict__ in, bh16* __restrict__ outp, int C, int R)
{
    int idx = blockIdx.x * 256 + threadIdx.x;   // C*R/8 threads
    int c = idx % C, rg = idx / C;
    bf16x8 o;
#pragma unroll
    for (int j = 0; j < 8; ++j) o[j] = (bh16)in[(ll)(rg * 8 + j) * C + c];
    *(bf16x8*)(outp + (ll)c * R + rg * 8) = o;
}

// landmark means for ALL samples; ql pre-scaled by DH^-0.5
__global__ void landmarks_k(const bh16* __restrict__ qkv,
                            bh16* __restrict__ qlb, bh16* __restrict__ klb)
{
    int idx = blockIdx.x * 256 + threadIdx.x;   // 8*8*256*64 = 1,048,576
    int d = idx & 63;
    int m = (idx >> 6) & 255;
    int h = (idx >> 14) & 7;
    int b = idx >> 17;
    const bh16* base = qkv + (ll)b * (NVEC * 1536) + (ll)(m * LSEG) * 1536 + h * 64 + d;
    float sq = 0.f, sk = 0.f;
#pragma unroll
    for (int l = 0; l < LSEG; ++l) {
        sq += (float)base[(ll)l * 1536];
        sk += (float)base[(ll)l * 1536 + 512];
    }
    ll o = (ll)(b * 8 + h) * 16384 + m * 64 + d;
    qlb[o] = (bh16)(sq * (0.0625f * 0.125f));
    klb[o] = (bh16)(sk * 0.0625f);
}

// wb bf16 [bh][256][64] -> wbT bf16 [bh][64][256]
__global__ void wbt_k(const bh16* __restrict__ wb, bh16* __restrict__ wbt)
{
    int idx = blockIdx.x * 256 + threadIdx.x;   // 131072
    int d = idx & 63, kg = (idx >> 6) & 31, bhh = idx >> 11;
    const bh16* p = wb + (ll)bhh * 16384 + kg * 8 * 64 + d;
    bf16x8 o;
#pragma unroll
    for (int j = 0; j < 8; ++j) o[j] = p[j * 64];
    *(bf16x8*)(wbt + (ll)bhh * 16384 + d * 256 + kg * 8) = o;
}

// reduce split-K partials for a 2-sample chunk:
// part [2][8h][8s][256][64] f32 -> A3Vb bf16 at [bh0+smp*8+h][256][64]
__global__ void a3vred_k(const float* __restrict__ part, bh16* __restrict__ outp)
{
    int idx = blockIdx.x * 256 + threadIdx.x;   // 262144
    int smp = idx >> 17;
    int rest = idx & 131071;
    int h = rest >> 14, o = rest & 16383;
    const float* p = part + (ll)smp * 1048576 + (ll)h * 131072 + o;
    float s = 0.f;
#pragma unroll
    for (int j = 0; j < 8; ++j) s += p[j * 16384];
    outp[(ll)(smp * 8 + h) * 16384 + o] = (bh16)s;
}

// ---------------------------------------------------------------------------
// Depthwise conv, sliding-window vectorized: thread = (b, 4 n's, 8 channels).
// 36 bf16x8 loads produce 4x8 outputs; accumulation order per output (k
// ascending) identical to the scalar version -> bit-identical results.
// ---------------------------------------------------------------------------
__global__ void __launch_bounds__(256)
conv_k(const bh16* __restrict__ qkv, const float* __restrict__ cw,
       bh16* __restrict__ convo)
{
    int idx = blockIdx.x * 256 + threadIdx.x;   // 8*1024*64 = 524288
    int c8 = idx & 63;                          // 8-channel group
    int ng = (idx >> 6) & 1023;                 // n-group (4 n's)
    int b  = idx >> 16;
    const int n0 = ng * 4;
    const int h = c8 >> 3;
    const bh16* v = qkv + (ll)b * (NVEC * 1536) + 1024 + c8 * 8;

    float wreg[KER];
#pragma unroll
    for (int k = 0; k < KER; ++k) wreg[k] = cw[h * KER + k];

    float acc[4][8];
#pragma unroll
    for (int t = 0; t < 4; ++t)
#pragma unroll
        for (int e = 0; e < 8; ++e) acc[t][e] = 0.f;

#pragma unroll
    for (int m = 0; m < 36; ++m) {
        int nn = n0 + m - (KER / 2);
        bf16x8 vv = {};
        if ((unsigned)nn < (unsigned)NVEC)
            vv = *(const bf16x8*)(v + (ll)nn * 1536);
#pragma unroll
        for (int t = 0; t < 4; ++t) {
            constexpr int KMAX = KER - 1;
            int k = m - t;
            if (k >= 0 && k <= KMAX) {
                float wk = wreg[k];
#pragma unroll
                for (int e = 0; e < 8; ++e)
                    acc[t][e] = fmaf((float)vv[e], wk, acc[t][e]);
            }
        }
    }

    bh16* o = convo + (ll)b * (NVEC * 512) + (ll)n0 * 512 + c8 * 8;
#pragma unroll
    for (int t = 0; t < 4; ++t) {
        bf16x8 ov;
#pragma unroll
        for (int e = 0; e < 8; ++e) ov[e] = (bh16)acc[t][e];
        *(bf16x8*)(o + (ll)t * 512) = ov;
    }
}

// -------- softmax helpers --------
__device__ __forceinline__ float blkmax(float m, float* red, int tid)
{
#pragma unroll
    for (int o = 32; o; o >>= 1) m = fmaxf(m, __shfl_down(m, o));
    if ((tid & 63) == 0) red[tid >> 6] = m;
    __syncthreads();
    m = fmaxf(fmaxf(red[0], red[1]), fmaxf(red[2], red[3]));
    __syncthreads();
    return m;
}
__device__ __forceinline__ float blksum(float s, float* red, int tid)
{
#pragma unroll
    for (int o = 32; o; o >>= 1) s += __shfl_down(s, o);
    if ((tid & 63) == 0) red[tid >> 6] = s;
    __syncthreads();
    s = red[0] + red[1] + red[2] + red[3];
    __syncthreads();
    return s;
}

// in-place bf16 row softmax, L == 4096; one block (256 thr) per row
__global__ void __launch_bounds__(256)
softmax_bf_k(bh16* __restrict__ X, int L)
{
    const ll row = blockIdx.x;
    bh16* x = X + row * (ll)L;
    const int tid = threadIdx.x;
    __shared__ float red[4];
    float v[16];
    bf16x8 a = *(const bf16x8*)(x + tid * 8);
    bf16x8 b = *(const bf16x8*)(x + 2048 + tid * 8);
#pragma unroll
    for (int j = 0; j < 8; ++j) { v[j] = (float)a[j]; v[8 + j] = (float)b[j]; }
    float m = -1e30f;
#pragma unroll
    for (int j = 0; j < 16; ++j) m = fmaxf(m, v[j]);
    m = blkmax(m, red, tid);
    float s = 0.f;
#pragma unroll
    for (int j = 0; j < 16; ++j) { v[j] = __expf(v[j] - m); s += v[j]; }
    s = blksum(s, red, tid);
    float inv = 1.0f / s;
    bf16x8 oa, ob;
#pragma unroll
    for (int j = 0; j < 8; ++j) { oa[j] = (bh16)(v[j] * inv); ob[j] = (bh16)(v[8 + j] * inv); }
    *(bf16x8*)(x + tid * 8) = oa;
    *(bf16x8*)(x + 2048 + tid * 8) = ob;
}

// in-place bf16 row softmax, L == 256: one row per 32-lane group, 8 rows/block
__global__ void __launch_bounds__(256)
softmax256_k(bh16* __restrict__ X)
{
    const int tid = threadIdx.x;
    const ll row = (ll)blockIdx.x * 8 + (tid >> 5);
    const int l = tid & 31;
    bh16* x = X + row * 256 + l * 8;
    bf16x8 a = *(const bf16x8*)x;
    float v[8];
#pragma unroll
    for (int j = 0; j < 8; ++j) v[j] = (float)a[j];
    float m = -1e30f;
#pragma unroll
    for (int j = 0; j < 8; ++j) m = fmaxf(m, v[j]);
#pragma unroll
    for (int o = 16; o; o >>= 1) m = fmaxf(m, __shfl_xor(m, o, 32));
    float s = 0.f;
#pragma unroll
    for (int j = 0; j < 8; ++j) { v[j] = __expf(v[j] - m); s += v[j]; }
#pragma unroll
    for (int o = 16; o; o >>= 1) s += __shfl_xor(s, o, 32);
    float inv = 1.0f / s;
    bf16x8 ov;
#pragma unroll
    for (int j = 0; j < 8; ++j) ov[j] = (bh16)(v[j] * inv);
    *(bf16x8*)x = ov;
}

// z0 = x^T / (max_rowsum * max_colsum), bf16 in/out, f32 math
__global__ void __launch_bounds__(256)
pinv_init_k(const bh16* __restrict__ X, bh16* __restrict__ Z)
{
    const ll bh = blockIdx.x;
    const bh16* x = X + bh * 65536;
    bh16* z = Z + bh * 65536;
    const int tid = threadIdx.x;
    float rs = 0.f, cs = 0.f;
    for (int j = 0; j < 256; ++j) {
        rs += fabsf((float)x[tid * 256 + j]);
        cs += fabsf((float)x[j * 256 + tid]);
    }
    __shared__ float rbuf[256], cbuf[256];
    rbuf[tid] = rs; cbuf[tid] = cs;
    __syncthreads();
    for (int o = 128; o; o >>= 1) {
        if (tid < o) {
            rbuf[tid] = fmaxf(rbuf[tid], rbuf[tid + o]);
            cbuf[tid] = fmaxf(cbuf[tid], cbuf[tid + o]);
        }
        __syncthreads();
    }
    float inv = 1.0f / (rbuf[0] * cbuf[0]);
    for (int e = tid; e < 65536; e += 256) {
        int i = e >> 8, j = e & 255;
        z[e] = (bh16)((float)x[j * 256 + i] * inv);
    }
}

__global__ void final_init_k(const float* __restrict__ fb, float* __restrict__ out)
{
    int i = threadIdx.x;
    if (i < BB_ * NCLASS) out[i] = fb[i % NCLASS];
}

__global__ void __launch_bounds__(256)
final_gemv_k(const float* __restrict__ hbuf, const float* __restrict__ w,
             float* __restrict__ out)
{
    const int b = blockIdx.y;
    const int chunk = blockIdx.x;
    const int tid = threadIdx.x;
    const float* hrow = hbuf + (ll)b * (NVEC * DIM);
    float pc[NCLASS] = {};
    const int k0 = chunk * 8192;
    for (int e = 0; e < 32; ++e) {
        int k = k0 + e * 256 + tid;
        float hv = hrow[k];
        const float* wr = w + (ll)k * NCLASS;
#pragma unroll
        for (int c = 0; c < NCLASS; ++c) pc[c] += hv * wr[c];
    }
    __shared__ float red[256];
    for (int c = 0; c < NCLASS; ++c) {
        red[tid] = pc[c];
        __syncthreads();
        for (int o = 128; o; o >>= 1) {
            if (tid < o) red[tid] += red[tid + o];
            __syncthreads();
        }
        if (tid == 0) atomicAdd(out + b * NCLASS + c, red[0]);
        __syncthreads();
    }
}

// ===========================================================================
extern "C" void kernel_launch(void* const* d_in, const int* in_sizes, int n_in,
                              void* d_out, int out_size, void* d_ws, size_t ws_size,
                              hipStream_t stream)
{
    const float* x      = (const float*)d_in[0];
    const float* lin_w  = (const float*)d_in[1];
    const float* lin_b  = (const float*)d_in[2];
    const float* ln1_g  = (const float*)d_in[3];
    const float* ln1_b  = (const float*)d_in[4];
    const float* qkv_w  = (const float*)d_in[5];
    const float* out_w  = (const float*)d_in[6];
    const float* out_b  = (const float*)d_in[7];
    const float* conv_w = (const float*)d_in[8];
    const float* ln2_g  = (const float*)d_in[9];
    const float* ln2_b  = (const float*)d_in[10];
    const float* ff1_w  = (const float*)d_in[11];
    const float* ff1_b  = (const float*)d_in[12];
    const float* ff2_w  = (const float*)d_in[13];
    const float* ff2_b  = (const float*)d_in[14];
    const float* final_w = (const float*)d_in[15];
    const float* final_b = (const float*)d_in[16];
    float* out = (float*)d_out;
    float* ws  = (float*)d_ws;

    // ---- workspace layout (f32 units), total 56,623,104 f32 = 226.5 MB ----
    float* H    = ws;                                  // [8][4096][512] f32, 16,777,216
    bh16*  QKV  = (bh16*)(ws + 16777216);              // [8][4096][1536] bf16, 25,165,824 f32
    float* P    = ws + 41943040;                       // pool, 10,485,760 f32
    bh16*  qlbf = (bh16*)(ws + 52428800);              // [64bh][256][64] bf16
    bh16*  klbf = (bh16*)(ws + 52953088);
    bh16*  A3Vb = (bh16*)(ws + 53477376);              // [64bh][256][64] bf16
    bh16*  WBb  = (bh16*)(ws + 54001664);
    bh16*  WBT  = (bh16*)(ws + 54525952);              // [64bh][64][256] bf16
    bh16*  WQT  = (bh16*)(ws + 55050240);              // [1536][512] bf16
    bh16*  WOT  = (bh16*)(ws + 55443456);              // [512][512] bf16
    bh16*  F1WT = (bh16*)(ws + 55574528);              // [2048][512] bf16
    bh16*  F2WT = (bh16*)(ws + 56098816);              // [512][2048] bf16
    if (ws_size < 56623104ULL * 4) return;

    // pool aliases (time-sliced)
    bh16*  XLNall = (bh16*)P;                          // [32768][512] bf16 (8,388,608 f32)
    bh16*  ATT3c  = (bh16*)P;                          // [16bh][256][4096] bf16 (8,388,608 f32)
    float* A3Vp   = P + 8388608;                       // [2][8h][8s][256][64] f32 (2,097,152)
    bh16*  CONVa  = (bh16*)P;                          // [8][4096][512] bf16 (8,388,608 f32)
    bh16*  Xbf = (bh16*)P;                             // pinv: 5 x [64][256][256] bf16
    bh16*  Z0  = (bh16*)(P + 2097152);
    bh16*  Z1  = (bh16*)(P + 4194304);
    bh16*  T1  = (bh16*)(P + 6291456);
    bh16*  T2  = (bh16*)(P + 8388608);
    bh16*  ATT1c  = (bh16*)P;                          // [16bh][4096][256] bf16 (8,388,608 f32)
    bh16*  AOUTc  = (bh16*)(P + 8388608);              // [2][4096][512] bf16 (2,097,152 f32)
    bh16*  XLNc   = (bh16*)P;                          // FFN: [8192][512] bf16 (2,097,152 f32)
    bh16*  HIDc   = (bh16*)(P + 2097152);              // [2][4096][2048] bf16 (8,388,608 f32)

    const ll SMP = (ll)NVEC * 1536;                    // qkv stride per sample (bf16)

    // embed
    hipLaunchKernelGGL(embed_k, dim3(65536), dim3(256), 0, stream, x, lin_w, lin_b, H);

    for (int i = 0; i < DEPTH; ++i) {
        const float* wq  = qkv_w + (ll)i * 512 * 1536;
        const float* wo  = out_w + (ll)i * 512 * 512;
        const float* bo  = out_b + (ll)i * 512;
        const float* cw  = conv_w + (ll)i * HEADS * KER;
        const float* g1  = ln1_g + (ll)i * 512;
        const float* b1  = ln1_b + (ll)i * 512;
        const float* g2  = ln2_g + (ll)i * 512;
        const float* b2  = ln2_b + (ll)i * 512;
        const float* f1w = ff1_w + (ll)i * 512 * 2048;
        const float* f1b = ff1_b + (ll)i * 2048;
        const float* f2w = ff2_w + (ll)i * 2048 * 512;
        const float* f2b = ff2_b + (ll)i * 512;

        // weight convert+transpose (bf16 [N][K])
        hipLaunchKernelGGL(cvtT_k, dim3(384), dim3(256), 0, stream, wq, WQT, 1536, 512);
        hipLaunchKernelGGL(cvtT_k, dim3(128), dim3(256), 0, stream, wo, WOT, 512, 512);
        hipLaunchKernelGGL(cvtT_k, dim3(512), dim3(256), 0, stream, f1w, F1WT, 2048, 512);
        hipLaunchKernelGGL(cvtT_k, dim3(512), dim3(256), 0, stream, f2w, F2WT, 512, 2048);

        // LN1 (all samples) + qkv (M=32768, one launch)
        hipLaunchKernelGGL(ln_k, dim3(32768), dim3(256), 0, stream, H, g1, b1, XLNall);
        mg<2,2,0,0,0,1,0>(stream, 32768, 1536, 512, XLNall, 512, WQT, 512,
            QKV, 1536, nullptr, nullptr, 1, 1, 0,0, 0,0, 0,0, 1.f, 0.f);

        // landmarks (all samples)
        hipLaunchKernelGGL(landmarks_k, dim3(4096), dim3(256), 0, stream, QKV, qlbf, klbf);

        // ---- attn3 / softmax / a3v in 2-sample chunks ----
        for (int c = 0; c < 4; ++c) {
            const bh16* qkvc = QKV + (ll)c * 2 * SMP;
            // attn3: z = smp*8+h (BI=8)
            mg<2,2,0,0,0,1,0>(stream, 256, 4096, 64,
                qlbf + (ll)c * 262144, 64, qkvc + 512, 1536,
                ATT3c, 4096, nullptr, nullptr, 16, 8,
                131072, 16384, SMP, 64, 8388608LL, 1048576, 1.f, 0.f);
            hipLaunchKernelGGL(softmax_bf_k, dim3(4096), dim3(256), 0, stream, ATT3c, 4096);
            // a3v (NN via TRB), split-K 8, per sample: z = h*8+s
            for (int s = 0; s < 2; ++s) {
                mg<4,1,1,0,0,0,0>(stream, 256, 64, 512,
                    ATT3c + (ll)s * 8 * 1048576, 4096, qkvc + (ll)s * SMP + 1024, 1536,
                    A3Vp + (ll)s * 1048576, 64, nullptr, nullptr, 64, 8,
                    1048576, 512, 64, 512LL * 1536, 131072, 16384, 1.f, 0.f);
            }
            hipLaunchKernelGGL(a3vred_k, dim3(1024), dim3(256), 0, stream,
                               A3Vp, A3Vb + (ll)c * 2 * 131072);
        }

        // ---- depthwise conv (all samples) + H += conv @ Wo ----
        hipLaunchKernelGGL(conv_k, dim3(2048), dim3(256), 0, stream, QKV, cw, CONVa);
        mg<2,2,0,0,1,0,0>(stream, 32768, 512, 512, CONVa, 512, WOT, 512,
            H, 512, nullptr, nullptr, 1, 1, 0,0, 0,0, 0,0, 1.f, 0.f);

        // ---- pinv (bf16 MFMA, batched 64) ----
        mg<2,2,0,0,0,1,0>(stream, 256, 256, 64, qlbf, 64, klbf, 64,
            Xbf, 256, nullptr, nullptr, 64, 64, 0, 16384, 0, 16384, 0, 65536, 1.f, 0.f);
        hipLaunchKernelGGL(softmax256_k, dim3(2048), dim3(256), 0, stream, Xbf);
        hipLaunchKernelGGL(pinv_init_k, dim3(64), dim3(256), 0, stream, Xbf, Z0);
        bh16* zc = Z0; bh16* zn = Z1;
        for (int it = 0; it < ITERS; ++it) {
            mg<2,2,1,0,0,1,1>(stream, 256, 256, 256, Xbf, 256, zc, 256,
                T1, 256, T2, nullptr, 64, 64, 0, 65536, 0, 65536, 0, 65536, 1.f, 7.f);
            mg<2,2,1,0,0,1,0>(stream, 256, 256, 256, T1, 256, T2, 256,
                zn, 256, nullptr, nullptr, 64, 64, 0, 65536, 0, 65536, 0, 65536, -1.f, 15.f);
            mg<2,2,1,0,0,1,0>(stream, 256, 256, 256, T1, 256, zn, 256,
                T2, 256, nullptr, nullptr, 64, 64, 0, 65536, 0, 65536, 0, 65536, -1.f, 13.f);
            mg<2,2,1,0,0,1,0>(stream, 256, 256, 256, zc, 256, T2, 256,
                zn, 256, nullptr, nullptr, 64, 64, 0, 65536, 0, 65536, 0, 65536, 0.25f, 0.f);
            bh16* t = zc; zc = zn; zn = t;
        }
        // WB = zc @ A3V  (NN)
        mg<4,1,1,0,0,1,0>(stream, 256, 64, 256, zc, 256, A3Vb, 64,
            WBb, 64, nullptr, nullptr, 64, 64, 0, 65536, 0, 16384, 0, 16384, 1.f, 0.f);
        hipLaunchKernelGGL(wbt_k, dim3(512), dim3(256), 0, stream, WBb, WBT);

        // ---- attn1 / softmax / a1@wb / out-proj in 2-sample chunks ----
        for (int c = 0; c < 4; ++c) {
            const bh16* qkvc = QKV + (ll)c * 2 * SMP;
            // attn1 = 0.125 * q @ kl^T; q read in place (lda=1536); z = smp*8+h
            mg<2,2,0,0,0,1,0>(stream, 4096, 256, 64,
                qkvc, 1536, klbf + (ll)c * 262144, 64,
                ATT1c, 256, nullptr, nullptr, 16, 8,
                SMP, 64, 131072, 16384, 8388608LL, 1048576, 0.125f, 0.f);
            hipLaunchKernelGGL(softmax256_k, dim3(8192), dim3(256), 0, stream, ATT1c);
            // aout = attn1 @ wb (heads into cols via ldc=512)
            mg<4,1,0,0,0,1,0>(stream, 4096, 64, 256,
                ATT1c, 256, WBT + (ll)c * 262144, 256,
                AOUTc, 512, nullptr, nullptr, 16, 8,
                8388608LL, 1048576, 131072, 16384, 2097152LL, 64, 1.f, 0.f);
            // H += aout @ Wo + bo   (M=8192)
            mg<2,2,0,0,1,0,0>(stream, 8192, 512, 512, AOUTc, 512, WOT, 512,
                H + (ll)c * 2 * 2097152, 512, nullptr, bo, 1, 1, 0,0, 0,0, 0,0, 1.f, 0.f);
        }

        // ---- FFN in 2-sample chunks ----
        for (int c = 0; c < 4; ++c) {
            float* Hc = H + (ll)c * 2 * 2097152;
            hipLaunchKernelGGL(ln_k, dim3(8192), dim3(256), 0, stream, Hc, g2, b2, XLNc);
            mg<2,2,0,1,0,1,0>(stream, 8192, 2048, 512, XLNc, 512, F1WT, 512,
                HIDc, 2048, nullptr, f1b, 1, 1, 0,0, 0,0, 0,0, 1.f, 0.f);
            mg<2,2,0,0,1,0,0>(stream, 8192, 512, 2048, HIDc, 2048, F2WT, 2048,
                Hc, 512, nullptr, f2b, 1, 1, 0,0, 0,0, 0,0, 1.f, 0.f);
        }
    }

    hipLaunchKernelGGL(final_init_k, dim3(1), dim3(128), 0, stream, final_b, out);
    hipLaunchKernelGGL(final_gemv_k, dim3(256, BB_), dim3(256), 0, stream, H, final_w, out);
}

// Round 10
// 3525.533 us; speedup vs baseline: 4.8226x; 1.0410x over previous
//
#include <hip/hip_runtime.h>
#include <hip/hip_bf16.h>

// Problem constants
#define BB_ 8
#define NVEC 4096
#define DIM 512
#define HEADS 8
#define DH 64
#define MM_ 256
#define ITERS 6
#define DEPTH 2
#define NCLASS 10
#define KER 33
#define INNER 512
#define LSEG 16  // NVEC / MM_

typedef long long ll;
typedef __bf16 bh16;
typedef __attribute__((ext_vector_type(8))) __bf16 bf16x8;
typedef __attribute__((ext_vector_type(4))) float f32x4;

// ===========================================================================
// MFMA bf16 GEMM. TRB=0 (TN): C = A[M,K] @ B_t[N,K]^T. TRB=1 (NN):
// C = A[M,K] @ B[K,N] (B transposed into LDS during staging).
// Tile BM=WR*64 x BN=WC*64, BK=32, 256 threads = 4 waves (WR*WC==4).
// TN staging uses global_load_lds (16B): LDS dest is linear (wave base +
// lane*16); the XOR bank-swizzle is applied to the GLOBAL source address
// (pre-swizzle pattern), so the swizzled-read side is unchanged and the
// bytes landing in each LDS slot are bit-identical to the reg-staged path.
// Epilogue: v = alpha*acc (+bias[col]) (+diagv if row==col) (+GELU).
// DUAL: C gets raw acc, C2 gets diagv*I - acc (both bf16).
// Two-level batch: z -> bo=z/BI (stride sXo), bi=z%BI (stride sXi).
// ===========================================================================
template<int WR, int WC, bool TRB, bool GELU_ACT, bool RESID, bool BF16OUT, bool DUAL>
__global__ void __launch_bounds__(256)
mgemm_k(const bh16* __restrict__ A, const bh16* __restrict__ B,
        const float* __restrict__ bias, void* __restrict__ Cv, void* __restrict__ C2v,
        int K, int lda, int ldb, int ldc,
        int BI, ll sAo, ll sAi, ll sBo, ll sBi, ll sCo, ll sCi,
        float alpha, float diagv)
{
    constexpr int BM = WR * 64, BN = WC * 64;
    const int bz = blockIdx.z;
    const int bo = bz / BI, bi = bz % BI;
    const bh16* Ab = A + bo * sAo + (ll)bi * sAi;
    const bh16* Bb = B + bo * sBo + (ll)bi * sBi;
    const ll coff = bo * sCo + (ll)bi * sCi;
    const int m0 = blockIdx.y * BM;
    const int n0 = blockIdx.x * BN;
    const int tid = threadIdx.x;
    const int lane = tid & 63;
    const int wave = tid >> 6;
    const int wr = wave / WC, wc = wave % WC;

    __shared__ bh16 Al[BM * 32];
    __shared__ bh16 Bl[BN * 32];

    f32x4 acc[4][4];
#pragma unroll
    for (int i = 0; i < 4; ++i)
#pragma unroll
        for (int j = 0; j < 4; ++j) acc[i][j] = (f32x4){0.f, 0.f, 0.f, 0.f};

    const int srow = tid >> 2;   // 0..63
    const int ssl  = tid & 3;    // 16B slot (linear LDS dest)

    const int rsel  = ((lane & 15) >> 1) & 3;
    const int kslot = lane >> 4;

    for (int k0 = 0; k0 < K; k0 += 32) {
        __syncthreads();
#pragma unroll
        for (int i = 0; i < BM / 64; ++i) {
            int row = i * 64 + srow;
            int gsl = ssl ^ ((row >> 1) & 3);   // pre-swizzled global source slot
            __builtin_amdgcn_global_load_lds(
                (const __attribute__((address_space(1))) unsigned int*)
                    (Ab + (ll)(m0 + row) * lda + k0 + gsl * 8),
                (__attribute__((address_space(3))) unsigned int*)
                    (Al + row * 32 + ssl * 8),
                16, 0, 0);
        }
        if (!TRB) {
#pragma unroll
            for (int i = 0; i < BN / 64; ++i) {
                int row = i * 64 + srow;
                int gsl = ssl ^ ((row >> 1) & 3);
                __builtin_amdgcn_global_load_lds(
                    (const __attribute__((address_space(1))) unsigned int*)
                        (Bb + (ll)(n0 + row) * ldb + k0 + gsl * 8),
                    (__attribute__((address_space(3))) unsigned int*)
                        (Bl + row * 32 + ssl * 8),
                    16, 0, 0);
            }
        } else {
            // B stored [K][N]; transpose into LDS [n][k] with matching swizzle
            const int bk = tid >> 3;                 // 0..31
            const int nb0 = (tid & 7) * (BN / 8);
#pragma unroll
            for (int v8 = 0; v8 < BN / 64; ++v8) {
                int nb = nb0 + v8 * 8;
                bf16x8 v = *(const bf16x8*)(Bb + (ll)(k0 + bk) * ldb + n0 + nb);
#pragma unroll
                for (int j = 0; j < 8; ++j) {
                    int n = nb + j;
                    int sl = (bk >> 3) ^ ((n >> 1) & 3);
                    Bl[n * 32 + sl * 8 + (bk & 7)] = v[j];
                }
            }
        }
        __syncthreads();

        bf16x8 af[4], bfr[4];
#pragma unroll
        for (int mi = 0; mi < 4; ++mi) {
            int row = wr * 64 + mi * 16 + (lane & 15);
            af[mi] = *(const bf16x8*)(Al + row * 32 + (kslot ^ rsel) * 8);
        }
#pragma unroll
        for (int ni = 0; ni < 4; ++ni) {
            int row = wc * 64 + ni * 16 + (lane & 15);
            bfr[ni] = *(const bf16x8*)(Bl + row * 32 + (kslot ^ rsel) * 8);
        }
#pragma unroll
        for (int mi = 0; mi < 4; ++mi)
#pragma unroll
            for (int ni = 0; ni < 4; ++ni)
                acc[mi][ni] = __builtin_amdgcn_mfma_f32_16x16x32_bf16(
                    af[mi], bfr[ni], acc[mi][ni], 0, 0, 0);
    }

#pragma unroll
    for (int mi = 0; mi < 4; ++mi) {
#pragma unroll
        for (int ni = 0; ni < 4; ++ni) {
            const int colg = n0 + wc * 64 + ni * 16 + (lane & 15);
            const float bia = (!DUAL && bias) ? bias[colg] : 0.f;
#pragma unroll
            for (int r = 0; r < 4; ++r) {
                const int rowg = m0 + wr * 64 + mi * 16 + (lane >> 4) * 4 + r;
                const float a = acc[mi][ni][r];
                const ll off = coff + (ll)rowg * ldc + colg;
                if (DUAL) {
                    ((bh16*)Cv)[off] = (bh16)a;
                    float w = ((rowg == colg) ? diagv : 0.f) - a;
                    ((bh16*)C2v)[off] = (bh16)w;
                } else {
                    float v = alpha * a + bia;
                    if (diagv != 0.f && rowg == colg) v += diagv;
                    if (GELU_ACT) {
                        float t = tanhf(0.7978845608f * (v + 0.044715f * v * v * v));
                        v = 0.5f * v * (1.0f + t);
                    }
                    if (BF16OUT) {
                        ((bh16*)Cv)[off] = (bh16)v;
                    } else {
                        float* p = (float*)Cv + off;
                        float o = v;
                        if (RESID) o += *p;
                        *p = o;
                    }
                }
            }
        }
    }
}

template<int WR, int WC, bool TRB, bool G, bool R, bool BO, bool D>
static inline void mg(hipStream_t s, int M, int N, int K,
                      const bh16* A, int lda, const bh16* B, int ldb,
                      void* C, int ldc, void* C2, const float* bias,
                      int batch, int BI,
                      ll sAo, ll sAi, ll sBo, ll sBi, ll sCo, ll sCi,
                      float alpha, float diagv)
{
    dim3 grid(N / (WC * 64), M / (WR * 64), batch);
    hipLaunchKernelGGL((mgemm_k<WR, WC, TRB, G, R, BO, D>), grid, dim3(256), 0, s,
                       A, B, bias, C, C2, K, lda, ldb, ldc, BI,
                       sAo, sAi, sBo, sBi, sCo, sCi, alpha, diagv);
}

// ===========================================================================
// Small kernels
// ===========================================================================
__global__ void embed_k(const float* __restrict__ x, const float* __restrict__ w,
                        const float* __restrict__ b, float* __restrict__ h)
{
    ll idx = (ll)blockIdx.x * 256 + threadIdx.x;
    int d = (int)(idx & 511);
    ll bn = idx >> 9;
    h[idx] = x[bn * 2] * w[d] + x[bn * 2 + 1] * w[512 + d] + b[d];
}

// LayerNorm, bf16 output; one block per row of 512
__global__ void __launch_bounds__(256)
ln_k(const float* __restrict__ X, const float* __restrict__ g,
     const float* __restrict__ bta, bh16* __restrict__ Y)
{
    const ll row = blockIdx.x;
    const float* x = X + row * 512;
    bh16* y = Y + row * 512;
    const int tid = threadIdx.x;
    float v0 = x[tid], v1 = x[tid + 256];
    float s = v0 + v1;
    float q = v0 * v0 + v1 * v1;
    __shared__ float sred[8];
    for (int o = 32; o; o >>= 1) { s += __shfl_down(s, o); q += __shfl_down(q, o); }
    const int lane = tid & 63, w = tid >> 6;
    if (lane == 0) { sred[w] = s; sred[4 + w] = q; }
    __syncthreads();
    float ssum = sred[0] + sred[1] + sred[2] + sred[3];
    float qsum = sred[4] + sred[5] + sred[6] + sred[7];
    float mu = ssum * (1.0f / 512.0f);
    float var = qsum * (1.0f / 512.0f) - mu * mu;
    float r = rsqrtf(var + 1e-5f);
    y[tid] = (bh16)((v0 - mu) * r * g[tid] + bta[tid]);
    y[tid + 256] = (bh16)((v1 - mu) * r * g[tid + 256] + bta[tid + 256]);
}

// weight f32 [R][C] -> bf16 [C][R]; 64x64 LDS-tiled transpose.
// grid = (C/64)*(R/64) blocks of 256 threads.
__global__ void __launch_bounds__(256)
cvtT_k(const float* __restrict__ in, bh16* __restrict__ outp, int C, int R)
{
    __shared__ float t[64][65];
    const int nCt = C >> 6;
    const int c0 = (blockIdx.x % nCt) * 64;
    const int r0 = (blockIdx.x / nCt) * 64;
    const int tid = threadIdx.x;
#pragma unroll
    for (int j = 0; j < 16; ++j) {
        int idx = j * 256 + tid;
        int lr = idx >> 6, lc = idx & 63;
        t[lc][lr] = in[(ll)(r0 + lr) * C + c0 + lc];
    }
    __syncthreads();
#pragma unroll
    for (int v = 0; v < 2; ++v) {
        int flat = v * 256 + tid;
        int lc = flat >> 3, r8 = (flat & 7) * 8;
        bf16x8 o;
#pragma unroll
        for (int j = 0; j < 8; ++j) o[j] = (bh16)t[lc][r8 + j];
        *(bf16x8*)(outp + (ll)(c0 + lc) * R + r0 + r8) = o;
    }
}

// landmark means for ALL samples; ql pre-scaled by DH^-0.5
__global__ void landmarks_k(const bh16* __restrict__ qkv,
                            bh16* __restrict__ qlb, bh16* __restrict__ klb)
{
    int idx = blockIdx.x * 256 + threadIdx.x;   // 8*8*256*64 = 1,048,576
    int d = idx & 63;
    int m = (idx >> 6) & 255;
    int h = (idx >> 14) & 7;
    int b = idx >> 17;
    const bh16* base = qkv + (ll)b * (NVEC * 1536) + (ll)(m * LSEG) * 1536 + h * 64 + d;
    float sq = 0.f, sk = 0.f;
#pragma unroll
    for (int l = 0; l < LSEG; ++l) {
        sq += (float)base[(ll)l * 1536];
        sk += (float)base[(ll)l * 1536 + 512];
    }
    ll o = (ll)(b * 8 + h) * 16384 + m * 64 + d;
    qlb[o] = (bh16)(sq * (0.0625f * 0.125f));
    klb[o] = (bh16)(sk * 0.0625f);
}

// wb bf16 [bh][256][64] -> wbT bf16 [bh][64][256]
__global__ void wbt_k(const bh16* __restrict__ wb, bh16* __restrict__ wbt)
{
    int idx = blockIdx.x * 256 + threadIdx.x;   // 131072
    int d = idx & 63, kg = (idx >> 6) & 31, bhh = idx >> 11;
    const bh16* p = wb + (ll)bhh * 16384 + kg * 8 * 64 + d;
    bf16x8 o;
#pragma unroll
    for (int j = 0; j < 8; ++j) o[j] = p[j * 64];
    *(bf16x8*)(wbt + (ll)bhh * 16384 + d * 256 + kg * 8) = o;
}

// reduce split-K partials for a 2-sample chunk:
// part [2][8h][8s][256][64] f32 -> A3Vb bf16 at [bh0+smp*8+h][256][64]
__global__ void a3vred_k(const float* __restrict__ part, bh16* __restrict__ outp)
{
    int idx = blockIdx.x * 256 + threadIdx.x;   // 262144
    int smp = idx >> 17;
    int rest = idx & 131071;
    int h = rest >> 14, o = rest & 16383;
    const float* p = part + (ll)smp * 1048576 + (ll)h * 131072 + o;
    float s = 0.f;
#pragma unroll
    for (int j = 0; j < 8; ++j) s += p[j * 16384];
    outp[(ll)(smp * 8 + h) * 16384 + o] = (bh16)s;
}

// ---------------------------------------------------------------------------
// Depthwise conv, sliding-window vectorized: thread = (b, 4 n's, 8 channels).
// ---------------------------------------------------------------------------
__global__ void __launch_bounds__(256)
conv_k(const bh16* __restrict__ qkv, const float* __restrict__ cw,
       bh16* __restrict__ convo)
{
    int idx = blockIdx.x * 256 + threadIdx.x;   // 8*1024*64 = 524288
    int c8 = idx & 63;                          // 8-channel group
    int ng = (idx >> 6) & 1023;                 // n-group (4 n's)
    int b  = idx >> 16;
    const int n0 = ng * 4;
    const int h = c8 >> 3;
    const bh16* v = qkv + (ll)b * (NVEC * 1536) + 1024 + c8 * 8;

    float wreg[KER];
#pragma unroll
    for (int k = 0; k < KER; ++k) wreg[k] = cw[h * KER + k];

    float acc[4][8];
#pragma unroll
    for (int t = 0; t < 4; ++t)
#pragma unroll
        for (int e = 0; e < 8; ++e) acc[t][e] = 0.f;

#pragma unroll
    for (int m = 0; m < 36; ++m) {
        int nn = n0 + m - (KER / 2);
        bf16x8 vv = {};
        if ((unsigned)nn < (unsigned)NVEC)
            vv = *(const bf16x8*)(v + (ll)nn * 1536);
#pragma unroll
        for (int t = 0; t < 4; ++t) {
            constexpr int KMAX = KER - 1;
            int k = m - t;
            if (k >= 0 && k <= KMAX) {
                float wk = wreg[k];
#pragma unroll
                for (int e = 0; e < 8; ++e)
                    acc[t][e] = fmaf((float)vv[e], wk, acc[t][e]);
            }
        }
    }

    bh16* o = convo + (ll)b * (NVEC * 512) + (ll)n0 * 512 + c8 * 8;
#pragma unroll
    for (int t = 0; t < 4; ++t) {
        bf16x8 ov;
#pragma unroll
        for (int e = 0; e < 8; ++e) ov[e] = (bh16)acc[t][e];
        *(bf16x8*)(o + (ll)t * 512) = ov;
    }
}

// -------- softmax helpers --------
__device__ __forceinline__ float blkmax(float m, float* red, int tid)
{
#pragma unroll
    for (int o = 32; o; o >>= 1) m = fmaxf(m, __shfl_down(m, o));
    if ((tid & 63) == 0) red[tid >> 6] = m;
    __syncthreads();
    m = fmaxf(fmaxf(red[0], red[1]), fmaxf(red[2], red[3]));
    __syncthreads();
    return m;
}
__device__ __forceinline__ float blksum(float s, float* red, int tid)
{
#pragma unroll
    for (int o = 32; o; o >>= 1) s += __shfl_down(s, o);
    if ((tid & 63) == 0) red[tid >> 6] = s;
    __syncthreads();
    s = red[0] + red[1] + red[2] + red[3];
    __syncthreads();
    return s;
}

// in-place bf16 row softmax, L == 4096; one block (256 thr) per row
__global__ void __launch_bounds__(256)
softmax_bf_k(bh16* __restrict__ X, int L)
{
    const ll row = blockIdx.x;
    bh16* x = X + row * (ll)L;
    const int tid = threadIdx.x;
    __shared__ float red[4];
    float v[16];
    bf16x8 a = *(const bf16x8*)(x + tid * 8);
    bf16x8 b = *(const bf16x8*)(x + 2048 + tid * 8);
#pragma unroll
    for (int j = 0; j < 8; ++j) { v[j] = (float)a[j]; v[8 + j] = (float)b[j]; }
    float m = -1e30f;
#pragma unroll
    for (int j = 0; j < 16; ++j) m = fmaxf(m, v[j]);
    m = blkmax(m, red, tid);
    float s = 0.f;
#pragma unroll
    for (int j = 0; j < 16; ++j) { v[j] = __expf(v[j] - m); s += v[j]; }
    s = blksum(s, red, tid);
    float inv = 1.0f / s;
    bf16x8 oa, ob;
#pragma unroll
    for (int j = 0; j < 8; ++j) { oa[j] = (bh16)(v[j] * inv); ob[j] = (bh16)(v[8 + j] * inv); }
    *(bf16x8*)(x + tid * 8) = oa;
    *(bf16x8*)(x + 2048 + tid * 8) = ob;
}

// in-place bf16 row softmax, L == 256: one row per 32-lane group, 8 rows/block
__global__ void __launch_bounds__(256)
softmax256_k(bh16* __restrict__ X)
{
    const int tid = threadIdx.x;
    const ll row = (ll)blockIdx.x * 8 + (tid >> 5);
    const int l = tid & 31;
    bh16* x = X + row * 256 + l * 8;
    bf16x8 a = *(const bf16x8*)x;
    float v[8];
#pragma unroll
    for (int j = 0; j < 8; ++j) v[j] = (float)a[j];
    float m = -1e30f;
#pragma unroll
    for (int j = 0; j < 8; ++j) m = fmaxf(m, v[j]);
#pragma unroll
    for (int o = 16; o; o >>= 1) m = fmaxf(m, __shfl_xor(m, o, 32));
    float s = 0.f;
#pragma unroll
    for (int j = 0; j < 8; ++j) { v[j] = __expf(v[j] - m); s += v[j]; }
#pragma unroll
    for (int o = 16; o; o >>= 1) s += __shfl_xor(s, o, 32);
    float inv = 1.0f / s;
    bf16x8 ov;
#pragma unroll
    for (int j = 0; j < 8; ++j) ov[j] = (bh16)(v[j] * inv);
    *(bf16x8*)x = ov;
}

// z0 = x^T / (max_rowsum * max_colsum), bf16 in/out, f32 math
__global__ void __launch_bounds__(256)
pinv_init_k(const bh16* __restrict__ X, bh16* __restrict__ Z)
{
    const ll bh = blockIdx.x;
    const bh16* x = X + bh * 65536;
    bh16* z = Z + bh * 65536;
    const int tid = threadIdx.x;
    float rs = 0.f, cs = 0.f;
    for (int j = 0; j < 256; ++j) {
        rs += fabsf((float)x[tid * 256 + j]);
        cs += fabsf((float)x[j * 256 + tid]);
    }
    __shared__ float rbuf[256], cbuf[256];
    rbuf[tid] = rs; cbuf[tid] = cs;
    __syncthreads();
    for (int o = 128; o; o >>= 1) {
        if (tid < o) {
            rbuf[tid] = fmaxf(rbuf[tid], rbuf[tid + o]);
            cbuf[tid] = fmaxf(cbuf[tid], cbuf[tid + o]);
        }
        __syncthreads();
    }
    float inv = 1.0f / (rbuf[0] * cbuf[0]);
    for (int e = tid; e < 65536; e += 256) {
        int i = e >> 8, j = e & 255;
        z[e] = (bh16)((float)x[j * 256 + i] * inv);
    }
}

__global__ void final_init_k(const float* __restrict__ fb, float* __restrict__ out)
{
    int i = threadIdx.x;
    if (i < BB_ * NCLASS) out[i] = fb[i % NCLASS];
}

// grid (256 chunks, 2 halves); block handles 8192 k's for 4 samples so the
// final_w chunk is read ONCE per 4 samples (was once per sample: 316 MB fetch).
__global__ void __launch_bounds__(256)
final_gemv_k(const float* __restrict__ hbuf, const float* __restrict__ w,
             float* __restrict__ out)
{
    const int half = blockIdx.y;
    const int chunk = blockIdx.x;
    const int tid = threadIdx.x;
    const int k0 = chunk * 8192;
    float pc[4][NCLASS] = {};
    for (int e = 0; e < 32; ++e) {
        int k = k0 + e * 256 + tid;
        const float* wr = w + (ll)k * NCLASS;
        float wv[NCLASS];
#pragma unroll
        for (int c = 0; c < NCLASS; ++c) wv[c] = wr[c];
#pragma unroll
        for (int b = 0; b < 4; ++b) {
            float hv = hbuf[(ll)(half * 4 + b) * (NVEC * DIM) + k];
#pragma unroll
            for (int c = 0; c < NCLASS; ++c) pc[b][c] = fmaf(hv, wv[c], pc[b][c]);
        }
    }
    __shared__ float red[4][4][NCLASS];
    const int lane = tid & 63, wv_ = tid >> 6;
#pragma unroll
    for (int b = 0; b < 4; ++b)
#pragma unroll
        for (int c = 0; c < NCLASS; ++c) {
            float s = pc[b][c];
#pragma unroll
            for (int o = 32; o; o >>= 1) s += __shfl_down(s, o);
            if (lane == 0) red[wv_][b][c] = s;
        }
    __syncthreads();
    if (tid < 4 * NCLASS) {
        int b = tid / NCLASS, c = tid % NCLASS;
        float s = red[0][b][c] + red[1][b][c] + red[2][b][c] + red[3][b][c];
        atomicAdd(out + (half * 4 + b) * NCLASS + c, s);
    }
}

// ===========================================================================
extern "C" void kernel_launch(void* const* d_in, const int* in_sizes, int n_in,
                              void* d_out, int out_size, void* d_ws, size_t ws_size,
                              hipStream_t stream)
{
    const float* x      = (const float*)d_in[0];
    const float* lin_w  = (const float*)d_in[1];
    const float* lin_b  = (const float*)d_in[2];
    const float* ln1_g  = (const float*)d_in[3];
    const float* ln1_b  = (const float*)d_in[4];
    const float* qkv_w  = (const float*)d_in[5];
    const float* out_w  = (const float*)d_in[6];
    const float* out_b  = (const float*)d_in[7];
    const float* conv_w = (const float*)d_in[8];
    const float* ln2_g  = (const float*)d_in[9];
    const float* ln2_b  = (const float*)d_in[10];
    const float* ff1_w  = (const float*)d_in[11];
    const float* ff1_b  = (const float*)d_in[12];
    const float* ff2_w  = (const float*)d_in[13];
    const float* ff2_b  = (const float*)d_in[14];
    const float* final_w = (const float*)d_in[15];
    const float* final_b = (const float*)d_in[16];
    float* out = (float*)d_out;
    float* ws  = (float*)d_ws;

    // ---- workspace layout (f32 units), total 56,623,104 f32 = 226.5 MB ----
    float* H    = ws;                                  // [8][4096][512] f32, 16,777,216
    bh16*  QKV  = (bh16*)(ws + 16777216);              // [8][4096][1536] bf16, 25,165,824 f32
    float* P    = ws + 41943040;                       // pool, 10,485,760 f32
    bh16*  qlbf = (bh16*)(ws + 52428800);              // [64bh][256][64] bf16
    bh16*  klbf = (bh16*)(ws + 52953088);
    bh16*  A3Vb = (bh16*)(ws + 53477376);              // [64bh][256][64] bf16
    bh16*  WBb  = (bh16*)(ws + 54001664);
    bh16*  WBT  = (bh16*)(ws + 54525952);              // [64bh][64][256] bf16
    bh16*  WQT  = (bh16*)(ws + 55050240);              // [1536][512] bf16
    bh16*  WOT  = (bh16*)(ws + 55443456);              // [512][512] bf16
    bh16*  F1WT = (bh16*)(ws + 55574528);              // [2048][512] bf16
    bh16*  F2WT = (bh16*)(ws + 56098816);              // [512][2048] bf16
    if (ws_size < 56623104ULL * 4) return;

    // pool aliases (time-sliced)
    bh16*  XLNall = (bh16*)P;                          // [32768][512] bf16 (8,388,608 f32)
    bh16*  ATT3c  = (bh16*)P;                          // [16bh][256][4096] bf16 (8,388,608 f32)
    float* A3Vp   = P + 8388608;                       // [2][8h][8s][256][64] f32 (2,097,152)
    bh16*  CONVa  = (bh16*)P;                          // [8][4096][512] bf16 (8,388,608 f32)
    bh16*  Xbf = (bh16*)P;                             // pinv: 5 x [64][256][256] bf16
    bh16*  Z0  = (bh16*)(P + 2097152);
    bh16*  Z1  = (bh16*)(P + 4194304);
    bh16*  T1  = (bh16*)(P + 6291456);
    bh16*  T2  = (bh16*)(P + 8388608);
    bh16*  ATT1c  = (bh16*)P;                          // [16bh][4096][256] bf16 (8,388,608 f32)
    bh16*  AOUTc  = (bh16*)(P + 8388608);              // [2][4096][512] bf16 (2,097,152 f32)
    bh16*  XLNc   = (bh16*)P;                          // FFN: [8192][512] bf16 (2,097,152 f32)
    bh16*  HIDc   = (bh16*)(P + 2097152);              // [2][4096][2048] bf16 (8,388,608 f32)

    const ll SMP = (ll)NVEC * 1536;                    // qkv stride per sample (bf16)

    // embed
    hipLaunchKernelGGL(embed_k, dim3(65536), dim3(256), 0, stream, x, lin_w, lin_b, H);

    for (int i = 0; i < DEPTH; ++i) {
        const float* wq  = qkv_w + (ll)i * 512 * 1536;
        const float* wo  = out_w + (ll)i * 512 * 512;
        const float* bo  = out_b + (ll)i * 512;
        const float* cw  = conv_w + (ll)i * HEADS * KER;
        const float* g1  = ln1_g + (ll)i * 512;
        const float* b1  = ln1_b + (ll)i * 512;
        const float* g2  = ln2_g + (ll)i * 512;
        const float* b2  = ln2_b + (ll)i * 512;
        const float* f1w = ff1_w + (ll)i * 512 * 2048;
        const float* f1b = ff1_b + (ll)i * 2048;
        const float* f2w = ff2_w + (ll)i * 2048 * 512;
        const float* f2b = ff2_b + (ll)i * 512;

        // weight convert+transpose (bf16 [N][K]); LDS-tiled
        hipLaunchKernelGGL(cvtT_k, dim3(192), dim3(256), 0, stream, wq, WQT, 1536, 512);
        hipLaunchKernelGGL(cvtT_k, dim3(64), dim3(256), 0, stream, wo, WOT, 512, 512);
        hipLaunchKernelGGL(cvtT_k, dim3(256), dim3(256), 0, stream, f1w, F1WT, 2048, 512);
        hipLaunchKernelGGL(cvtT_k, dim3(256), dim3(256), 0, stream, f2w, F2WT, 512, 2048);

        // LN1 (all samples) + qkv (M=32768, one launch)
        hipLaunchKernelGGL(ln_k, dim3(32768), dim3(256), 0, stream, H, g1, b1, XLNall);
        mg<2,2,0,0,0,1,0>(stream, 32768, 1536, 512, XLNall, 512, WQT, 512,
            QKV, 1536, nullptr, nullptr, 1, 1, 0,0, 0,0, 0,0, 1.f, 0.f);

        // landmarks (all samples)
        hipLaunchKernelGGL(landmarks_k, dim3(4096), dim3(256), 0, stream, QKV, qlbf, klbf);

        // ---- attn3 / softmax / a3v in 2-sample chunks ----
        for (int c = 0; c < 4; ++c) {
            const bh16* qkvc = QKV + (ll)c * 2 * SMP;
            // attn3: z = smp*8+h (BI=8)
            mg<2,2,0,0,0,1,0>(stream, 256, 4096, 64,
                qlbf + (ll)c * 262144, 64, qkvc + 512, 1536,
                ATT3c, 4096, nullptr, nullptr, 16, 8,
                131072, 16384, SMP, 64, 8388608LL, 1048576, 1.f, 0.f);
            hipLaunchKernelGGL(softmax_bf_k, dim3(4096), dim3(256), 0, stream, ATT3c, 4096);
            // a3v (NN via TRB), split-K 8, per sample: z = h*8+s
            for (int s = 0; s < 2; ++s) {
                mg<4,1,1,0,0,0,0>(stream, 256, 64, 512,
                    ATT3c + (ll)s * 8 * 1048576, 4096, qkvc + (ll)s * SMP + 1024, 1536,
                    A3Vp + (ll)s * 1048576, 64, nullptr, nullptr, 64, 8,
                    1048576, 512, 64, 512LL * 1536, 131072, 16384, 1.f, 0.f);
            }
            hipLaunchKernelGGL(a3vred_k, dim3(1024), dim3(256), 0, stream,
                               A3Vp, A3Vb + (ll)c * 2 * 131072);
        }

        // ---- depthwise conv (all samples) + H += conv @ Wo ----
        hipLaunchKernelGGL(conv_k, dim3(2048), dim3(256), 0, stream, QKV, cw, CONVa);
        mg<2,2,0,0,1,0,0>(stream, 32768, 512, 512, CONVa, 512, WOT, 512,
            H, 512, nullptr, nullptr, 1, 1, 0,0, 0,0, 0,0, 1.f, 0.f);

        // ---- pinv (bf16 MFMA, batched 64) ----
        mg<2,2,0,0,0,1,0>(stream, 256, 256, 64, qlbf, 64, klbf, 64,
            Xbf, 256, nullptr, nullptr, 64, 64, 0, 16384, 0, 16384, 0, 65536, 1.f, 0.f);
        hipLaunchKernelGGL(softmax256_k, dim3(2048), dim3(256), 0, stream, Xbf);
        hipLaunchKernelGGL(pinv_init_k, dim3(64), dim3(256), 0, stream, Xbf, Z0);
        bh16* zc = Z0; bh16* zn = Z1;
        for (int it = 0; it < ITERS; ++it) {
            mg<2,2,1,0,0,1,1>(stream, 256, 256, 256, Xbf, 256, zc, 256,
                T1, 256, T2, nullptr, 64, 64, 0, 65536, 0, 65536, 0, 65536, 1.f, 7.f);
            mg<2,2,1,0,0,1,0>(stream, 256, 256, 256, T1, 256, T2, 256,
                zn, 256, nullptr, nullptr, 64, 64, 0, 65536, 0, 65536, 0, 65536, -1.f, 15.f);
            mg<2,2,1,0,0,1,0>(stream, 256, 256, 256, T1, 256, zn, 256,
                T2, 256, nullptr, nullptr, 64, 64, 0, 65536, 0, 65536, 0, 65536, -1.f, 13.f);
            mg<2,2,1,0,0,1,0>(stream, 256, 256, 256, zc, 256, T2, 256,
                zn, 256, nullptr, nullptr, 64, 64, 0, 65536, 0, 65536, 0, 65536, 0.25f, 0.f);
            bh16* t = zc; zc = zn; zn = t;
        }
        // WB = zc @ A3V  (NN)
        mg<4,1,1,0,0,1,0>(stream, 256, 64, 256, zc, 256, A3Vb, 64,
            WBb, 64, nullptr, nullptr, 64, 64, 0, 65536, 0, 16384, 0, 16384, 1.f, 0.f);
        hipLaunchKernelGGL(wbt_k, dim3(512), dim3(256), 0, stream, WBb, WBT);

        // ---- attn1 / softmax / a1@wb / out-proj in 2-sample chunks ----
        for (int c = 0; c < 4; ++c) {
            const bh16* qkvc = QKV + (ll)c * 2 * SMP;
            // attn1 = 0.125 * q @ kl^T; q read in place (lda=1536); z = smp*8+h
            mg<2,2,0,0,0,1,0>(stream, 4096, 256, 64,
                qkvc, 1536, klbf + (ll)c * 262144, 64,
                ATT1c, 256, nullptr, nullptr, 16, 8,
                SMP, 64, 131072, 16384, 8388608LL, 1048576, 0.125f, 0.f);
            hipLaunchKernelGGL(softmax256_k, dim3(8192), dim3(256), 0, stream, ATT1c);
            // aout = attn1 @ wb (heads into cols via ldc=512)
            mg<4,1,0,0,0,1,0>(stream, 4096, 64, 256,
                ATT1c, 256, WBT + (ll)c * 262144, 256,
                AOUTc, 512, nullptr, nullptr, 16, 8,
                8388608LL, 1048576, 131072, 16384, 2097152LL, 64, 1.f, 0.f);
            // H += aout @ Wo + bo   (M=8192)
            mg<2,2,0,0,1,0,0>(stream, 8192, 512, 512, AOUTc, 512, WOT, 512,
                H + (ll)c * 2 * 2097152, 512, nullptr, bo, 1, 1, 0,0, 0,0, 0,0, 1.f, 0.f);
        }

        // ---- FFN in 2-sample chunks ----
        for (int c = 0; c < 4; ++c) {
            float* Hc = H + (ll)c * 2 * 2097152;
            hipLaunchKernelGGL(ln_k, dim3(8192), dim3(256), 0, stream, Hc, g2, b2, XLNc);
            mg<2,2,0,1,0,1,0>(stream, 8192, 2048, 512, XLNc, 512, F1WT, 512,
                HIDc, 2048, nullptr, f1b, 1, 1, 0,0, 0,0, 0,0, 1.f, 0.f);
            mg<2,2,0,0,1,0,0>(stream, 8192, 512, 2048, HIDc, 2048, F2WT, 2048,
                Hc, 512, nullptr, f2b, 1, 1, 0,0, 0,0, 0,0, 1.f, 0.f);
        }
    }

    hipLaunchKernelGGL(final_init_k, dim3(1), dim3(128), 0, stream, final_b, out);
    hipLaunchKernelGGL(final_gemv_k, dim3(256, 2), dim3(256), 0, stream, H, final_w, out);
}

// Round 11
// 3388.221 us; speedup vs baseline: 5.0180x; 1.0405x over previous
//
#include <hip/hip_runtime.h>
#include <hip/hip_bf16.h>

// Problem constants
#define BB_ 8
#define NVEC 4096
#define DIM 512
#define HEADS 8
#define DH 64
#define MM_ 256
#define ITERS 6
#define DEPTH 2
#define NCLASS 10
#define KER 33
#define INNER 512
#define LSEG 16  // NVEC / MM_

typedef long long ll;
typedef __bf16 bh16;
typedef __attribute__((ext_vector_type(8))) __bf16 bf16x8;
typedef __attribute__((ext_vector_type(4))) float f32x4;

// ===========================================================================
// MFMA bf16 GEMM. TRB=0 (TN): C = A[M,K] @ B_t[N,K]^T. TRB=1 (NN).
// Tile BM=WR*64 x BN=WC*64, BK=32, 256 threads = 4 waves (WR*WC==4).
// XCD-bijective block swizzle (m204) for L2 A-panel locality.
// SMAX: (requires WR==1, gridDim.x==1) fused row-softmax epilogue; writes
//       normalized P (bf16). alpha applied to scores before softmax.
// ADDC: adds bf16 C2[off2] (ldc2/sC2o/sC2i) to acc before output (conv fold).
// DUAL: C gets raw acc, C2 gets diagv*I - acc (both bf16, same geometry).
// Two-level batch: z -> bo=z/BI (stride sXo), bi=z%BI (stride sXi).
// ===========================================================================
template<int WR, int WC, bool TRB, bool GELU_ACT, bool RESID, bool BF16OUT,
         bool DUAL, bool SMAX, bool ADDC>
__global__ void __launch_bounds__(256)
mgemm_k(const bh16* __restrict__ A, const bh16* __restrict__ B,
        const float* __restrict__ bias, void* __restrict__ Cv, void* __restrict__ C2v,
        int K, int lda, int ldb, int ldc,
        int BI, ll sAo, ll sAi, ll sBo, ll sBi, ll sCo, ll sCi,
        int ldc2, ll sC2o, ll sC2i,
        float alpha, float diagv)
{
    constexpr int BM = WR * 64, BN = WC * 64;
    const int bz = blockIdx.z;
    const int bo = bz / BI, bi = bz % BI;
    const bh16* Ab = A + bo * sAo + (ll)bi * sAi;
    const bh16* Bb = B + bo * sBo + (ll)bi * sBi;
    const ll coff = bo * sCo + (ll)bi * sCi;

    // XCD-bijective swizzle of (y,x) tile coords (m204)
    const int gx = gridDim.x;
    const int nwg = gx * gridDim.y;
    int flat = blockIdx.y * gx + blockIdx.x;
    {
        int xcd = flat & 7, base = flat >> 3;
        int q = nwg >> 3, rr = nwg & 7;
        flat = (xcd < rr ? xcd * (q + 1) : rr * (q + 1) + (xcd - rr) * q) + base;
    }
    const int m0 = (flat / gx) * BM;
    const int n0 = (flat % gx) * BN;

    const int tid = threadIdx.x;
    const int lane = tid & 63;
    const int wave = tid >> 6;
    const int wr = wave / WC, wc = wave % WC;

    __shared__ bh16 Al[BM * 32];
    __shared__ bh16 Bl[BN * 32];
    __shared__ float srow[SMAX ? 4 * 64 : 4];

    f32x4 acc[4][4];
#pragma unroll
    for (int i = 0; i < 4; ++i)
#pragma unroll
        for (int j = 0; j < 4; ++j) acc[i][j] = (f32x4){0.f, 0.f, 0.f, 0.f};

    const int srowi = tid >> 2;  // 0..63
    const int ssl   = tid & 3;   // 16B slot (linear LDS dest)

    const int rsel  = ((lane & 15) >> 1) & 3;
    const int kslot = lane >> 4;

    for (int k0 = 0; k0 < K; k0 += 32) {
        __syncthreads();
#pragma unroll
        for (int i = 0; i < BM / 64; ++i) {
            int row = i * 64 + srowi;
            int gsl = ssl ^ ((row >> 1) & 3);   // pre-swizzled global source slot
            __builtin_amdgcn_global_load_lds(
                (const __attribute__((address_space(1))) unsigned int*)
                    (Ab + (ll)(m0 + row) * lda + k0 + gsl * 8),
                (__attribute__((address_space(3))) unsigned int*)
                    (Al + row * 32 + ssl * 8),
                16, 0, 0);
        }
        if (!TRB) {
#pragma unroll
            for (int i = 0; i < BN / 64; ++i) {
                int row = i * 64 + srowi;
                int gsl = ssl ^ ((row >> 1) & 3);
                __builtin_amdgcn_global_load_lds(
                    (const __attribute__((address_space(1))) unsigned int*)
                        (Bb + (ll)(n0 + row) * ldb + k0 + gsl * 8),
                    (__attribute__((address_space(3))) unsigned int*)
                        (Bl + row * 32 + ssl * 8),
                    16, 0, 0);
            }
        } else {
            // B stored [K][N]; transpose into LDS [n][k] with matching swizzle
            const int bk = tid >> 3;                 // 0..31
            const int nb0 = (tid & 7) * (BN / 8);
#pragma unroll
            for (int v8 = 0; v8 < BN / 64; ++v8) {
                int nb = nb0 + v8 * 8;
                bf16x8 v = *(const bf16x8*)(Bb + (ll)(k0 + bk) * ldb + n0 + nb);
#pragma unroll
                for (int j = 0; j < 8; ++j) {
                    int n = nb + j;
                    int sl = (bk >> 3) ^ ((n >> 1) & 3);
                    Bl[n * 32 + sl * 8 + (bk & 7)] = v[j];
                }
            }
        }
        __syncthreads();

        bf16x8 af[4], bfr[4];
#pragma unroll
        for (int mi = 0; mi < 4; ++mi) {
            int row = wr * 64 + mi * 16 + (lane & 15);
            af[mi] = *(const bf16x8*)(Al + row * 32 + (kslot ^ rsel) * 8);
        }
#pragma unroll
        for (int ni = 0; ni < 4; ++ni) {
            int row = wc * 64 + ni * 16 + (lane & 15);
            bfr[ni] = *(const bf16x8*)(Bl + row * 32 + (kslot ^ rsel) * 8);
        }
#pragma unroll
        for (int mi = 0; mi < 4; ++mi)
#pragma unroll
            for (int ni = 0; ni < 4; ++ni)
                acc[mi][ni] = __builtin_amdgcn_mfma_f32_16x16x32_bf16(
                    af[mi], bfr[ni], acc[mi][ni], 0, 0, 0);
    }

    if (SMAX) {
        // fused row-softmax: WR==1, full rows in block (gridDim.x==1).
        bh16* Cb = (bh16*)Cv;
        // scale scores
#pragma unroll
        for (int mi = 0; mi < 4; ++mi)
#pragma unroll
            for (int ni = 0; ni < 4; ++ni)
#pragma unroll
                for (int r = 0; r < 4; ++r) acc[mi][ni][r] *= alpha;
        // pass 1: row max
        float mx[4][4];
#pragma unroll
        for (int mi = 0; mi < 4; ++mi)
#pragma unroll
            for (int r = 0; r < 4; ++r) {
                float m_ = acc[mi][0][r];
#pragma unroll
                for (int ni = 1; ni < 4; ++ni) m_ = fmaxf(m_, acc[mi][ni][r]);
#pragma unroll
                for (int msk = 1; msk < 16; msk <<= 1)
                    m_ = fmaxf(m_, __shfl_xor(m_, msk));
                mx[mi][r] = m_;
            }
        if ((lane & 15) == 0) {
#pragma unroll
            for (int mi = 0; mi < 4; ++mi)
#pragma unroll
                for (int r = 0; r < 4; ++r)
                    srow[wc * 64 + mi * 16 + (lane >> 4) * 4 + r] = mx[mi][r];
        }
        __syncthreads();
        float M_[4][4];
#pragma unroll
        for (int mi = 0; mi < 4; ++mi)
#pragma unroll
            for (int r = 0; r < 4; ++r) {
                int row = mi * 16 + (lane >> 4) * 4 + r;
                M_[mi][r] = fmaxf(fmaxf(srow[row], srow[64 + row]),
                                  fmaxf(srow[128 + row], srow[192 + row]));
            }
        __syncthreads();
        // pass 2: exp + sum
        float sm[4][4];
#pragma unroll
        for (int mi = 0; mi < 4; ++mi)
#pragma unroll
            for (int r = 0; r < 4; ++r) {
                float s_ = 0.f;
#pragma unroll
                for (int ni = 0; ni < 4; ++ni) {
                    float e = __expf(acc[mi][ni][r] - M_[mi][r]);
                    acc[mi][ni][r] = e;
                    s_ += e;
                }
#pragma unroll
                for (int msk = 1; msk < 16; msk <<= 1)
                    s_ += __shfl_xor(s_, msk);
                sm[mi][r] = s_;
            }
        if ((lane & 15) == 0) {
#pragma unroll
            for (int mi = 0; mi < 4; ++mi)
#pragma unroll
                for (int r = 0; r < 4; ++r)
                    srow[wc * 64 + mi * 16 + (lane >> 4) * 4 + r] = sm[mi][r];
        }
        __syncthreads();
#pragma unroll
        for (int mi = 0; mi < 4; ++mi)
#pragma unroll
            for (int r = 0; r < 4; ++r) {
                int row = mi * 16 + (lane >> 4) * 4 + r;
                float inv = 1.0f / (srow[row] + srow[64 + row] +
                                    srow[128 + row] + srow[192 + row]);
                int rowg = m0 + row;
#pragma unroll
                for (int ni = 0; ni < 4; ++ni) {
                    int colg = n0 + wc * 64 + ni * 16 + (lane & 15);
                    Cb[coff + (ll)rowg * ldc + colg] = (bh16)(acc[mi][ni][r] * inv);
                }
            }
        return;
    }

    const ll c2off = ADDC ? (bo * sC2o + (ll)bi * sC2i) : 0;
#pragma unroll
    for (int mi = 0; mi < 4; ++mi) {
#pragma unroll
        for (int ni = 0; ni < 4; ++ni) {
            const int colg = n0 + wc * 64 + ni * 16 + (lane & 15);
            const float bia = (!DUAL && bias) ? bias[colg] : 0.f;
#pragma unroll
            for (int r = 0; r < 4; ++r) {
                const int rowg = m0 + wr * 64 + mi * 16 + (lane >> 4) * 4 + r;
                const float a = acc[mi][ni][r];
                const ll off = coff + (ll)rowg * ldc + colg;
                if (DUAL) {
                    ((bh16*)Cv)[off] = (bh16)a;
                    float w = ((rowg == colg) ? diagv : 0.f) - a;
                    ((bh16*)C2v)[off] = (bh16)w;
                } else {
                    float v = alpha * a + bia;
                    if (ADDC)
                        v += (float)((const bh16*)C2v)[c2off + (ll)rowg * ldc2 + colg];
                    if (diagv != 0.f && rowg == colg) v += diagv;
                    if (GELU_ACT) {
                        float t = tanhf(0.7978845608f * (v + 0.044715f * v * v * v));
                        v = 0.5f * v * (1.0f + t);
                    }
                    if (BF16OUT) {
                        ((bh16*)Cv)[off] = (bh16)v;
                    } else {
                        float* p = (float*)Cv + off;
                        float o = v;
                        if (RESID) o += *p;
                        *p = o;
                    }
                }
            }
        }
    }
}

template<int WR, int WC, bool TRB, bool G, bool R, bool BO, bool D, bool SX, bool AC>
static inline void mg(hipStream_t s, int M, int N, int K,
                      const bh16* A, int lda, const bh16* B, int ldb,
                      void* C, int ldc, void* C2, const float* bias,
                      int batch, int BI,
                      ll sAo, ll sAi, ll sBo, ll sBi, ll sCo, ll sCi,
                      float alpha, float diagv,
                      int ldc2 = 0, ll sC2o = 0, ll sC2i = 0)
{
    dim3 grid(N / (WC * 64), M / (WR * 64), batch);
    hipLaunchKernelGGL((mgemm_k<WR, WC, TRB, G, R, BO, D, SX, AC>), grid, dim3(256), 0, s,
                       A, B, bias, C, C2, K, lda, ldb, ldc, BI,
                       sAo, sAi, sBo, sBi, sCo, sCi, ldc2, sC2o, sC2i, alpha, diagv);
}

// ===========================================================================
// Small kernels
// ===========================================================================
__global__ void embed_k(const float* __restrict__ x, const float* __restrict__ w,
                        const float* __restrict__ b, float* __restrict__ h)
{
    ll idx = (ll)blockIdx.x * 256 + threadIdx.x;
    int d = (int)(idx & 511);
    ll bn = idx >> 9;
    h[idx] = x[bn * 2] * w[d] + x[bn * 2 + 1] * w[512 + d] + b[d];
}

// LayerNorm, bf16 output; one block per row of 512
__global__ void __launch_bounds__(256)
ln_k(const float* __restrict__ X, const float* __restrict__ g,
     const float* __restrict__ bta, bh16* __restrict__ Y)
{
    const ll row = blockIdx.x;
    const float* x = X + row * 512;
    bh16* y = Y + row * 512;
    const int tid = threadIdx.x;
    float v0 = x[tid], v1 = x[tid + 256];
    float s = v0 + v1;
    float q = v0 * v0 + v1 * v1;
    __shared__ float sred[8];
    for (int o = 32; o; o >>= 1) { s += __shfl_down(s, o); q += __shfl_down(q, o); }
    const int lane = tid & 63, w = tid >> 6;
    if (lane == 0) { sred[w] = s; sred[4 + w] = q; }
    __syncthreads();
    float ssum = sred[0] + sred[1] + sred[2] + sred[3];
    float qsum = sred[4] + sred[5] + sred[6] + sred[7];
    float mu = ssum * (1.0f / 512.0f);
    float var = qsum * (1.0f / 512.0f) - mu * mu;
    float r = rsqrtf(var + 1e-5f);
    y[tid] = (bh16)((v0 - mu) * r * g[tid] + bta[tid]);
    y[tid + 256] = (bh16)((v1 - mu) * r * g[tid + 256] + bta[tid + 256]);
}

// weight f32 [R][C] -> bf16 [C][R]; 64x64 LDS-tiled transpose.
__global__ void __launch_bounds__(256)
cvtT_k(const float* __restrict__ in, bh16* __restrict__ outp, int C, int R)
{
    __shared__ float t[64][65];
    const int nCt = C >> 6;
    const int c0 = (blockIdx.x % nCt) * 64;
    const int r0 = (blockIdx.x / nCt) * 64;
    const int tid = threadIdx.x;
#pragma unroll
    for (int j = 0; j < 16; ++j) {
        int idx = j * 256 + tid;
        int lr = idx >> 6, lc = idx & 63;
        t[lc][lr] = in[(ll)(r0 + lr) * C + c0 + lc];
    }
    __syncthreads();
#pragma unroll
    for (int v = 0; v < 2; ++v) {
        int flat = v * 256 + tid;
        int lc = flat >> 3, r8 = (flat & 7) * 8;
        bf16x8 o;
#pragma unroll
        for (int j = 0; j < 8; ++j) o[j] = (bh16)t[lc][r8 + j];
        *(bf16x8*)(outp + (ll)(c0 + lc) * R + r0 + r8) = o;
    }
}

// landmark means for ALL samples; ql pre-scaled by DH^-0.5
__global__ void landmarks_k(const bh16* __restrict__ qkv,
                            bh16* __restrict__ qlb, bh16* __restrict__ klb)
{
    int idx = blockIdx.x * 256 + threadIdx.x;   // 8*8*256*64 = 1,048,576
    int d = idx & 63;
    int m = (idx >> 6) & 255;
    int h = (idx >> 14) & 7;
    int b = idx >> 17;
    const bh16* base = qkv + (ll)b * (NVEC * 1536) + (ll)(m * LSEG) * 1536 + h * 64 + d;
    float sq = 0.f, sk = 0.f;
#pragma unroll
    for (int l = 0; l < LSEG; ++l) {
        sq += (float)base[(ll)l * 1536];
        sk += (float)base[(ll)l * 1536 + 512];
    }
    ll o = (ll)(b * 8 + h) * 16384 + m * 64 + d;
    qlb[o] = (bh16)(sq * (0.0625f * 0.125f));
    klb[o] = (bh16)(sk * 0.0625f);
}

// wb bf16 [bh][256][64] -> wbT bf16 [bh][64][256]
__global__ void wbt_k(const bh16* __restrict__ wb, bh16* __restrict__ wbt)
{
    int idx = blockIdx.x * 256 + threadIdx.x;   // 131072
    int d = idx & 63, kg = (idx >> 6) & 31, bhh = idx >> 11;
    const bh16* p = wb + (ll)bhh * 16384 + kg * 8 * 64 + d;
    bf16x8 o;
#pragma unroll
    for (int j = 0; j < 8; ++j) o[j] = p[j * 64];
    *(bf16x8*)(wbt + (ll)bhh * 16384 + d * 256 + kg * 8) = o;
}

// reduce split-K partials for a 2-sample chunk:
// part [2][8h][8s][256][64] f32 -> A3Vb bf16 at [bh0+smp*8+h][256][64]
__global__ void a3vred_k(const float* __restrict__ part, bh16* __restrict__ outp)
{
    int idx = blockIdx.x * 256 + threadIdx.x;   // 262144
    int smp = idx >> 17;
    int rest = idx & 131071;
    int h = rest >> 14, o = rest & 16383;
    const float* p = part + (ll)smp * 1048576 + (ll)h * 131072 + o;
    float s = 0.f;
#pragma unroll
    for (int j = 0; j < 8; ++j) s += p[j * 16384];
    outp[(ll)(smp * 8 + h) * 16384 + o] = (bh16)s;
}

// ---------------------------------------------------------------------------
// Depthwise conv, sliding-window vectorized; OUTPUT goes into the dead k-slot
// of QKV (cols 512..1023) -- k is fully consumed (landmarks, attn3) before
// this runs, and aout's ADDC epilogue reads it from there.
// ---------------------------------------------------------------------------
__global__ void __launch_bounds__(256)
conv_k(bh16* __restrict__ qkv, const float* __restrict__ cw)
{
    int idx = blockIdx.x * 256 + threadIdx.x;   // 8*1024*64 = 524288
    int c8 = idx & 63;                          // 8-channel group
    int ng = (idx >> 6) & 1023;                 // n-group (4 n's)
    int b  = idx >> 16;
    const int n0 = ng * 4;
    const int h = c8 >> 3;
    const bh16* v = qkv + (ll)b * (NVEC * 1536) + 1024 + c8 * 8;

    float wreg[KER];
#pragma unroll
    for (int k = 0; k < KER; ++k) wreg[k] = cw[h * KER + k];

    float acc[4][8];
#pragma unroll
    for (int t = 0; t < 4; ++t)
#pragma unroll
        for (int e = 0; e < 8; ++e) acc[t][e] = 0.f;

#pragma unroll
    for (int m = 0; m < 36; ++m) {
        int nn = n0 + m - (KER / 2);
        bf16x8 vv = {};
        if ((unsigned)nn < (unsigned)NVEC)
            vv = *(const bf16x8*)(v + (ll)nn * 1536);
#pragma unroll
        for (int t = 0; t < 4; ++t) {
            constexpr int KMAX = KER - 1;
            int k = m - t;
            if (k >= 0 && k <= KMAX) {
                float wk = wreg[k];
#pragma unroll
                for (int e = 0; e < 8; ++e)
                    acc[t][e] = fmaf((float)vv[e], wk, acc[t][e]);
            }
        }
    }

    bh16* o = qkv + (ll)b * (NVEC * 1536) + (ll)n0 * 1536 + 512 + c8 * 8;
#pragma unroll
    for (int t = 0; t < 4; ++t) {
        bf16x8 ov;
#pragma unroll
        for (int e = 0; e < 8; ++e) ov[e] = (bh16)acc[t][e];
        *(bf16x8*)(o + (ll)t * 1536) = ov;
    }
}

// -------- softmax helpers --------
__device__ __forceinline__ float blkmax(float m, float* red, int tid)
{
#pragma unroll
    for (int o = 32; o; o >>= 1) m = fmaxf(m, __shfl_down(m, o));
    if ((tid & 63) == 0) red[tid >> 6] = m;
    __syncthreads();
    m = fmaxf(fmaxf(red[0], red[1]), fmaxf(red[2], red[3]));
    __syncthreads();
    return m;
}
__device__ __forceinline__ float blksum(float s, float* red, int tid)
{
#pragma unroll
    for (int o = 32; o; o >>= 1) s += __shfl_down(s, o);
    if ((tid & 63) == 0) red[tid >> 6] = s;
    __syncthreads();
    s = red[0] + red[1] + red[2] + red[3];
    __syncthreads();
    return s;
}

// in-place bf16 row softmax, L == 4096; one block (256 thr) per row
__global__ void __launch_bounds__(256)
softmax_bf_k(bh16* __restrict__ X, int L)
{
    const ll row = blockIdx.x;
    bh16* x = X + row * (ll)L;
    const int tid = threadIdx.x;
    __shared__ float red[4];
    float v[16];
    bf16x8 a = *(const bf16x8*)(x + tid * 8);
    bf16x8 b = *(const bf16x8*)(x + 2048 + tid * 8);
#pragma unroll
    for (int j = 0; j < 8; ++j) { v[j] = (float)a[j]; v[8 + j] = (float)b[j]; }
    float m = -1e30f;
#pragma unroll
    for (int j = 0; j < 16; ++j) m = fmaxf(m, v[j]);
    m = blkmax(m, red, tid);
    float s = 0.f;
#pragma unroll
    for (int j = 0; j < 16; ++j) { v[j] = __expf(v[j] - m); s += v[j]; }
    s = blksum(s, red, tid);
    float inv = 1.0f / s;
    bf16x8 oa, ob;
#pragma unroll
    for (int j = 0; j < 8; ++j) { oa[j] = (bh16)(v[j] * inv); ob[j] = (bh16)(v[8 + j] * inv); }
    *(bf16x8*)(x + tid * 8) = oa;
    *(bf16x8*)(x + 2048 + tid * 8) = ob;
}

// z0 = x^T / (max_rowsum * max_colsum), bf16 in/out, f32 math
__global__ void __launch_bounds__(256)
pinv_init_k(const bh16* __restrict__ X, bh16* __restrict__ Z)
{
    const ll bh = blockIdx.x;
    const bh16* x = X + bh * 65536;
    bh16* z = Z + bh * 65536;
    const int tid = threadIdx.x;
    float rs = 0.f, cs = 0.f;
    for (int j = 0; j < 256; ++j) {
        rs += fabsf((float)x[tid * 256 + j]);
        cs += fabsf((float)x[j * 256 + tid]);
    }
    __shared__ float rbuf[256], cbuf[256];
    rbuf[tid] = rs; cbuf[tid] = cs;
    __syncthreads();
    for (int o = 128; o; o >>= 1) {
        if (tid < o) {
            rbuf[tid] = fmaxf(rbuf[tid], rbuf[tid + o]);
            cbuf[tid] = fmaxf(cbuf[tid], cbuf[tid + o]);
        }
        __syncthreads();
    }
    float inv = 1.0f / (rbuf[0] * cbuf[0]);
    for (int e = tid; e < 65536; e += 256) {
        int i = e >> 8, j = e & 255;
        z[e] = (bh16)((float)x[j * 256 + i] * inv);
    }
}

__global__ void final_init_k(const float* __restrict__ fb, float* __restrict__ out)
{
    int i = threadIdx.x;
    if (i < BB_ * NCLASS) out[i] = fb[i % NCLASS];
}

// grid (256 chunks, 2 halves); block handles 8192 k's for 4 samples.
__global__ void __launch_bounds__(256)
final_gemv_k(const float* __restrict__ hbuf, const float* __restrict__ w,
             float* __restrict__ out)
{
    const int half = blockIdx.y;
    const int chunk = blockIdx.x;
    const int tid = threadIdx.x;
    const int k0 = chunk * 8192;
    float pc[4][NCLASS] = {};
    for (int e = 0; e < 32; ++e) {
        int k = k0 + e * 256 + tid;
        const float* wr = w + (ll)k * NCLASS;
        float wv[NCLASS];
#pragma unroll
        for (int c = 0; c < NCLASS; ++c) wv[c] = wr[c];
#pragma unroll
        for (int b = 0; b < 4; ++b) {
            float hv = hbuf[(ll)(half * 4 + b) * (NVEC * DIM) + k];
#pragma unroll
            for (int c = 0; c < NCLASS; ++c) pc[b][c] = fmaf(hv, wv[c], pc[b][c]);
        }
    }
    __shared__ float red[4][4][NCLASS];
    const int lane = tid & 63, wv_ = tid >> 6;
#pragma unroll
    for (int b = 0; b < 4; ++b)
#pragma unroll
        for (int c = 0; c < NCLASS; ++c) {
            float s = pc[b][c];
#pragma unroll
            for (int o = 32; o; o >>= 1) s += __shfl_down(s, o);
            if (lane == 0) red[wv_][b][c] = s;
        }
    __syncthreads();
    if (tid < 4 * NCLASS) {
        int b = tid / NCLASS, c = tid % NCLASS;
        float s = red[0][b][c] + red[1][b][c] + red[2][b][c] + red[3][b][c];
        atomicAdd(out + (half * 4 + b) * NCLASS + c, s);
    }
}

// ===========================================================================
extern "C" void kernel_launch(void* const* d_in, const int* in_sizes, int n_in,
                              void* d_out, int out_size, void* d_ws, size_t ws_size,
                              hipStream_t stream)
{
    const float* x      = (const float*)d_in[0];
    const float* lin_w  = (const float*)d_in[1];
    const float* lin_b  = (const float*)d_in[2];
    const float* ln1_g  = (const float*)d_in[3];
    const float* ln1_b  = (const float*)d_in[4];
    const float* qkv_w  = (const float*)d_in[5];
    const float* out_w  = (const float*)d_in[6];
    const float* out_b  = (const float*)d_in[7];
    const float* conv_w = (const float*)d_in[8];
    const float* ln2_g  = (const float*)d_in[9];
    const float* ln2_b  = (const float*)d_in[10];
    const float* ff1_w  = (const float*)d_in[11];
    const float* ff1_b  = (const float*)d_in[12];
    const float* ff2_w  = (const float*)d_in[13];
    const float* ff2_b  = (const float*)d_in[14];
    const float* final_w = (const float*)d_in[15];
    const float* final_b = (const float*)d_in[16];
    float* out = (float*)d_out;
    float* ws  = (float*)d_ws;

    // ---- workspace layout (f32 units), total 56,623,104 f32 = 226.5 MB ----
    float* H    = ws;                                  // [8][4096][512] f32, 16,777,216
    bh16*  QKV  = (bh16*)(ws + 16777216);              // [8][4096][1536] bf16, 25,165,824 f32
    float* P    = ws + 41943040;                       // pool, 10,485,760 f32
    bh16*  qlbf = (bh16*)(ws + 52428800);              // [64bh][256][64] bf16
    bh16*  klbf = (bh16*)(ws + 52953088);
    bh16*  A3Vb = (bh16*)(ws + 53477376);              // [64bh][256][64] bf16
    bh16*  WBb  = (bh16*)(ws + 54001664);
    bh16*  WBT  = (bh16*)(ws + 54525952);              // [64bh][64][256] bf16
    bh16*  WQT  = (bh16*)(ws + 55050240);              // [1536][512] bf16
    bh16*  WOT  = (bh16*)(ws + 55443456);              // [512][512] bf16
    bh16*  F1WT = (bh16*)(ws + 55574528);              // [2048][512] bf16
    bh16*  F2WT = (bh16*)(ws + 56098816);              // [512][2048] bf16
    if (ws_size < 56623104ULL * 4) return;

    // pool aliases (time-sliced)
    bh16*  XLNall = (bh16*)P;                          // [32768][512] bf16
    bh16*  ATT3c  = (bh16*)P;                          // [16bh][256][4096] bf16
    float* A3Vp   = P + 8388608;                       // [2][8h][8s][256][64] f32
    bh16*  Xbf = (bh16*)P;                             // pinv: 5 x [64][256][256] bf16
    bh16*  Z0  = (bh16*)(P + 2097152);
    bh16*  Z1  = (bh16*)(P + 4194304);
    bh16*  T1  = (bh16*)(P + 6291456);
    bh16*  T2  = (bh16*)(P + 8388608);
    bh16*  ATT1c  = (bh16*)P;                          // [16bh][4096][256] bf16
    bh16*  AOUTc  = (bh16*)(P + 8388608);              // [2][4096][512] bf16
    bh16*  XLNc   = (bh16*)P;                          // FFN: [8192][512] bf16
    bh16*  HIDc   = (bh16*)(P + 2097152);              // [2][4096][2048] bf16

    const ll SMP = (ll)NVEC * 1536;                    // qkv stride per sample (bf16)

    // embed
    hipLaunchKernelGGL(embed_k, dim3(65536), dim3(256), 0, stream, x, lin_w, lin_b, H);

    for (int i = 0; i < DEPTH; ++i) {
        const float* wq  = qkv_w + (ll)i * 512 * 1536;
        const float* wo  = out_w + (ll)i * 512 * 512;
        const float* bo  = out_b + (ll)i * 512;
        const float* cw  = conv_w + (ll)i * HEADS * KER;
        const float* g1  = ln1_g + (ll)i * 512;
        const float* b1  = ln1_b + (ll)i * 512;
        const float* g2  = ln2_g + (ll)i * 512;
        const float* b2  = ln2_b + (ll)i * 512;
        const float* f1w = ff1_w + (ll)i * 512 * 2048;
        const float* f1b = ff1_b + (ll)i * 2048;
        const float* f2w = ff2_w + (ll)i * 2048 * 512;
        const float* f2b = ff2_b + (ll)i * 512;

        // weight convert+transpose (bf16 [N][K]); LDS-tiled
        hipLaunchKernelGGL(cvtT_k, dim3(192), dim3(256), 0, stream, wq, WQT, 1536, 512);
        hipLaunchKernelGGL(cvtT_k, dim3(64), dim3(256), 0, stream, wo, WOT, 512, 512);
        hipLaunchKernelGGL(cvtT_k, dim3(256), dim3(256), 0, stream, f1w, F1WT, 2048, 512);
        hipLaunchKernelGGL(cvtT_k, dim3(256), dim3(256), 0, stream, f2w, F2WT, 512, 2048);

        // LN1 (all samples) + qkv (M=32768, one launch)
        hipLaunchKernelGGL(ln_k, dim3(32768), dim3(256), 0, stream, H, g1, b1, XLNall);
        mg<2,2,0,0,0,1,0,0,0>(stream, 32768, 1536, 512, XLNall, 512, WQT, 512,
            QKV, 1536, nullptr, nullptr, 1, 1, 0,0, 0,0, 0,0, 1.f, 0.f);

        // landmarks (all samples)
        hipLaunchKernelGGL(landmarks_k, dim3(4096), dim3(256), 0, stream, QKV, qlbf, klbf);

        // ---- attn3 / softmax / a3v in 2-sample chunks ----
        for (int c = 0; c < 4; ++c) {
            const bh16* qkvc = QKV + (ll)c * 2 * SMP;
            mg<2,2,0,0,0,1,0,0,0>(stream, 256, 4096, 64,
                qlbf + (ll)c * 262144, 64, qkvc + 512, 1536,
                ATT3c, 4096, nullptr, nullptr, 16, 8,
                131072, 16384, SMP, 64, 8388608LL, 1048576, 1.f, 0.f);
            hipLaunchKernelGGL(softmax_bf_k, dim3(4096), dim3(256), 0, stream, ATT3c, 4096);
            for (int s = 0; s < 2; ++s) {
                mg<4,1,1,0,0,0,0,0,0>(stream, 256, 64, 512,
                    ATT3c + (ll)s * 8 * 1048576, 4096, qkvc + (ll)s * SMP + 1024, 1536,
                    A3Vp + (ll)s * 1048576, 64, nullptr, nullptr, 64, 8,
                    1048576, 512, 64, 512LL * 1536, 131072, 16384, 1.f, 0.f);
            }
            hipLaunchKernelGGL(a3vred_k, dim3(1024), dim3(256), 0, stream,
                               A3Vp, A3Vb + (ll)c * 2 * 131072);
        }

        // ---- depthwise conv (all samples) -> QKV k-slot (consumed by ADDC) ----
        hipLaunchKernelGGL(conv_k, dim3(2048), dim3(256), 0, stream, QKV, cw);

        // ---- pinv (bf16 MFMA, batched 64); X via fused-softmax GEMM ----
        mg<1,4,0,0,0,1,0,1,0>(stream, 256, 256, 64, qlbf, 64, klbf, 64,
            Xbf, 256, nullptr, nullptr, 64, 64, 0, 16384, 0, 16384, 0, 65536, 1.f, 0.f);
        hipLaunchKernelGGL(pinv_init_k, dim3(64), dim3(256), 0, stream, Xbf, Z0);
        bh16* zc = Z0; bh16* zn = Z1;
        for (int it = 0; it < ITERS; ++it) {
            mg<2,2,1,0,0,1,1,0,0>(stream, 256, 256, 256, Xbf, 256, zc, 256,
                T1, 256, T2, nullptr, 64, 64, 0, 65536, 0, 65536, 0, 65536, 1.f, 7.f,
                256, 0, 65536);
            mg<2,2,1,0,0,1,0,0,0>(stream, 256, 256, 256, T1, 256, T2, 256,
                zn, 256, nullptr, nullptr, 64, 64, 0, 65536, 0, 65536, 0, 65536, -1.f, 15.f);
            mg<2,2,1,0,0,1,0,0,0>(stream, 256, 256, 256, T1, 256, zn, 256,
                T2, 256, nullptr, nullptr, 64, 64, 0, 65536, 0, 65536, 0, 65536, -1.f, 13.f);
            mg<2,2,1,0,0,1,0,0,0>(stream, 256, 256, 256, zc, 256, T2, 256,
                zn, 256, nullptr, nullptr, 64, 64, 0, 65536, 0, 65536, 0, 65536, 0.25f, 0.f);
            bh16* t = zc; zc = zn; zn = t;
        }
        // WB = zc @ A3V  (NN)
        mg<4,1,1,0,0,1,0,0,0>(stream, 256, 64, 256, zc, 256, A3Vb, 64,
            WBb, 64, nullptr, nullptr, 64, 64, 0, 65536, 0, 16384, 0, 16384, 1.f, 0.f);
        hipLaunchKernelGGL(wbt_k, dim3(512), dim3(256), 0, stream, WBb, WBT);

        // ---- attn1 (fused softmax) / aout (+conv via ADDC) / out-proj ----
        for (int c = 0; c < 4; ++c) {
            const bh16* qkvc = QKV + (ll)c * 2 * SMP;
            // attn1 = softmax(0.125 * q @ kl^T); q in place (lda=1536)
            mg<1,4,0,0,0,1,0,1,0>(stream, 4096, 256, 64,
                qkvc, 1536, klbf + (ll)c * 262144, 64,
                ATT1c, 256, nullptr, nullptr, 16, 8,
                SMP, 64, 131072, 16384, 8388608LL, 1048576, 0.125f, 0.f);
            // aout = attn1 @ wb + conv (ADDC from QKV k-slot)
            mg<4,1,0,0,0,1,0,0,1>(stream, 4096, 64, 256,
                ATT1c, 256, WBT + (ll)c * 262144, 256,
                AOUTc, 512, (void*)(QKV + (ll)c * 2 * SMP + 512), nullptr, 16, 8,
                8388608LL, 1048576, 131072, 16384, 2097152LL, 64, 1.f, 0.f,
                1536, SMP, 64);
            // H += aout @ Wo + bo   (M=8192)
            mg<2,2,0,0,1,0,0,0,0>(stream, 8192, 512, 512, AOUTc, 512, WOT, 512,
                H + (ll)c * 2 * 2097152, 512, nullptr, bo, 1, 1, 0,0, 0,0, 0,0, 1.f, 0.f);
        }

        // ---- FFN in 2-sample chunks ----
        for (int c = 0; c < 4; ++c) {
            float* Hc = H + (ll)c * 2 * 2097152;
            hipLaunchKernelGGL(ln_k, dim3(8192), dim3(256), 0, stream, Hc, g2, b2, XLNc);
            mg<2,2,0,1,0,1,0,0,0>(stream, 8192, 2048, 512, XLNc, 512, F1WT, 512,
                HIDc, 2048, nullptr, f1b, 1, 1, 0,0, 0,0, 0,0, 1.f, 0.f);
            mg<2,2,0,0,1,0,0,0,0>(stream, 8192, 512, 2048, HIDc, 2048, F2WT, 2048,
                Hc, 512, nullptr, f2b, 1, 1, 0,0, 0,0, 0,0, 1.f, 0.f);
        }
    }

    hipLaunchKernelGGL(final_init_k, dim3(1), dim3(128), 0, stream, final_b, out);
    hipLaunchKernelGGL(final_gemv_k, dim3(256, 2), dim3(256), 0, stream, H, final_w, out);
}

// Round 12
// 3317.418 us; speedup vs baseline: 5.1251x; 1.0213x over previous
//
#include <hip/hip_runtime.h>
#include <hip/hip_bf16.h>

// Problem constants
#define BB_ 8
#define NVEC 4096
#define DIM 512
#define HEADS 8
#define DH 64
#define MM_ 256
#define ITERS 6
#define DEPTH 2
#define NCLASS 10
#define KER 33
#define INNER 512
#define LSEG 16  // NVEC / MM_

typedef long long ll;
typedef __bf16 bh16;
typedef __attribute__((ext_vector_type(8))) __bf16 bf16x8;
typedef __attribute__((ext_vector_type(4))) float f32x4;

// ===========================================================================
// MFMA bf16 GEMM. TRB=0 (TN): C = A[M,K] @ B_t[N,K]^T. TRB=1 (NN).
// Tile BM=WR*64 x BN=WC*64, BK=32, 256 threads = 4 waves (WR*WC==4).
// XCD-bijective block swizzle (m204). SMAX: fused row-softmax (WR==1,
// gridDim.x==1). DUAL: C=acc, C2=diagv*I-acc. Batch: z -> bo=z/BI, bi=z%BI.
// ===========================================================================
template<int WR, int WC, bool TRB, bool GELU_ACT, bool RESID, bool BF16OUT,
         bool DUAL, bool SMAX>
__global__ void __launch_bounds__(256)
mgemm_k(const bh16* __restrict__ A, const bh16* __restrict__ B,
        const float* __restrict__ bias, void* __restrict__ Cv, void* __restrict__ C2v,
        int K, int lda, int ldb, int ldc,
        int BI, ll sAo, ll sAi, ll sBo, ll sBi, ll sCo, ll sCi,
        float alpha, float diagv)
{
    constexpr int BM = WR * 64, BN = WC * 64;
    const int bz = blockIdx.z;
    const int bo = bz / BI, bi = bz % BI;
    const bh16* Ab = A + bo * sAo + (ll)bi * sAi;
    const bh16* Bb = B + bo * sBo + (ll)bi * sBi;
    const ll coff = bo * sCo + (ll)bi * sCi;

    const int gx = gridDim.x;
    const int nwg = gx * gridDim.y;
    int flat = blockIdx.y * gx + blockIdx.x;
    {
        int xcd = flat & 7, base = flat >> 3;
        int q = nwg >> 3, rr = nwg & 7;
        flat = (xcd < rr ? xcd * (q + 1) : rr * (q + 1) + (xcd - rr) * q) + base;
    }
    const int m0 = (flat / gx) * BM;
    const int n0 = (flat % gx) * BN;

    const int tid = threadIdx.x;
    const int lane = tid & 63;
    const int wave = tid >> 6;
    const int wr = wave / WC, wc = wave % WC;

    __shared__ bh16 Al[BM * 32];
    __shared__ bh16 Bl[BN * 32];
    __shared__ float srow[SMAX ? 4 * 64 : 4];

    f32x4 acc[4][4];
#pragma unroll
    for (int i = 0; i < 4; ++i)
#pragma unroll
        for (int j = 0; j < 4; ++j) acc[i][j] = (f32x4){0.f, 0.f, 0.f, 0.f};

    const int srowi = tid >> 2;  // 0..63
    const int ssl   = tid & 3;   // 16B slot (linear LDS dest)

    const int rsel  = ((lane & 15) >> 1) & 3;
    const int kslot = lane >> 4;

    for (int k0 = 0; k0 < K; k0 += 32) {
        __syncthreads();
#pragma unroll
        for (int i = 0; i < BM / 64; ++i) {
            int row = i * 64 + srowi;
            int gsl = ssl ^ ((row >> 1) & 3);
            __builtin_amdgcn_global_load_lds(
                (const __attribute__((address_space(1))) unsigned int*)
                    (Ab + (ll)(m0 + row) * lda + k0 + gsl * 8),
                (__attribute__((address_space(3))) unsigned int*)
                    (Al + row * 32 + ssl * 8),
                16, 0, 0);
        }
        if (!TRB) {
#pragma unroll
            for (int i = 0; i < BN / 64; ++i) {
                int row = i * 64 + srowi;
                int gsl = ssl ^ ((row >> 1) & 3);
                __builtin_amdgcn_global_load_lds(
                    (const __attribute__((address_space(1))) unsigned int*)
                        (Bb + (ll)(n0 + row) * ldb + k0 + gsl * 8),
                    (__attribute__((address_space(3))) unsigned int*)
                        (Bl + row * 32 + ssl * 8),
                    16, 0, 0);
            }
        } else {
            const int bk = tid >> 3;
            const int nb0 = (tid & 7) * (BN / 8);
#pragma unroll
            for (int v8 = 0; v8 < BN / 64; ++v8) {
                int nb = nb0 + v8 * 8;
                bf16x8 v = *(const bf16x8*)(Bb + (ll)(k0 + bk) * ldb + n0 + nb);
#pragma unroll
                for (int j = 0; j < 8; ++j) {
                    int n = nb + j;
                    int sl = (bk >> 3) ^ ((n >> 1) & 3);
                    Bl[n * 32 + sl * 8 + (bk & 7)] = v[j];
                }
            }
        }
        __syncthreads();

        bf16x8 af[4], bfr[4];
#pragma unroll
        for (int mi = 0; mi < 4; ++mi) {
            int row = wr * 64 + mi * 16 + (lane & 15);
            af[mi] = *(const bf16x8*)(Al + row * 32 + (kslot ^ rsel) * 8);
        }
#pragma unroll
        for (int ni = 0; ni < 4; ++ni) {
            int row = wc * 64 + ni * 16 + (lane & 15);
            bfr[ni] = *(const bf16x8*)(Bl + row * 32 + (kslot ^ rsel) * 8);
        }
#pragma unroll
        for (int mi = 0; mi < 4; ++mi)
#pragma unroll
            for (int ni = 0; ni < 4; ++ni)
                acc[mi][ni] = __builtin_amdgcn_mfma_f32_16x16x32_bf16(
                    af[mi], bfr[ni], acc[mi][ni], 0, 0, 0);
    }

    if (SMAX) {
        bh16* Cb = (bh16*)Cv;
#pragma unroll
        for (int mi = 0; mi < 4; ++mi)
#pragma unroll
            for (int ni = 0; ni < 4; ++ni)
#pragma unroll
                for (int r = 0; r < 4; ++r) acc[mi][ni][r] *= alpha;
        float mx[4][4];
#pragma unroll
        for (int mi = 0; mi < 4; ++mi)
#pragma unroll
            for (int r = 0; r < 4; ++r) {
                float m_ = acc[mi][0][r];
#pragma unroll
                for (int ni = 1; ni < 4; ++ni) m_ = fmaxf(m_, acc[mi][ni][r]);
#pragma unroll
                for (int msk = 1; msk < 16; msk <<= 1)
                    m_ = fmaxf(m_, __shfl_xor(m_, msk));
                mx[mi][r] = m_;
            }
        if ((lane & 15) == 0) {
#pragma unroll
            for (int mi = 0; mi < 4; ++mi)
#pragma unroll
                for (int r = 0; r < 4; ++r)
                    srow[wc * 64 + mi * 16 + (lane >> 4) * 4 + r] = mx[mi][r];
        }
        __syncthreads();
        float M_[4][4];
#pragma unroll
        for (int mi = 0; mi < 4; ++mi)
#pragma unroll
            for (int r = 0; r < 4; ++r) {
                int row = mi * 16 + (lane >> 4) * 4 + r;
                M_[mi][r] = fmaxf(fmaxf(srow[row], srow[64 + row]),
                                  fmaxf(srow[128 + row], srow[192 + row]));
            }
        __syncthreads();
        float sm[4][4];
#pragma unroll
        for (int mi = 0; mi < 4; ++mi)
#pragma unroll
            for (int r = 0; r < 4; ++r) {
                float s_ = 0.f;
#pragma unroll
                for (int ni = 0; ni < 4; ++ni) {
                    float e = __expf(acc[mi][ni][r] - M_[mi][r]);
                    acc[mi][ni][r] = e;
                    s_ += e;
                }
#pragma unroll
                for (int msk = 1; msk < 16; msk <<= 1)
                    s_ += __shfl_xor(s_, msk);
                sm[mi][r] = s_;
            }
        if ((lane & 15) == 0) {
#pragma unroll
            for (int mi = 0; mi < 4; ++mi)
#pragma unroll
                for (int r = 0; r < 4; ++r)
                    srow[wc * 64 + mi * 16 + (lane >> 4) * 4 + r] = sm[mi][r];
        }
        __syncthreads();
#pragma unroll
        for (int mi = 0; mi < 4; ++mi)
#pragma unroll
            for (int r = 0; r < 4; ++r) {
                int row = mi * 16 + (lane >> 4) * 4 + r;
                float inv = 1.0f / (srow[row] + srow[64 + row] +
                                    srow[128 + row] + srow[192 + row]);
                int rowg = m0 + row;
#pragma unroll
                for (int ni = 0; ni < 4; ++ni) {
                    int colg = n0 + wc * 64 + ni * 16 + (lane & 15);
                    Cb[coff + (ll)rowg * ldc + colg] = (bh16)(acc[mi][ni][r] * inv);
                }
            }
        return;
    }

#pragma unroll
    for (int mi = 0; mi < 4; ++mi) {
#pragma unroll
        for (int ni = 0; ni < 4; ++ni) {
            const int colg = n0 + wc * 64 + ni * 16 + (lane & 15);
            const float bia = (!DUAL && bias) ? bias[colg] : 0.f;
#pragma unroll
            for (int r = 0; r < 4; ++r) {
                const int rowg = m0 + wr * 64 + mi * 16 + (lane >> 4) * 4 + r;
                const float a = acc[mi][ni][r];
                const ll off = coff + (ll)rowg * ldc + colg;
                if (DUAL) {
                    ((bh16*)Cv)[off] = (bh16)a;
                    float w = ((rowg == colg) ? diagv : 0.f) - a;
                    ((bh16*)C2v)[off] = (bh16)w;
                } else {
                    float v = alpha * a + bia;
                    if (diagv != 0.f && rowg == colg) v += diagv;
                    if (GELU_ACT) {
                        float t = tanhf(0.7978845608f * (v + 0.044715f * v * v * v));
                        v = 0.5f * v * (1.0f + t);
                    }
                    if (BF16OUT) {
                        ((bh16*)Cv)[off] = (bh16)v;
                    } else {
                        float* p = (float*)Cv + off;
                        float o = v;
                        if (RESID) o += *p;
                        *p = o;
                    }
                }
            }
        }
    }
}

template<int WR, int WC, bool TRB, bool G, bool R, bool BO, bool D, bool SX>
static inline void mg(hipStream_t s, int M, int N, int K,
                      const bh16* A, int lda, const bh16* B, int ldb,
                      void* C, int ldc, void* C2, const float* bias,
                      int batch, int BI,
                      ll sAo, ll sAi, ll sBo, ll sBi, ll sCo, ll sCi,
                      float alpha, float diagv)
{
    dim3 grid(N / (WC * 64), M / (WR * 64), batch);
    hipLaunchKernelGGL((mgemm_k<WR, WC, TRB, G, R, BO, D, SX>), grid, dim3(256), 0, s,
                       A, B, bias, C, C2, K, lda, ldb, ldc, BI,
                       sAo, sAi, sBo, sBi, sCo, sCi, alpha, diagv);
}

// ===========================================================================
// Fused attn1: block = (qblock 64 rows, one (b,h)). Phase 1: S=q@kl^T (K=64),
// cross-wave softmax (alpha=0.125). P -> LDS (chunk-XOR swizzle). Phase 2:
// aout = P@wbT^T (K=256, 4-way wave K-split, LDS f32 reduce) + conv (bf16,
// from QKV k-slot) -> bf16 aout. Numerically identical rounding sites to the
// unfused path.
// ===========================================================================
__global__ void __launch_bounds__(256)
fattn_k(const bh16* __restrict__ qkv, const bh16* __restrict__ klb,
        const bh16* __restrict__ wbt, bh16* __restrict__ aout)
{
    const int qb = blockIdx.x;          // 0..63
    const int bh = blockIdx.y;          // 0..63
    const int b = bh >> 3, h = bh & 7;
    const int q0 = qb * 64;
    const int tid = threadIdx.x, lane = tid & 63, wave = tid >> 6;
    const ll SMPq = (ll)NVEC * 1536;

    __shared__ bh16 Pl[64 * 256];       // 32 KB
    __shared__ float red[64 * 64];      // 16 KB (also reused as srow[256])
    float* srow = red;

    const bh16* qbase = qkv + (ll)b * SMPq + (ll)q0 * 1536 + h * 64;
    const bh16* klbh = klb + (ll)bh * 16384;
    const bh16* wbh  = wbt + (ll)bh * 16384;

    const int kslot = lane >> 4;

    // ---- phase 1: scores ----
    f32x4 acc[4][4];
#pragma unroll
    for (int i = 0; i < 4; ++i)
#pragma unroll
        for (int j = 0; j < 4; ++j) acc[i][j] = (f32x4){0.f, 0.f, 0.f, 0.f};
#pragma unroll
    for (int ks = 0; ks < 2; ++ks) {
        int k0 = ks * 32;
        bf16x8 af[4], bfr[4];
#pragma unroll
        for (int mi = 0; mi < 4; ++mi) {
            int row = mi * 16 + (lane & 15);
            af[mi] = *(const bf16x8*)(qbase + (ll)row * 1536 + k0 + kslot * 8);
        }
#pragma unroll
        for (int ni = 0; ni < 4; ++ni) {
            int brow = wave * 64 + ni * 16 + (lane & 15);
            bfr[ni] = *(const bf16x8*)(klbh + brow * 64 + k0 + kslot * 8);
        }
#pragma unroll
        for (int mi = 0; mi < 4; ++mi)
#pragma unroll
            for (int ni = 0; ni < 4; ++ni)
                acc[mi][ni] = __builtin_amdgcn_mfma_f32_16x16x32_bf16(
                    af[mi], bfr[ni], acc[mi][ni], 0, 0, 0);
    }

    // ---- softmax over 256 cols (4 wave-quadrants) ----
#pragma unroll
    for (int mi = 0; mi < 4; ++mi)
#pragma unroll
        for (int ni = 0; ni < 4; ++ni)
#pragma unroll
            for (int r = 0; r < 4; ++r) acc[mi][ni][r] *= 0.125f;
    float mx[4][4];
#pragma unroll
    for (int mi = 0; mi < 4; ++mi)
#pragma unroll
        for (int r = 0; r < 4; ++r) {
            float m_ = acc[mi][0][r];
#pragma unroll
            for (int ni = 1; ni < 4; ++ni) m_ = fmaxf(m_, acc[mi][ni][r]);
#pragma unroll
            for (int msk = 1; msk < 16; msk <<= 1)
                m_ = fmaxf(m_, __shfl_xor(m_, msk));
            mx[mi][r] = m_;
        }
    if ((lane & 15) == 0) {
#pragma unroll
        for (int mi = 0; mi < 4; ++mi)
#pragma unroll
            for (int r = 0; r < 4; ++r)
                srow[wave * 64 + mi * 16 + (lane >> 4) * 4 + r] = mx[mi][r];
    }
    __syncthreads();
    float M_[4][4];
#pragma unroll
    for (int mi = 0; mi < 4; ++mi)
#pragma unroll
        for (int r = 0; r < 4; ++r) {
            int row = mi * 16 + (lane >> 4) * 4 + r;
            M_[mi][r] = fmaxf(fmaxf(srow[row], srow[64 + row]),
                              fmaxf(srow[128 + row], srow[192 + row]));
        }
    __syncthreads();
    float sm[4][4];
#pragma unroll
    for (int mi = 0; mi < 4; ++mi)
#pragma unroll
        for (int r = 0; r < 4; ++r) {
            float s_ = 0.f;
#pragma unroll
            for (int ni = 0; ni < 4; ++ni) {
                float e = __expf(acc[mi][ni][r] - M_[mi][r]);
                acc[mi][ni][r] = e;
                s_ += e;
            }
#pragma unroll
            for (int msk = 1; msk < 16; msk <<= 1)
                s_ += __shfl_xor(s_, msk);
            sm[mi][r] = s_;
        }
    if ((lane & 15) == 0) {
#pragma unroll
        for (int mi = 0; mi < 4; ++mi)
#pragma unroll
            for (int r = 0; r < 4; ++r)
                srow[wave * 64 + mi * 16 + (lane >> 4) * 4 + r] = sm[mi][r];
    }
    __syncthreads();
    // normalize + write P to LDS with chunk-XOR swizzle; then srow reusable
#pragma unroll
    for (int mi = 0; mi < 4; ++mi)
#pragma unroll
        for (int r = 0; r < 4; ++r) {
            int row = mi * 16 + (lane >> 4) * 4 + r;
            float inv = 1.0f / (srow[row] + srow[64 + row] +
                                srow[128 + row] + srow[192 + row]);
            int rsw = (row >> 1) & 3;
#pragma unroll
            for (int ni = 0; ni < 4; ++ni) {
                int col = wave * 64 + ni * 16 + (lane & 15);
                int kc = col >> 5, sl = (col >> 3) & 3, e = col & 7;
                Pl[row * 256 + kc * 32 + ((sl ^ rsw) * 8) + e] =
                    (bh16)(acc[mi][ni][r] * inv);
            }
        }
    __syncthreads();

    // ---- phase 2: aout = P @ wbT^T, wave K-split (wave covers K 64*wave..) --
    f32x4 acc2[4][4];
#pragma unroll
    for (int i = 0; i < 4; ++i)
#pragma unroll
        for (int j = 0; j < 4; ++j) acc2[i][j] = (f32x4){0.f, 0.f, 0.f, 0.f};
#pragma unroll
    for (int kk = 0; kk < 2; ++kk) {
        int k0 = wave * 64 + kk * 32;
        int kc = k0 >> 5;
        bf16x8 af[4], bfr[4];
#pragma unroll
        for (int mi = 0; mi < 4; ++mi) {
            int row = mi * 16 + (lane & 15);
            int rsw = (row >> 1) & 3;
            af[mi] = *(const bf16x8*)(Pl + row * 256 + kc * 32 + ((kslot ^ rsw) * 8));
        }
#pragma unroll
        for (int ni = 0; ni < 4; ++ni) {
            int brow = ni * 16 + (lane & 15);
            bfr[ni] = *(const bf16x8*)(wbh + brow * 256 + k0 + kslot * 8);
        }
#pragma unroll
        for (int mi = 0; mi < 4; ++mi)
#pragma unroll
            for (int ni = 0; ni < 4; ++ni)
                acc2[mi][ni] = __builtin_amdgcn_mfma_f32_16x16x32_bf16(
                    af[mi], bfr[ni], acc2[mi][ni], 0, 0, 0);
    }
    // deterministic 4-wave f32 reduce in LDS
    for (int w = 0; w < 4; ++w) {
        if (wave == w) {
#pragma unroll
            for (int mi = 0; mi < 4; ++mi)
#pragma unroll
                for (int ni = 0; ni < 4; ++ni)
#pragma unroll
                    for (int r = 0; r < 4; ++r) {
                        int row = mi * 16 + (lane >> 4) * 4 + r;
                        int col = ni * 16 + (lane & 15);
                        if (w == 0) red[row * 64 + col] = acc2[mi][ni][r];
                        else        red[row * 64 + col] += acc2[mi][ni][r];
                    }
        }
        __syncthreads();
    }
    // epilogue: + conv (bf16, QKV k-slot), round, write
    {
        int flat = tid * 16;
        int row = flat >> 6, col0 = flat & 63;
        const bh16* cv = qkv + (ll)b * SMPq + (ll)(q0 + row) * 1536 + 512 + h * 64 + col0;
        bh16* op = aout + (ll)b * (NVEC * 512) + (ll)(q0 + row) * 512 + h * 64 + col0;
        bf16x8 c0 = *(const bf16x8*)cv;
        bf16x8 c1 = *(const bf16x8*)(cv + 8);
        bf16x8 o0, o1;
#pragma unroll
        for (int j = 0; j < 8; ++j) {
            o0[j] = (bh16)(red[row * 64 + col0 + j] + (float)c0[j]);
            o1[j] = (bh16)(red[row * 64 + col0 + 8 + j] + (float)c1[j]);
        }
        *(bf16x8*)op = o0;
        *(bf16x8*)(op + 8) = o1;
    }
}

// ===========================================================================
// Small kernels
// ===========================================================================
__global__ void embed_k(const float* __restrict__ x, const float* __restrict__ w,
                        const float* __restrict__ b, float* __restrict__ h)
{
    ll idx = (ll)blockIdx.x * 256 + threadIdx.x;
    int d = (int)(idx & 511);
    ll bn = idx >> 9;
    h[idx] = x[bn * 2] * w[d] + x[bn * 2 + 1] * w[512 + d] + b[d];
}

__global__ void __launch_bounds__(256)
ln_k(const float* __restrict__ X, const float* __restrict__ g,
     const float* __restrict__ bta, bh16* __restrict__ Y)
{
    const ll row = blockIdx.x;
    const float* x = X + row * 512;
    bh16* y = Y + row * 512;
    const int tid = threadIdx.x;
    float v0 = x[tid], v1 = x[tid + 256];
    float s = v0 + v1;
    float q = v0 * v0 + v1 * v1;
    __shared__ float sred[8];
    for (int o = 32; o; o >>= 1) { s += __shfl_down(s, o); q += __shfl_down(q, o); }
    const int lane = tid & 63, w = tid >> 6;
    if (lane == 0) { sred[w] = s; sred[4 + w] = q; }
    __syncthreads();
    float ssum = sred[0] + sred[1] + sred[2] + sred[3];
    float qsum = sred[4] + sred[5] + sred[6] + sred[7];
    float mu = ssum * (1.0f / 512.0f);
    float var = qsum * (1.0f / 512.0f) - mu * mu;
    float r = rsqrtf(var + 1e-5f);
    y[tid] = (bh16)((v0 - mu) * r * g[tid] + bta[tid]);
    y[tid + 256] = (bh16)((v1 - mu) * r * g[tid + 256] + bta[tid + 256]);
}

__global__ void __launch_bounds__(256)
cvtT_k(const float* __restrict__ in, bh16* __restrict__ outp, int C, int R)
{
    __shared__ float t[64][65];
    const int nCt = C >> 6;
    const int c0 = (blockIdx.x % nCt) * 64;
    const int r0 = (blockIdx.x / nCt) * 64;
    const int tid = threadIdx.x;
#pragma unroll
    for (int j = 0; j < 16; ++j) {
        int idx = j * 256 + tid;
        int lr = idx >> 6, lc = idx & 63;
        t[lc][lr] = in[(ll)(r0 + lr) * C + c0 + lc];
    }
    __syncthreads();
#pragma unroll
    for (int v = 0; v < 2; ++v) {
        int flat = v * 256 + tid;
        int lc = flat >> 3, r8 = (flat & 7) * 8;
        bf16x8 o;
#pragma unroll
        for (int j = 0; j < 8; ++j) o[j] = (bh16)t[lc][r8 + j];
        *(bf16x8*)(outp + (ll)(c0 + lc) * R + r0 + r8) = o;
    }
}

__global__ void landmarks_k(const bh16* __restrict__ qkv,
                            bh16* __restrict__ qlb, bh16* __restrict__ klb)
{
    int idx = blockIdx.x * 256 + threadIdx.x;
    int d = idx & 63;
    int m = (idx >> 6) & 255;
    int h = (idx >> 14) & 7;
    int b = idx >> 17;
    const bh16* base = qkv + (ll)b * (NVEC * 1536) + (ll)(m * LSEG) * 1536 + h * 64 + d;
    float sq = 0.f, sk = 0.f;
#pragma unroll
    for (int l = 0; l < LSEG; ++l) {
        sq += (float)base[(ll)l * 1536];
        sk += (float)base[(ll)l * 1536 + 512];
    }
    ll o = (ll)(b * 8 + h) * 16384 + m * 64 + d;
    qlb[o] = (bh16)(sq * (0.0625f * 0.125f));
    klb[o] = (bh16)(sk * 0.0625f);
}

__global__ void wbt_k(const bh16* __restrict__ wb, bh16* __restrict__ wbt)
{
    int idx = blockIdx.x * 256 + threadIdx.x;
    int d = idx & 63, kg = (idx >> 6) & 31, bhh = idx >> 11;
    const bh16* p = wb + (ll)bhh * 16384 + kg * 8 * 64 + d;
    bf16x8 o;
#pragma unroll
    for (int j = 0; j < 8; ++j) o[j] = p[j * 64];
    *(bf16x8*)(wbt + (ll)bhh * 16384 + d * 256 + kg * 8) = o;
}

// per-sample split-K reduce: part [8h][8s][256][64] f32 -> bf16 out[h][256][64]
__global__ void a3vred_k(const float* __restrict__ part, bh16* __restrict__ outp)
{
    int idx = blockIdx.x * 256 + threadIdx.x;   // 131072
    int h = idx >> 14, o = idx & 16383;
    const float* p = part + (ll)h * 131072 + o;
    float s = 0.f;
#pragma unroll
    for (int j = 0; j < 8; ++j) s += p[j * 16384];
    outp[idx] = (bh16)s;
}

__global__ void __launch_bounds__(256)
conv_k(bh16* __restrict__ qkv, const float* __restrict__ cw)
{
    int idx = blockIdx.x * 256 + threadIdx.x;
    int c8 = idx & 63;
    int ng = (idx >> 6) & 1023;
    int b  = idx >> 16;
    const int n0 = ng * 4;
    const int h = c8 >> 3;
    const bh16* v = qkv + (ll)b * (NVEC * 1536) + 1024 + c8 * 8;

    float wreg[KER];
#pragma unroll
    for (int k = 0; k < KER; ++k) wreg[k] = cw[h * KER + k];

    float acc[4][8];
#pragma unroll
    for (int t = 0; t < 4; ++t)
#pragma unroll
        for (int e = 0; e < 8; ++e) acc[t][e] = 0.f;

#pragma unroll
    for (int m = 0; m < 36; ++m) {
        int nn = n0 + m - (KER / 2);
        bf16x8 vv = {};
        if ((unsigned)nn < (unsigned)NVEC)
            vv = *(const bf16x8*)(v + (ll)nn * 1536);
#pragma unroll
        for (int t = 0; t < 4; ++t) {
            constexpr int KMAX = KER - 1;
            int k = m - t;
            if (k >= 0 && k <= KMAX) {
                float wk = wreg[k];
#pragma unroll
                for (int e = 0; e < 8; ++e)
                    acc[t][e] = fmaf((float)vv[e], wk, acc[t][e]);
            }
        }
    }

    bh16* o = qkv + (ll)b * (NVEC * 1536) + (ll)n0 * 1536 + 512 + c8 * 8;
#pragma unroll
    for (int t = 0; t < 4; ++t) {
        bf16x8 ov;
#pragma unroll
        for (int e = 0; e < 8; ++e) ov[e] = (bh16)acc[t][e];
        *(bf16x8*)(o + (ll)t * 1536) = ov;
    }
}

__device__ __forceinline__ float blkmax(float m, float* red, int tid)
{
#pragma unroll
    for (int o = 32; o; o >>= 1) m = fmaxf(m, __shfl_down(m, o));
    if ((tid & 63) == 0) red[tid >> 6] = m;
    __syncthreads();
    m = fmaxf(fmaxf(red[0], red[1]), fmaxf(red[2], red[3]));
    __syncthreads();
    return m;
}
__device__ __forceinline__ float blksum(float s, float* red, int tid)
{
#pragma unroll
    for (int o = 32; o; o >>= 1) s += __shfl_down(s, o);
    if ((tid & 63) == 0) red[tid >> 6] = s;
    __syncthreads();
    s = red[0] + red[1] + red[2] + red[3];
    __syncthreads();
    return s;
}

// row softmax: reads 4096 f32 scores, writes 4096 bf16 IN PLACE at row base
// (bf16 row occupies first half of the f32 row's bytes; row pitch stays 4096 f32)
__global__ void __launch_bounds__(256)
softmax_f2b_k(float* __restrict__ X)
{
    const ll row = blockIdx.x;
    float* x = X + row * 4096;
    const int tid = threadIdx.x;
    __shared__ float red[4];
    float v[16];
#pragma unroll
    for (int j = 0; j < 4; ++j) {
        float4 t = *(const float4*)(x + tid * 16 + j * 4);
        v[j * 4 + 0] = t.x; v[j * 4 + 1] = t.y; v[j * 4 + 2] = t.z; v[j * 4 + 3] = t.w;
    }
    float m = -1e30f;
#pragma unroll
    for (int j = 0; j < 16; ++j) m = fmaxf(m, v[j]);
    m = blkmax(m, red, tid);
    float s = 0.f;
#pragma unroll
    for (int j = 0; j < 16; ++j) { v[j] = __expf(v[j] - m); s += v[j]; }
    s = blksum(s, red, tid);
    float inv = 1.0f / s;
    __syncthreads();   // all reads complete before overlay writes
    bh16* o = (bh16*)x;
    bf16x8 oa, ob;
#pragma unroll
    for (int j = 0; j < 8; ++j) { oa[j] = (bh16)(v[j] * inv); ob[j] = (bh16)(v[8 + j] * inv); }
    *(bf16x8*)(o + tid * 16) = oa;
    *(bf16x8*)(o + tid * 16 + 8) = ob;
}

__global__ void __launch_bounds__(256)
pinv_init_k(const bh16* __restrict__ X, bh16* __restrict__ Z)
{
    const ll bh = blockIdx.x;
    const bh16* x = X + bh * 65536;
    bh16* z = Z + bh * 65536;
    const int tid = threadIdx.x;
    float rs = 0.f, cs = 0.f;
    for (int j = 0; j < 256; ++j) {
        rs += fabsf((float)x[tid * 256 + j]);
        cs += fabsf((float)x[j * 256 + tid]);
    }
    __shared__ float rbuf[256], cbuf[256];
    rbuf[tid] = rs; cbuf[tid] = cs;
    __syncthreads();
    for (int o = 128; o; o >>= 1) {
        if (tid < o) {
            rbuf[tid] = fmaxf(rbuf[tid], rbuf[tid + o]);
            cbuf[tid] = fmaxf(cbuf[tid], cbuf[tid + o]);
        }
        __syncthreads();
    }
    float inv = 1.0f / (rbuf[0] * cbuf[0]);
    for (int e = tid; e < 65536; e += 256) {
        int i = e >> 8, j = e & 255;
        z[e] = (bh16)((float)x[j * 256 + i] * inv);
    }
}

__global__ void final_init_k(const float* __restrict__ fb, float* __restrict__ out)
{
    int i = threadIdx.x;
    if (i < BB_ * NCLASS) out[i] = fb[i % NCLASS];
}

__global__ void __launch_bounds__(256)
final_gemv_k(const float* __restrict__ hbuf, const float* __restrict__ w,
             float* __restrict__ out)
{
    const int half = blockIdx.y;
    const int chunk = blockIdx.x;
    const int tid = threadIdx.x;
    const int k0 = chunk * 8192;
    float pc[4][NCLASS] = {};
    for (int e = 0; e < 32; ++e) {
        int k = k0 + e * 256 + tid;
        const float* wr = w + (ll)k * NCLASS;
        float wv[NCLASS];
#pragma unroll
        for (int c = 0; c < NCLASS; ++c) wv[c] = wr[c];
#pragma unroll
        for (int b = 0; b < 4; ++b) {
            float hv = hbuf[(ll)(half * 4 + b) * (NVEC * DIM) + k];
#pragma unroll
            for (int c = 0; c < NCLASS; ++c) pc[b][c] = fmaf(hv, wv[c], pc[b][c]);
        }
    }
    __shared__ float red[4][4][NCLASS];
    const int lane = tid & 63, wv_ = tid >> 6;
#pragma unroll
    for (int b = 0; b < 4; ++b)
#pragma unroll
        for (int c = 0; c < NCLASS; ++c) {
            float s = pc[b][c];
#pragma unroll
            for (int o = 32; o; o >>= 1) s += __shfl_down(s, o);
            if (lane == 0) red[wv_][b][c] = s;
        }
    __syncthreads();
    if (tid < 4 * NCLASS) {
        int b = tid / NCLASS, c = tid % NCLASS;
        float s = red[0][b][c] + red[1][b][c] + red[2][b][c] + red[3][b][c];
        atomicAdd(out + (half * 4 + b) * NCLASS + c, s);
    }
}

// ===========================================================================
extern "C" void kernel_launch(void* const* d_in, const int* in_sizes, int n_in,
                              void* d_out, int out_size, void* d_ws, size_t ws_size,
                              hipStream_t stream)
{
    const float* x      = (const float*)d_in[0];
    const float* lin_w  = (const float*)d_in[1];
    const float* lin_b  = (const float*)d_in[2];
    const float* ln1_g  = (const float*)d_in[3];
    const float* ln1_b  = (const float*)d_in[4];
    const float* qkv_w  = (const float*)d_in[5];
    const float* out_w  = (const float*)d_in[6];
    const float* out_b  = (const float*)d_in[7];
    const float* conv_w = (const float*)d_in[8];
    const float* ln2_g  = (const float*)d_in[9];
    const float* ln2_b  = (const float*)d_in[10];
    const float* ff1_w  = (const float*)d_in[11];
    const float* ff1_b  = (const float*)d_in[12];
    const float* ff2_w  = (const float*)d_in[13];
    const float* ff2_b  = (const float*)d_in[14];
    const float* final_w = (const float*)d_in[15];
    const float* final_b = (const float*)d_in[16];
    float* out = (float*)d_out;
    float* ws  = (float*)d_ws;

    // ---- workspace layout (f32 units), total 56,623,104 f32 = 226.5 MB ----
    float* H    = ws;                                  // [8][4096][512] f32
    bh16*  QKV  = (bh16*)(ws + 16777216);              // [8][4096][1536] bf16
    float* P    = ws + 41943040;                       // pool, 10,485,760 f32
    bh16*  qlbf = (bh16*)(ws + 52428800);              // [64bh][256][64] bf16
    bh16*  klbf = (bh16*)(ws + 52953088);
    bh16*  A3Vb = (bh16*)(ws + 53477376);              // [64bh][256][64] bf16
    bh16*  WBb  = (bh16*)(ws + 54001664);
    bh16*  WBT  = (bh16*)(ws + 54525952);              // [64bh][64][256] bf16
    bh16*  WQT  = (bh16*)(ws + 55050240);              // [1536][512] bf16
    bh16*  WOT  = (bh16*)(ws + 55443456);              // [512][512] bf16
    bh16*  F1WT = (bh16*)(ws + 55574528);              // [2048][512] bf16
    bh16*  F2WT = (bh16*)(ws + 56098816);              // [512][2048] bf16
    if (ws_size < 56623104ULL * 4) return;

    // pool aliases (time-sliced)
    bh16*  XLNall = (bh16*)P;                          // [32768][512] bf16
    float* SCORESf = P;                                // [8h][256][4096] f32 (1 sample)
    float* A3Vp   = P + 8388608;                       // [8h][8s][256][64] f32
    bh16*  Xbf = (bh16*)P;                             // pinv: 5 x [64][256][256] bf16
    bh16*  Z0  = (bh16*)(P + 2097152);
    bh16*  Z1  = (bh16*)(P + 4194304);
    bh16*  T1  = (bh16*)(P + 6291456);
    bh16*  T2  = (bh16*)(P + 8388608);
    bh16*  AOUTa  = (bh16*)P;                          // [8][4096][512] bf16
    bh16*  XLNc   = (bh16*)P;                          // FFN: [8192][512] bf16
    bh16*  HIDc   = (bh16*)(P + 2097152);              // [2][4096][2048] bf16

    const ll SMP = (ll)NVEC * 1536;

    hipLaunchKernelGGL(embed_k, dim3(65536), dim3(256), 0, stream, x, lin_w, lin_b, H);

    for (int i = 0; i < DEPTH; ++i) {
        const float* wq  = qkv_w + (ll)i * 512 * 1536;
        const float* wo  = out_w + (ll)i * 512 * 512;
        const float* bo  = out_b + (ll)i * 512;
        const float* cw  = conv_w + (ll)i * HEADS * KER;
        const float* g1  = ln1_g + (ll)i * 512;
        const float* b1  = ln1_b + (ll)i * 512;
        const float* g2  = ln2_g + (ll)i * 512;
        const float* b2  = ln2_b + (ll)i * 512;
        const float* f1w = ff1_w + (ll)i * 512 * 2048;
        const float* f1b = ff1_b + (ll)i * 2048;
        const float* f2w = ff2_w + (ll)i * 2048 * 512;
        const float* f2b = ff2_b + (ll)i * 512;

        hipLaunchKernelGGL(cvtT_k, dim3(192), dim3(256), 0, stream, wq, WQT, 1536, 512);
        hipLaunchKernelGGL(cvtT_k, dim3(64), dim3(256), 0, stream, wo, WOT, 512, 512);
        hipLaunchKernelGGL(cvtT_k, dim3(256), dim3(256), 0, stream, f1w, F1WT, 2048, 512);
        hipLaunchKernelGGL(cvtT_k, dim3(256), dim3(256), 0, stream, f2w, F2WT, 512, 2048);

        // LN1 + qkv (M=32768)
        hipLaunchKernelGGL(ln_k, dim3(32768), dim3(256), 0, stream, H, g1, b1, XLNall);
        mg<2,2,0,0,0,1,0,0>(stream, 32768, 1536, 512, XLNall, 512, WQT, 512,
            QKV, 1536, nullptr, nullptr, 1, 1, 0,0, 0,0, 0,0, 1.f, 0.f);

        hipLaunchKernelGGL(landmarks_k, dim3(4096), dim3(256), 0, stream, QKV, qlbf, klbf);

        // ---- attn3 (f32 scores) / softmax f32->bf16 in place / a3v, per sample ----
        for (int b = 0; b < BB_; ++b) {
            const bh16* qkvb = QKV + (ll)b * SMP;
            // scores f32: [8h][256][4096]
            mg<2,2,0,0,0,0,0,0>(stream, 256, 4096, 64,
                qlbf + (ll)b * 131072, 64, qkvb + 512, 1536,
                SCORESf, 4096, nullptr, nullptr, 8, 8,
                0, 16384, 0, 64, 0, 1048576, 1.f, 0.f);
            hipLaunchKernelGGL(softmax_f2b_k, dim3(2048), dim3(256), 0, stream, SCORESf);
            // a3v: A = bf16 P (in-place rows, lda 8192), NN B from v, split-K 8
            mg<4,1,1,0,0,0,0,0>(stream, 256, 64, 512,
                (const bh16*)SCORESf, 8192, qkvb + 1024, 1536,
                A3Vp, 64, nullptr, nullptr, 64, 8,
                2097152, 512, 64, 512LL * 1536, 131072, 16384, 1.f, 0.f);
            hipLaunchKernelGGL(a3vred_k, dim3(512), dim3(256), 0, stream,
                               A3Vp, A3Vb + (ll)b * 131072);
        }

        // conv -> QKV k-slot (k fully consumed above)
        hipLaunchKernelGGL(conv_k, dim3(2048), dim3(256), 0, stream, QKV, cw);

        // ---- pinv (bf16 MFMA, batched 64); X via fused-softmax GEMM ----
        mg<1,4,0,0,0,1,0,1>(stream, 256, 256, 64, qlbf, 64, klbf, 64,
            Xbf, 256, nullptr, nullptr, 64, 64, 0, 16384, 0, 16384, 0, 65536, 1.f, 0.f);
        hipLaunchKernelGGL(pinv_init_k, dim3(64), dim3(256), 0, stream, Xbf, Z0);
        bh16* zc = Z0; bh16* zn = Z1;
        for (int it = 0; it < ITERS; ++it) {
            mg<2,2,1,0,0,1,1,0>(stream, 256, 256, 256, Xbf, 256, zc, 256,
                T1, 256, T2, nullptr, 64, 64, 0, 65536, 0, 65536, 0, 65536, 1.f, 7.f);
            mg<2,2,1,0,0,1,0,0>(stream, 256, 256, 256, T1, 256, T2, 256,
                zn, 256, nullptr, nullptr, 64, 64, 0, 65536, 0, 65536, 0, 65536, -1.f, 15.f);
            mg<2,2,1,0,0,1,0,0>(stream, 256, 256, 256, T1, 256, zn, 256,
                T2, 256, nullptr, nullptr, 64, 64, 0, 65536, 0, 65536, 0, 65536, -1.f, 13.f);
            mg<2,2,1,0,0,1,0,0>(stream, 256, 256, 256, zc, 256, T2, 256,
                zn, 256, nullptr, nullptr, 64, 64, 0, 65536, 0, 65536, 0, 65536, 0.25f, 0.f);
            bh16* t = zc; zc = zn; zn = t;
        }
        mg<4,1,1,0,0,1,0,0>(stream, 256, 64, 256, zc, 256, A3Vb, 64,
            WBb, 64, nullptr, nullptr, 64, 64, 0, 65536, 0, 16384, 0, 16384, 1.f, 0.f);
        hipLaunchKernelGGL(wbt_k, dim3(512), dim3(256), 0, stream, WBb, WBT);

        // ---- fused attn1 + P@wb + conv -> AOUTa; then one out-proj ----
        hipLaunchKernelGGL(fattn_k, dim3(64, 64), dim3(256), 0, stream,
                           QKV, klbf, WBT, AOUTa);
        mg<2,2,0,0,1,0,0,0>(stream, 32768, 512, 512, AOUTa, 512, WOT, 512,
            H, 512, nullptr, bo, 1, 1, 0,0, 0,0, 0,0, 1.f, 0.f);

        // ---- FFN in 2-sample chunks ----
        for (int c = 0; c < 4; ++c) {
            float* Hc = H + (ll)c * 2 * 2097152;
            hipLaunchKernelGGL(ln_k, dim3(8192), dim3(256), 0, stream, Hc, g2, b2, XLNc);
            mg<2,2,0,1,0,1,0,0>(stream, 8192, 2048, 512, XLNc, 512, F1WT, 512,
                HIDc, 2048, nullptr, f1b, 1, 1, 0,0, 0,0, 0,0, 1.f, 0.f);
            mg<2,2,0,0,1,0,0,0>(stream, 8192, 512, 2048, HIDc, 2048, F2WT, 2048,
                Hc, 512, nullptr, f2b, 1, 1, 0,0, 0,0, 0,0, 1.f, 0.f);
        }
    }

    hipLaunchKernelGGL(final_init_k, dim3(1), dim3(128), 0, stream, final_b, out);
    hipLaunchKernelGGL(final_gemv_k, dim3(256, 2), dim3(256), 0, stream, H, final_w, out);
}